// Round 5
// baseline (13128.596 us; speedup 1.0000x reference)
//
#include <hip/hip_runtime.h>
#include <cstdint>
#include <cstddef>

// ---------- types ----------
typedef float     f32x4 __attribute__((ext_vector_type(4)));
typedef _Float16  f16x8 __attribute__((ext_vector_type(8)));
typedef _Float16  f16x4 __attribute__((ext_vector_type(4)));

#define GLD16(g, l)                                                            \
  __builtin_amdgcn_global_load_lds(                                           \
      (const __attribute__((address_space(1))) void*)(g),                     \
      (__attribute__((address_space(3))) void*)(l), 16, 0, 0)

// ---------- constants ----------
#define BQ    4
#define SEQ   1024
#define DMOD  768
#define NH    12
#define DKH   64
#define DVH   128
#define DVAL  1536
#define DFFN  3072
#define BS    4096   /* BQ*SEQ */

// =====================================================================
// weight transpose + f32->f16 hi/lo split:  in[K][N] -> hi/lo[N][K]
// lo is scaled by 1024 to stay in f16 normal range; epilogue divides.
// =====================================================================
__global__ void wcvt_kernel(const float* __restrict__ win, _Float16* __restrict__ whi,
                            _Float16* __restrict__ wlo, int K, int N)
{
  __shared__ float tle[32][33];
  size_t base = (size_t)blockIdx.z * K * N;
  int k0 = blockIdx.y * 32, n0 = blockIdx.x * 32;
  int tx = threadIdx.x, ty = threadIdx.y;
#pragma unroll
  for (int i = 0; i < 4; ++i)
    tle[ty + 8*i][tx] = win[base + (size_t)(k0 + ty + 8*i) * N + n0 + tx];
  __syncthreads();
#pragma unroll
  for (int i = 0; i < 4; ++i) {
    float v = tle[tx][ty + 8*i];
    _Float16 h = (_Float16)v;
    size_t idx = base + (size_t)(n0 + ty + 8*i) * K + k0 + tx;
    whi[idx] = h;
    wlo[idx] = (_Float16)((v - (float)h) * 1024.0f);
  }
}

// =====================================================================
// embedding gather
// =====================================================================
__global__ void embed_kernel(const int* __restrict__ ids, const float* __restrict__ emb,
                             float* __restrict__ x)
{
  int tok = blockIdx.x;
  int id  = ids[tok];
  const float4* s = (const float4*)(emb + (size_t)id * DMOD);
  float4*       d = (float4*)(x + (size_t)tok * DMOD);
  d[threadIdx.x] = s[threadIdx.x];   // block = 192 threads, 192*16B = 768 f32
}

// =====================================================================
// layernorm over 768 -> f32 out (final LN)
// =====================================================================
__global__ __launch_bounds__(256) void ln_kernel(const float* __restrict__ x,
                                                 const float* __restrict__ g,
                                                 const float* __restrict__ bta,
                                                 float* __restrict__ out)
{
  int row = blockIdx.x;
  const float* xr = x + (size_t)row * DMOD;
  int t = threadIdx.x;
  float v0 = xr[t], v1 = xr[t + 256], v2 = xr[t + 512];
  float s  = v0 + v1 + v2;
  float sq = v0*v0 + v1*v1 + v2*v2;
#pragma unroll
  for (int m = 1; m < 64; m <<= 1) { s += __shfl_xor(s, m); sq += __shfl_xor(sq, m); }
  __shared__ float red[8];
  int wv = t >> 6, ln_ = t & 63;
  if (ln_ == 0) { red[wv] = s; red[wv + 4] = sq; }
  __syncthreads();
  s  = red[0] + red[1] + red[2] + red[3];
  sq = red[4] + red[5] + red[6] + red[7];
  float mu = s * (1.f / DMOD);
  float rs = rsqrtf(sq * (1.f / DMOD) - mu * mu + 1e-5f);
  out[(size_t)row * DMOD + t      ] = (v0 - mu) * rs * g[t      ] + bta[t      ];
  out[(size_t)row * DMOD + t + 256] = (v1 - mu) * rs * g[t + 256] + bta[t + 256];
  out[(size_t)row * DMOD + t + 512] = (v2 - mu) * rs * g[t + 512] + bta[t + 512];
}

// =====================================================================
// layernorm over 768 -> f16 hi/lo pair (GEMM A-operand)
// =====================================================================
__global__ __launch_bounds__(256) void ln_hl_kernel(const float* __restrict__ x,
                                                    const float* __restrict__ g,
                                                    const float* __restrict__ bta,
                                                    _Float16* __restrict__ oh,
                                                    _Float16* __restrict__ ol)
{
  int row = blockIdx.x;
  const float* xr = x + (size_t)row * DMOD;
  int t = threadIdx.x;
  float v0 = xr[t], v1 = xr[t + 256], v2 = xr[t + 512];
  float s  = v0 + v1 + v2;
  float sq = v0*v0 + v1*v1 + v2*v2;
#pragma unroll
  for (int m = 1; m < 64; m <<= 1) { s += __shfl_xor(s, m); sq += __shfl_xor(sq, m); }
  __shared__ float red[8];
  int wv = t >> 6, ln_ = t & 63;
  if (ln_ == 0) { red[wv] = s; red[wv + 4] = sq; }
  __syncthreads();
  s  = red[0] + red[1] + red[2] + red[3];
  sq = red[4] + red[5] + red[6] + red[7];
  float mu = s * (1.f / DMOD);
  float rs = rsqrtf(sq * (1.f / DMOD) - mu * mu + 1e-5f);
#pragma unroll
  for (int q = 0; q < 3; ++q) {
    int c = t + q * 256;
    float y = (xr[c] - mu) * rs * g[c] + bta[c];
    _Float16 h = (_Float16)y;
    size_t idx = (size_t)row * DMOD + c;
    oh[idx] = h;
    ol[idx] = (_Float16)((y - (float)h) * 1024.0f);
  }
}

// =====================================================================
// GEMM: C[M][N] (f32, opt += R) =
//   (Ah + Al/1024)[M][K](f16) @ (Bh + Bl/1024)[N][K](f16)^T
// 128x128 tile, BK=32, 4 waves of 64x64, global_load_lds w/ chunk XOR swizzle.
// 3-term split product: AhBh + (AhBl + AlBh)/1024  (AlBl dropped, ~2^-22)
// =====================================================================
__global__ __launch_bounds__(256) void gemm_bt(const _Float16* __restrict__ Ah,
                                               const _Float16* __restrict__ Al,
                                               const _Float16* __restrict__ Bh,
                                               const _Float16* __restrict__ Bl,
                                               float* C, const float* R,
                                               int N, int K)
{
  __shared__ char sAh[8192];
  __shared__ char sAl[8192];
  __shared__ char sBh[8192];
  __shared__ char sBl[8192];
  const int tid = threadIdx.x, lane = tid & 63, w = tid >> 6;
  const int m0 = blockIdx.y * 128, n0 = blockIdx.x * 128;
  const int wm = (w >> 1) * 64, wn = (w & 1) * 64;
  const int lhi = lane >> 4, llo = lane & 15;

  const f32x4 fz = {0.f, 0.f, 0.f, 0.f};
  f32x4 accH[4][4], accM[4][4];
#pragma unroll
  for (int i = 0; i < 4; ++i)
#pragma unroll
    for (int j = 0; j < 4; ++j) { accH[i][j] = fz; accM[i][j] = fz; }

  // staging geometry (two 1KB issues per plane per wave)
  int off0 = w * 2048 + lane * 16;
  int rA0 = off0 >> 6,          cA0 = (off0 >> 4) & 3;
  int rA1 = (off0 + 1024) >> 6, cA1 = ((off0 + 1024) >> 4) & 3;
  size_t gA0 = (size_t)rA0 * K + ((cA0 ^ (rA0 & 3)) << 3);
  size_t gA1 = (size_t)rA1 * K + ((cA1 ^ (rA1 & 3)) << 3);

  for (int k0 = 0; k0 < K; k0 += 32) {
    __syncthreads();
    GLD16(Ah + (size_t)m0 * K + k0 + gA0, sAh + w*2048);
    GLD16(Ah + (size_t)m0 * K + k0 + gA1, sAh + w*2048 + 1024);
    GLD16(Al + (size_t)m0 * K + k0 + gA0, sAl + w*2048);
    GLD16(Al + (size_t)m0 * K + k0 + gA1, sAl + w*2048 + 1024);
    GLD16(Bh + (size_t)n0 * K + k0 + gA0, sBh + w*2048);
    GLD16(Bh + (size_t)n0 * K + k0 + gA1, sBh + w*2048 + 1024);
    GLD16(Bl + (size_t)n0 * K + k0 + gA0, sBl + w*2048);
    GLD16(Bl + (size_t)n0 * K + k0 + gA1, sBl + w*2048 + 1024);
    __syncthreads();

    f16x8 ah[4], al[4], bh[4], bl[4];
#pragma unroll
    for (int r = 0; r < 4; ++r) {
      int ra = wm + r * 16 + llo;
      int sa = ra * 64 + ((lhi ^ (ra & 3)) << 4);
      ah[r] = *(const f16x8*)(sAh + sa);
      al[r] = *(const f16x8*)(sAl + sa);
      int rb = wn + r * 16 + llo;
      int sb = rb * 64 + ((lhi ^ (rb & 3)) << 4);
      bh[r] = *(const f16x8*)(sBh + sb);
      bl[r] = *(const f16x8*)(sBl + sb);
    }
#pragma unroll
    for (int i = 0; i < 4; ++i)
#pragma unroll
      for (int j = 0; j < 4; ++j) {
        accH[i][j] = __builtin_amdgcn_mfma_f32_16x16x32_f16(ah[i], bh[j], accH[i][j], 0, 0, 0);
        accM[i][j] = __builtin_amdgcn_mfma_f32_16x16x32_f16(ah[i], bl[j], accM[i][j], 0, 0, 0);
        accM[i][j] = __builtin_amdgcn_mfma_f32_16x16x32_f16(al[i], bh[j], accM[i][j], 0, 0, 0);
      }
  }

#pragma unroll
  for (int i = 0; i < 4; ++i)
#pragma unroll
    for (int j = 0; j < 4; ++j)
#pragma unroll
      for (int rg = 0; rg < 4; ++rg) {
        int m = m0 + wm + i * 16 + lhi * 4 + rg;
        int n = n0 + wn + j * 16 + llo;
        size_t idx = (size_t)m * N + n;
        float v = accH[i][j][rg] + accM[i][j][rg] * (1.0f / 1024.0f);
        if (R) v += R[idx];
        C[idx] = v;
      }
}

// =====================================================================
// theta-shift q,k (f32 in) -> f16 hi/lo [B][H][S][DK]
// =====================================================================
__global__ void prep_qk_kernel(const float* __restrict__ qf, const float* __restrict__ kf,
                               _Float16* __restrict__ qrH, _Float16* __restrict__ qrL,
                               _Float16* __restrict__ krH, _Float16* __restrict__ krL)
{
  int row = blockIdx.x;                 // b*S + s
  int s = row & (SEQ - 1), b = row >> 10;
  int pi = threadIdx.x;                 // 0..383
  int d0 = pi * 2;
  int h = d0 >> 6;
  int i = d0 & 63;
  int j = i >> 1;
  float ang = exp2f(-(float)j * (13.287712379549449f / 31.f)); // 10000^{-j/31}
  float arg = (float)s * ang;
  float cc = cosf(arg), sn = sinf(arg);
  size_t src = (size_t)row * DMOD + d0;
  size_t dst = ((size_t)(b * NH + h) * SEQ + s) * DKH + i;

  float q0 = qf[src], q1 = qf[src + 1];
  float rq0 = q0 * cc - q1 * sn;
  float rq1 = q1 * cc + q0 * sn;
  _Float16 h0 = (_Float16)rq0, h1 = (_Float16)rq1;
  qrH[dst]     = h0; qrL[dst]     = (_Float16)((rq0 - (float)h0) * 1024.f);
  qrH[dst + 1] = h1; qrL[dst + 1] = (_Float16)((rq1 - (float)h1) * 1024.f);

  float k0 = kf[src], k1 = kf[src + 1];
  float rk0 = k0 * cc - k1 * sn;
  float rk1 = k1 * cc + k0 * sn;
  _Float16 g0 = (_Float16)rk0, g1 = (_Float16)rk1;
  krH[dst]     = g0; krL[dst]     = (_Float16)((rk0 - (float)g0) * 1024.f);
  krH[dst + 1] = g1; krL[dst + 1] = (_Float16)((rk1 - (float)g1) * 1024.f);
}

// =====================================================================
// v transpose: f32 (B,S,H,128) -> f16 [B][H][128][S]
// =====================================================================
__global__ __launch_bounds__(256) void vtrans_kernel(const float* __restrict__ vf,
                                                     _Float16* __restrict__ vt)
{
  __shared__ _Float16 tl[128][65];
  int bh = blockIdx.x >> 4;
  int s0 = (blockIdx.x & 15) << 6;
  int b = bh / NH, h = bh % NH;
  int t = threadIdx.x;
#pragma unroll
  for (int it = 0; it < 32; ++it) {
    int idx = it * 256 + t;
    int sl = idx >> 7, d = idx & 127;
    tl[d][sl] = (_Float16)vf[((size_t)(b * SEQ + s0 + sl)) * DVAL + h * DVH + d];
  }
  __syncthreads();
#pragma unroll
  for (int it = 0; it < 32; ++it) {
    int idx = it * 256 + t;
    int d = idx >> 6, sl = idx & 63;
    vt[((size_t)bh * DVH + d) * SEQ + s0 + sl] = tl[d][sl];
  }
}

// =====================================================================
// retention: per (row-block, b, h): o = (qr kr^T * D)/clip(sum|.|,1) @ v,
// then group-norm over DV=128. q/k hi/lo (3-term QK^T); p,v single f16.
// =====================================================================
__global__ __launch_bounds__(256) void attn_kernel(const _Float16* __restrict__ qrH_,
                                                   const _Float16* __restrict__ qrL_,
                                                   const _Float16* __restrict__ krH_,
                                                   const _Float16* __restrict__ krL_,
                                                   const _Float16* __restrict__ vt,
                                                   float* __restrict__ outp)
{
  __shared__ char pbuf[32768];          // 4 waves x [32][128] f16, XOR-swizzled
  const int tid = threadIdx.x, lane = tid & 63, w = tid >> 6;
  const int rb = blockIdx.x;            // row block 0..7
  const int bh = blockIdx.y;            // 0..47
  const int h = bh % NH, b = bh / NH;
  const int wrow0 = rb * 128 + w * 32;
  const int lhi = lane >> 4, llo = lane & 15;

  const _Float16* qbhH = qrH_ + (size_t)bh * SEQ * DKH;
  const _Float16* qbhL = qrL_ + (size_t)bh * SEQ * DKH;
  const _Float16* kbhH = krH_ + (size_t)bh * SEQ * DKH;
  const _Float16* kbhL = krL_ + (size_t)bh * SEQ * DKH;
  const _Float16* vbh  = vt   + (size_t)bh * DVH * SEQ;

  const float lg = log1pf(-exp2f(-(float)(5 + h)));   // ln(gamma_h)
  const float den_lg = expm1f(lg);                    // gamma - 1

  float invn[2][4];
#pragma unroll
  for (int rf = 0; rf < 2; ++rf)
#pragma unroll
    for (int rg = 0; rg < 4; ++rg) {
      int n = wrow0 + rf * 16 + lhi * 4 + rg;
      float sumD = expm1f((float)(n + 1) * lg) / den_lg;  // (1-g^{n+1})/(1-g)
      invn[rf][rg] = rsqrtf(sumD) * 0.125f;               // fold DK^-0.5
    }

  f16x8 qaH[2][2], qaL[2][2];
#pragma unroll
  for (int rf = 0; rf < 2; ++rf)
#pragma unroll
    for (int kt = 0; kt < 2; ++kt) {
      size_t qo = (size_t)(wrow0 + rf * 16 + llo) * DKH + kt * 32 + lhi * 8;
      qaH[rf][kt] = *(const f16x8*)(qbhH + qo);
      qaL[rf][kt] = *(const f16x8*)(qbhL + qo);
    }

  const f32x4 fz = {0.f, 0.f, 0.f, 0.f};
  f32x4 acc[2][8];
#pragma unroll
  for (int i = 0; i < 2; ++i)
#pragma unroll
    for (int j = 0; j < 8; ++j) acc[i][j] = fz;
  float dsum[2][4] = {{0, 0, 0, 0}, {0, 0, 0, 0}};

  for (int ct = 0; ct <= rb; ++ct) {
    __syncthreads();

    // ---- QK^T, per column-fragment: 3-term hi/lo split ----
#pragma unroll
    for (int fc = 0; fc < 8; ++fc) {
      f32x4 pH[2] = {fz, fz}, pM[2] = {fz, fz};
#pragma unroll
      for (int kt = 0; kt < 2; ++kt) {
        size_t kro = (size_t)(ct * 128 + fc * 16 + llo) * DKH + kt * 32 + lhi * 8;
        f16x8 kbH = *(const f16x8*)(kbhH + kro);
        f16x8 kbL = *(const f16x8*)(kbhL + kro);
        pH[0] = __builtin_amdgcn_mfma_f32_16x16x32_f16(qaH[0][kt], kbH, pH[0], 0, 0, 0);
        pH[1] = __builtin_amdgcn_mfma_f32_16x16x32_f16(qaH[1][kt], kbH, pH[1], 0, 0, 0);
        pM[0] = __builtin_amdgcn_mfma_f32_16x16x32_f16(qaL[0][kt], kbH, pM[0], 0, 0, 0);
        pM[1] = __builtin_amdgcn_mfma_f32_16x16x32_f16(qaL[1][kt], kbH, pM[1], 0, 0, 0);
        pM[0] = __builtin_amdgcn_mfma_f32_16x16x32_f16(qaH[0][kt], kbL, pM[0], 0, 0, 0);
        pM[1] = __builtin_amdgcn_mfma_f32_16x16x32_f16(qaH[1][kt], kbL, pM[1], 0, 0, 0);
      }
      // decay, |.|-sum, f16 -> LDS (swizzled)
#pragma unroll
      for (int rf = 0; rf < 2; ++rf)
#pragma unroll
        for (int rg = 0; rg < 4; ++rg) {
          int n = wrow0 + rf * 16 + lhi * 4 + rg;
          int m = ct * 128 + fc * 16 + llo;
          int e = n - m;
          float pv = 0.f;
          if (e >= 0)
            pv = (pH[rf][rg] + pM[rf][rg] * (1.f / 1024.f)) * expf((float)e * lg) * invn[rf][rg];
          dsum[rf][rg] += fabsf(pv);
          int prow = rf * 16 + lhi * 4 + rg;
          int byte = (w << 13) + prow * 256 + (fc * 16 + llo) * 2;
          byte ^= (prow & 7) << 4;
          *(_Float16*)(pbuf + byte) = (_Float16)pv;
        }
    }
    __syncthreads();

    // ---- PV ----
    f16x8 pa[2][4];
#pragma unroll
    for (int rf2 = 0; rf2 < 2; ++rf2)
#pragma unroll
      for (int kt = 0; kt < 4; ++kt) {
        int prow = rf2 * 16 + llo;
        int byte = (w << 13) + prow * 256 + kt * 64 + lhi * 16;
        byte ^= (prow & 7) << 4;
        pa[rf2][kt] = *(const f16x8*)(pbuf + byte);
      }
#pragma unroll
    for (int fd = 0; fd < 8; ++fd)
#pragma unroll
      for (int kt = 0; kt < 4; ++kt) {
        f16x8 vb = *(const f16x8*)(vbh + (size_t)(fd * 16 + llo) * SEQ + ct * 128 + kt * 32 + lhi * 8);
        acc[0][fd] = __builtin_amdgcn_mfma_f32_16x16x32_f16(pa[0][kt], vb, acc[0][fd], 0, 0, 0);
        acc[1][fd] = __builtin_amdgcn_mfma_f32_16x16x32_f16(pa[1][kt], vb, acc[1][fd], 0, 0, 0);
      }
  }

  // epilogue: row normalize + group-norm + store
#pragma unroll
  for (int rf = 0; rf < 2; ++rf) {
    float inv_[4];
#pragma unroll
    for (int rg = 0; rg < 4; ++rg) {
      float d = dsum[rf][rg];
      d += __shfl_xor(d, 1); d += __shfl_xor(d, 2);
      d += __shfl_xor(d, 4); d += __shfl_xor(d, 8);
      inv_[rg] = 1.f / fmaxf(d, 1.f);
    }
    float ssq[4] = {0, 0, 0, 0};
#pragma unroll
    for (int fd = 0; fd < 8; ++fd)
#pragma unroll
      for (int rg = 0; rg < 4; ++rg) {
        acc[rf][fd][rg] *= inv_[rg];
        ssq[rg] += acc[rf][fd][rg] * acc[rf][fd][rg];
      }
    float s2[4];
#pragma unroll
    for (int rg = 0; rg < 4; ++rg) {
      float t2 = ssq[rg];
      t2 += __shfl_xor(t2, 1); t2 += __shfl_xor(t2, 2);
      t2 += __shfl_xor(t2, 4); t2 += __shfl_xor(t2, 8);
      s2[rg] = rsqrtf(t2 * (1.f / 128.f) + 1e-5f);
    }
#pragma unroll
    for (int fd = 0; fd < 8; ++fd)
#pragma unroll
      for (int rg = 0; rg < 4; ++rg) {
        int n = wrow0 + rf * 16 + lhi * 4 + rg;
        int col = fd * 16 + llo;
        outp[(size_t)(b * SEQ + n) * DVAL + h * DVH + col] = acc[rf][fd][rg] * s2[rg];
      }
  }
}

// =====================================================================
// out = silu(a) * b -> f16 hi/lo pair (GEMM A-operand), float4-vectorized
// =====================================================================
__global__ void silu_mul_kernel(const float* __restrict__ a, const float* __restrict__ b,
                                _Float16* __restrict__ oh, _Float16* __restrict__ ol,
                                int n4)
{
  int stride = gridDim.x * blockDim.x;
  for (int i = blockIdx.x * blockDim.x + threadIdx.x; i < n4; i += stride) {
    float4 av = ((const float4*)a)[i];
    float4 bv = ((const float4*)b)[i];
    float y0 = av.x / (1.f + expf(-av.x)) * bv.x;
    float y1 = av.y / (1.f + expf(-av.y)) * bv.y;
    float y2 = av.z / (1.f + expf(-av.z)) * bv.z;
    float y3 = av.w / (1.f + expf(-av.w)) * bv.w;
    f16x4 rh, rl;
    rh.x = (_Float16)y0; rl.x = (_Float16)((y0 - (float)rh.x) * 1024.f);
    rh.y = (_Float16)y1; rl.y = (_Float16)((y1 - (float)rh.y) * 1024.f);
    rh.z = (_Float16)y2; rl.z = (_Float16)((y2 - (float)rh.z) * 1024.f);
    rh.w = (_Float16)y3; rl.w = (_Float16)((y3 - (float)rh.w) * 1024.f);
    ((f16x4*)oh)[i] = rh;
    ((f16x4*)ol)[i] = rl;
  }
}

// =====================================================================
// mean pool over S
// =====================================================================
__global__ void pool_kernel(const float* __restrict__ xf, float* __restrict__ pooled)
{
  int d = blockIdx.x * 256 + threadIdx.x;   // grid.x = 3
  int b = blockIdx.y;
  float acc = 0.f;
  for (int s = 0; s < SEQ; ++s) acc += xf[((size_t)(b * SEQ + s)) * DMOD + d];
  pooled[b * DMOD + d] = acc * (1.f / SEQ);
}

// =====================================================================
// classifier: out[b][c] = pooled[b] . clf_w[:,c] + clf_b[c]
// =====================================================================
__global__ void clf_kernel(const float* __restrict__ pooled, const float* __restrict__ cw,
                           const float* __restrict__ cb, float* __restrict__ out)
{
  int b = blockIdx.x, c = threadIdx.x;
  if (c < 100) {
    float acc = cb[c];
    for (int d = 0; d < DMOD; ++d) acc += pooled[b * DMOD + d] * cw[d * 100 + c];
    out[b * 100 + c] = acc;
  }
}

// =====================================================================
// host
// =====================================================================
extern "C" void kernel_launch(void* const* d_in, const int* in_sizes, int n_in,
                              void* d_out, int out_size, void* d_ws, size_t ws_size,
                              hipStream_t stream)
{
  const int*   ids  = (const int*)d_in[0];
  const float* emb  = (const float*)d_in[1];
  const float* wq   = (const float*)d_in[2];
  const float* wk   = (const float*)d_in[3];
  const float* wv   = (const float*)d_in[4];
  const float* wg   = (const float*)d_in[5];
  const float* wo   = (const float*)d_in[6];
  const float* ln1g = (const float*)d_in[7];
  const float* ln1b = (const float*)d_in[8];
  const float* ln2g = (const float*)d_in[9];
  const float* ln2b = (const float*)d_in[10];
  const float* fc1  = (const float*)d_in[11];
  const float* gate = (const float*)d_in[12];
  const float* fc2  = (const float*)d_in[13];
  const float* lnfg = (const float*)d_in[14];
  const float* lnfb = (const float*)d_in[15];
  const float* clfw = (const float*)d_in[16];
  const float* clfb = (const float*)d_in[17];
  float* out = (float*)d_out;

  char* ws = (char*)d_ws;
  size_t off = 0;
  auto alloc = [&](size_t bytes) {
    size_t r = off;
    off = (off + bytes + 255) & ~(size_t)255;
    return r;
  };

  const size_t WDD = 12ull * 768 * 768 * 2;    // wq/wk f16
  const size_t WDV = 12ull * 768 * 1536 * 2;   // wv/wg/wo
  const size_t WDF = 12ull * 768 * 3072 * 2;   // fc1/gate/fc2
  // big mode: all 12 layers' weights hi+lo resident (~566 MB) + activations
  const bool big = ws_size >= 790ull * 1024 * 1024;

  _Float16* wtq  = (_Float16*)(ws + alloc(big ? WDD : WDD / 12));
  _Float16* wtqL = (_Float16*)(ws + alloc(big ? WDD : WDD / 12));
  _Float16* wtk  = (_Float16*)(ws + alloc(big ? WDD : WDD / 12));
  _Float16* wtkL = (_Float16*)(ws + alloc(big ? WDD : WDD / 12));
  _Float16* wtv  = (_Float16*)(ws + alloc(big ? WDV : WDV / 12));
  _Float16* wtvL = (_Float16*)(ws + alloc(big ? WDV : WDV / 12));
  _Float16* wtg  = (_Float16*)(ws + alloc(big ? WDV : WDV / 12));
  _Float16* wtgL = (_Float16*)(ws + alloc(big ? WDV : WDV / 12));
  _Float16* wto  = (_Float16*)(ws + alloc(big ? WDV : WDV / 12));
  _Float16* wtoL = (_Float16*)(ws + alloc(big ? WDV : WDV / 12));
  _Float16* wtf1  = (_Float16*)(ws + alloc(big ? WDF : WDF / 12));
  _Float16* wtf1L = (_Float16*)(ws + alloc(big ? WDF : WDF / 12));
  _Float16* wtgt  = (_Float16*)(ws + alloc(big ? WDF : WDF / 12));
  _Float16* wtgtL = (_Float16*)(ws + alloc(big ? WDF : WDF / 12));
  _Float16* wtf2  = (_Float16*)(ws + alloc(big ? WDF : WDF / 12));
  _Float16* wtf2L = (_Float16*)(ws + alloc(big ? WDF : WDF / 12));

  float*    x    = (float*)(ws + alloc((size_t)BS * DMOD * 4));
  _Float16* hbfH = (_Float16*)(ws + alloc((size_t)BS * DMOD * 2));
  _Float16* hbfL = (_Float16*)(ws + alloc((size_t)BS * DMOD * 2));
  char* r1 = ws + alloc((size_t)BS * DFFN * 4);   // q|k|v  ->  f1_out / xf
  char* r2 = ws + alloc((size_t)BS * DFFN * 4);   // g|attn_o -> gt_out
  char* r3 = ws + alloc((size_t)BS * DFFN * 2);   // qrH|krH|vt -> ogH -> ffnH
  char* r4 = ws + alloc((size_t)BS * DFFN * 2);   // qrL|krL -> ogL / ffnL
  float* pooled = (float*)(ws + alloc(4 * DMOD * 4));

  float* qf  = (float*)r1;
  float* kf  = (float*)(r1 + 12582912);
  float* vf  = (float*)(r1 + 25165824);
  float* f1o = (float*)r1;
  float* xf  = (float*)r1;

  float* gf  = (float*)r2;
  float* ao  = (float*)(r2 + 25165824);
  float* gto = (float*)r2;

  _Float16* qrbH  = (_Float16*)r3;
  _Float16* krbH  = (_Float16*)(r3 + 6291456);
  _Float16* vtb   = (_Float16*)(r3 + 12582912);
  _Float16* ogbH  = (_Float16*)r3;
  _Float16* ffnbH = (_Float16*)r3;

  _Float16* qrbL  = (_Float16*)r4;
  _Float16* krbL  = (_Float16*)(r4 + 6291456);
  _Float16* ogbL  = (_Float16*)r4;
  _Float16* ffnbL = (_Float16*)r4;

  dim3 tb(32, 8);
  if (big) {
    wcvt_kernel<<<dim3(24, 24, 12), tb, 0, stream>>>(wq,   wtq,  wtqL,  768, 768);
    wcvt_kernel<<<dim3(24, 24, 12), tb, 0, stream>>>(wk,   wtk,  wtkL,  768, 768);
    wcvt_kernel<<<dim3(48, 24, 12), tb, 0, stream>>>(wv,   wtv,  wtvL,  768, 1536);
    wcvt_kernel<<<dim3(48, 24, 12), tb, 0, stream>>>(wg,   wtg,  wtgL,  768, 1536);
    wcvt_kernel<<<dim3(24, 48, 12), tb, 0, stream>>>(wo,   wto,  wtoL,  1536, 768);
    wcvt_kernel<<<dim3(96, 24, 12), tb, 0, stream>>>(fc1,  wtf1, wtf1L, 768, 3072);
    wcvt_kernel<<<dim3(96, 24, 12), tb, 0, stream>>>(gate, wtgt, wtgtL, 768, 3072);
    wcvt_kernel<<<dim3(24, 96, 12), tb, 0, stream>>>(fc2,  wtf2, wtf2L, 3072, 768);
  }

  embed_kernel<<<BS, 192, 0, stream>>>(ids, emb, x);

  auto gemm = [&](const _Float16* AH, const _Float16* AL,
                  const _Float16* Bh, const _Float16* Bl,
                  float* C, const float* R, int N, int K) {
    gemm_bt<<<dim3(N / 128, 32), 256, 0, stream>>>(AH, AL, Bh, Bl, C, R, N, K);
  };

  for (int l = 0; l < 12; ++l) {
    const _Float16 *Wq, *WqL, *Wk, *WkL, *Wv, *WvL, *Wg, *WgL, *Wo, *WoL,
                   *Wf1, *Wf1L, *Wgt, *WgtL, *Wf2, *Wf2L;
    if (big) {
      Wq  = wtq  + (size_t)l * 768 * 768;   WqL  = wtqL  + (size_t)l * 768 * 768;
      Wk  = wtk  + (size_t)l * 768 * 768;   WkL  = wtkL  + (size_t)l * 768 * 768;
      Wv  = wtv  + (size_t)l * 1536 * 768;  WvL  = wtvL  + (size_t)l * 1536 * 768;
      Wg  = wtg  + (size_t)l * 1536 * 768;  WgL  = wtgL  + (size_t)l * 1536 * 768;
      Wo  = wto  + (size_t)l * 768 * 1536;  WoL  = wtoL  + (size_t)l * 768 * 1536;
      Wf1 = wtf1 + (size_t)l * 3072 * 768;  Wf1L = wtf1L + (size_t)l * 3072 * 768;
      Wgt = wtgt + (size_t)l * 3072 * 768;  WgtL = wtgtL + (size_t)l * 3072 * 768;
      Wf2 = wtf2 + (size_t)l * 768 * 3072;  Wf2L = wtf2L + (size_t)l * 768 * 3072;
    } else {
      wcvt_kernel<<<dim3(24, 24, 1), tb, 0, stream>>>(wq   + (size_t)l * 768 * 768,  wtq,  wtqL,  768, 768);
      wcvt_kernel<<<dim3(24, 24, 1), tb, 0, stream>>>(wk   + (size_t)l * 768 * 768,  wtk,  wtkL,  768, 768);
      wcvt_kernel<<<dim3(48, 24, 1), tb, 0, stream>>>(wv   + (size_t)l * 768 * 1536, wtv,  wtvL,  768, 1536);
      wcvt_kernel<<<dim3(48, 24, 1), tb, 0, stream>>>(wg   + (size_t)l * 768 * 1536, wtg,  wtgL,  768, 1536);
      wcvt_kernel<<<dim3(24, 48, 1), tb, 0, stream>>>(wo   + (size_t)l * 1536 * 768, wto,  wtoL,  1536, 768);
      wcvt_kernel<<<dim3(96, 24, 1), tb, 0, stream>>>(fc1  + (size_t)l * 768 * 3072, wtf1, wtf1L, 768, 3072);
      wcvt_kernel<<<dim3(96, 24, 1), tb, 0, stream>>>(gate + (size_t)l * 768 * 3072, wtgt, wtgtL, 768, 3072);
      wcvt_kernel<<<dim3(24, 96, 1), tb, 0, stream>>>(fc2  + (size_t)l * 3072 * 768, wtf2, wtf2L, 3072, 768);
      Wq = wtq; WqL = wtqL; Wk = wtk; WkL = wtkL; Wv = wtv; WvL = wtvL;
      Wg = wtg; WgL = wtgL; Wo = wto; WoL = wtoL;
      Wf1 = wtf1; Wf1L = wtf1L; Wgt = wtgt; WgtL = wtgtL; Wf2 = wtf2; Wf2L = wtf2L;
    }

    ln_hl_kernel<<<BS, 256, 0, stream>>>(x, ln1g + l * 768, ln1b + l * 768, hbfH, hbfL);
    gemm(hbfH, hbfL, Wq, WqL, qf, nullptr, 768, 768);
    gemm(hbfH, hbfL, Wk, WkL, kf, nullptr, 768, 768);
    gemm(hbfH, hbfL, Wv, WvL, vf, nullptr, 1536, 768);
    gemm(hbfH, hbfL, Wg, WgL, gf, nullptr, 1536, 768);
    prep_qk_kernel<<<BS, 384, 0, stream>>>(qf, kf, qrbH, qrbL, krbH, krbL);
    vtrans_kernel<<<768, 256, 0, stream>>>(vf, vtb);
    attn_kernel<<<dim3(8, 48), 256, 0, stream>>>(qrbH, qrbL, krbH, krbL, vtb, ao);
    silu_mul_kernel<<<1024, 256, 0, stream>>>(gf, ao, ogbH, ogbL, BS * DVAL / 4);
    gemm(ogbH, ogbL, Wo, WoL, x, x, 768, 1536);
    ln_hl_kernel<<<BS, 256, 0, stream>>>(x, ln2g + l * 768, ln2b + l * 768, hbfH, hbfL);
    gemm(hbfH, hbfL, Wf1, Wf1L, f1o, nullptr, 3072, 768);
    gemm(hbfH, hbfL, Wgt, WgtL, gto, nullptr, 3072, 768);
    silu_mul_kernel<<<2048, 256, 0, stream>>>(f1o, gto, ffnbH, ffnbL, BS * DFFN / 4);
    gemm(ffnbH, ffnbL, Wf2, Wf2L, x, x, 768, 3072);
  }

  ln_kernel<<<BS, 256, 0, stream>>>(x, lnfg, lnfb, xf);
  pool_kernel<<<dim3(3, 4), 256, 0, stream>>>(xf, pooled);
  clf_kernel<<<4, 128, 0, stream>>>(pooled, clfw, clfb, out);
}

// Round 6
// 11424.896 us; speedup vs baseline: 1.1491x; 1.1491x over previous
//
#include <hip/hip_runtime.h>
#include <cstdint>
#include <cstddef>

// ---------- types ----------
typedef float     f32x4 __attribute__((ext_vector_type(4)));
typedef _Float16  f16x8 __attribute__((ext_vector_type(8)));
typedef _Float16  f16x4 __attribute__((ext_vector_type(4)));

#define GLD16(g, l)                                                            \
  __builtin_amdgcn_global_load_lds(                                           \
      (const __attribute__((address_space(1))) void*)(g),                     \
      (__attribute__((address_space(3))) void*)(l), 16, 0, 0)

// ---------- constants ----------
#define BQ    4
#define SEQ   1024
#define DMOD  768
#define NH    12
#define DKH   64
#define DVH   128
#define DVAL  1536
#define DFFN  3072
#define BS    4096   /* BQ*SEQ */

// =====================================================================
// weight transpose + f32->f16 hi/lo split into fused layout:
//   in[z][K][N] -> out[z][row_off+N][K] slices of a larger [NTOT][K] matrix
// lo scaled by 1024 (stays f16-normal); GEMM epilogue divides.
// =====================================================================
__global__ void wcvt_kernel(const float* __restrict__ win, _Float16* __restrict__ whi,
                            _Float16* __restrict__ wlo, int K, int N,
                            long in_ls, long out_ls, int row_off)
{
  __shared__ float tle[32][33];
  size_t ib = (size_t)blockIdx.z * in_ls;
  size_t ob = (size_t)blockIdx.z * out_ls;
  int k0 = blockIdx.y * 32, n0 = blockIdx.x * 32;
  int tx = threadIdx.x, ty = threadIdx.y;
#pragma unroll
  for (int i = 0; i < 4; ++i)
    tle[ty + 8*i][tx] = win[ib + (size_t)(k0 + ty + 8*i) * N + n0 + tx];
  __syncthreads();
#pragma unroll
  for (int i = 0; i < 4; ++i) {
    float v = tle[tx][ty + 8*i];
    _Float16 h = (_Float16)v;
    size_t idx = ob + (size_t)(n0 + ty + 8*i + row_off) * K + k0 + tx;
    whi[idx] = h;
    wlo[idx] = (_Float16)((v - (float)h) * 1024.0f);
  }
}

// =====================================================================
// embedding gather
// =====================================================================
__global__ void embed_kernel(const int* __restrict__ ids, const float* __restrict__ emb,
                             float* __restrict__ x)
{
  int tok = blockIdx.x;
  int id  = ids[tok];
  const float4* s = (const float4*)(emb + (size_t)id * DMOD);
  float4*       d = (float4*)(x + (size_t)tok * DMOD);
  d[threadIdx.x] = s[threadIdx.x];   // block = 192 threads
}

// =====================================================================
// layernorm over 768 -> f32 out (final LN)
// =====================================================================
__global__ __launch_bounds__(256) void ln_kernel(const float* __restrict__ x,
                                                 const float* __restrict__ g,
                                                 const float* __restrict__ bta,
                                                 float* __restrict__ out)
{
  int row = blockIdx.x;
  const float* xr = x + (size_t)row * DMOD;
  int t = threadIdx.x;
  float v0 = xr[t], v1 = xr[t + 256], v2 = xr[t + 512];
  float s  = v0 + v1 + v2;
  float sq = v0*v0 + v1*v1 + v2*v2;
#pragma unroll
  for (int m = 1; m < 64; m <<= 1) { s += __shfl_xor(s, m); sq += __shfl_xor(sq, m); }
  __shared__ float red[8];
  int wv = t >> 6, ln_ = t & 63;
  if (ln_ == 0) { red[wv] = s; red[wv + 4] = sq; }
  __syncthreads();
  s  = red[0] + red[1] + red[2] + red[3];
  sq = red[4] + red[5] + red[6] + red[7];
  float mu = s * (1.f / DMOD);
  float rs = rsqrtf(sq * (1.f / DMOD) - mu * mu + 1e-5f);
  out[(size_t)row * DMOD + t      ] = (v0 - mu) * rs * g[t      ] + bta[t      ];
  out[(size_t)row * DMOD + t + 256] = (v1 - mu) * rs * g[t + 256] + bta[t + 256];
  out[(size_t)row * DMOD + t + 512] = (v2 - mu) * rs * g[t + 512] + bta[t + 512];
}

// =====================================================================
// layernorm over 768 -> f16 hi/lo pair (GEMM A-operand)
// =====================================================================
__global__ __launch_bounds__(256) void ln_hl_kernel(const float* __restrict__ x,
                                                    const float* __restrict__ g,
                                                    const float* __restrict__ bta,
                                                    _Float16* __restrict__ oh,
                                                    _Float16* __restrict__ ol)
{
  int row = blockIdx.x;
  const float* xr = x + (size_t)row * DMOD;
  int t = threadIdx.x;
  float v0 = xr[t], v1 = xr[t + 256], v2 = xr[t + 512];
  float s  = v0 + v1 + v2;
  float sq = v0*v0 + v1*v1 + v2*v2;
#pragma unroll
  for (int m = 1; m < 64; m <<= 1) { s += __shfl_xor(s, m); sq += __shfl_xor(sq, m); }
  __shared__ float red[8];
  int wv = t >> 6, ln_ = t & 63;
  if (ln_ == 0) { red[wv] = s; red[wv + 4] = sq; }
  __syncthreads();
  s  = red[0] + red[1] + red[2] + red[3];
  sq = red[4] + red[5] + red[6] + red[7];
  float mu = s * (1.f / DMOD);
  float rs = rsqrtf(sq * (1.f / DMOD) - mu * mu + 1e-5f);
#pragma unroll
  for (int q = 0; q < 3; ++q) {
    int c = t + q * 256;
    float y = (xr[c] - mu) * rs * g[c] + bta[c];
    _Float16 h = (_Float16)y;
    size_t idx = (size_t)row * DMOD + c;
    oh[idx] = h;
    ol[idx] = (_Float16)((y - (float)h) * 1024.0f);
  }
}

// =====================================================================
// GEMM: C[M][N] (f32 ldc-strided, opt += R) =
//   (Ah + Al/1024)[M][K](f16) @ (Bh + Bl/1024)[NTOT][K](f16)^T
// BMx128 tile (BM=128 or 64), BK=32, 4 waves, global_load_lds + XOR swizzle,
// 1D grid with bijective XCD swizzle. 3-term split product.
// =====================================================================
template<int BM>
__global__ __launch_bounds__(256) void gemm_bt(const _Float16* __restrict__ Ah,
                                               const _Float16* __restrict__ Al,
                                               const _Float16* __restrict__ Bh,
                                               const _Float16* __restrict__ Bl,
                                               float* __restrict__ C,
                                               const float* __restrict__ R,
                                               int nbx, int K, int ldc)
{
  constexpr int RI = BM / 32;           // row fragments per wave
  __shared__ char sAh[BM * 64];
  __shared__ char sAl[BM * 64];
  __shared__ char sBh[8192];
  __shared__ char sBl[8192];
  const int tid = threadIdx.x, lane = tid & 63, w = tid >> 6;

  // bijective XCD swizzle over the 1D grid
  int nwg = gridDim.x, bid = blockIdx.x;
  int qq = nwg >> 3, rr = nwg & 7;
  int xc = bid & 7, ix = bid >> 3;
  int wg = (xc < rr ? xc * (qq + 1) : rr * (qq + 1) + (xc - rr) * qq) + ix;
  int bx = wg % nbx, by = wg / nbx;

  const int m0 = by * BM, n0 = bx * 128;
  const int wm = (w >> 1) * (BM / 2), wn = (w & 1) * 64;
  const int lhi = lane >> 4, llo = lane & 15;

  const f32x4 fz = {0.f, 0.f, 0.f, 0.f};
  f32x4 accH[RI][4], accM[RI][4];
#pragma unroll
  for (int i = 0; i < RI; ++i)
#pragma unroll
    for (int j = 0; j < 4; ++j) { accH[i][j] = fz; accM[i][j] = fz; }

  for (int k0 = 0; k0 < K; k0 += 32) {
    __syncthreads();
#pragma unroll
    for (int i = 0; i < BM / 64; ++i) {           // A planes: BM*64 B each
      int off = w * (BM * 16) + i * 1024 + lane * 16;
      int r = off >> 6, c = (off >> 4) & 3;
      size_t go = (size_t)r * K + ((c ^ (r & 3)) << 3);
      GLD16(Ah + (size_t)m0 * K + k0 + go, sAh + w * (BM * 16) + i * 1024);
      GLD16(Al + (size_t)m0 * K + k0 + go, sAl + w * (BM * 16) + i * 1024);
    }
#pragma unroll
    for (int i = 0; i < 2; ++i) {                 // B planes: 8 KB each
      int off = w * 2048 + i * 1024 + lane * 16;
      int r = off >> 6, c = (off >> 4) & 3;
      size_t go = (size_t)r * K + ((c ^ (r & 3)) << 3);
      GLD16(Bh + (size_t)n0 * K + k0 + go, sBh + w * 2048 + i * 1024);
      GLD16(Bl + (size_t)n0 * K + k0 + go, sBl + w * 2048 + i * 1024);
    }
    __syncthreads();

    f16x8 ah[RI], al[RI], bh[4], bl[4];
#pragma unroll
    for (int r = 0; r < RI; ++r) {
      int ra = wm + r * 16 + llo;
      int sa = ra * 64 + ((lhi ^ (ra & 3)) << 4);
      ah[r] = *(const f16x8*)(sAh + sa);
      al[r] = *(const f16x8*)(sAl + sa);
    }
#pragma unroll
    for (int r = 0; r < 4; ++r) {
      int rb = wn + r * 16 + llo;
      int sb = rb * 64 + ((lhi ^ (rb & 3)) << 4);
      bh[r] = *(const f16x8*)(sBh + sb);
      bl[r] = *(const f16x8*)(sBl + sb);
    }
#pragma unroll
    for (int i = 0; i < RI; ++i)
#pragma unroll
      for (int j = 0; j < 4; ++j) {
        accH[i][j] = __builtin_amdgcn_mfma_f32_16x16x32_f16(ah[i], bh[j], accH[i][j], 0, 0, 0);
        accM[i][j] = __builtin_amdgcn_mfma_f32_16x16x32_f16(ah[i], bl[j], accM[i][j], 0, 0, 0);
        accM[i][j] = __builtin_amdgcn_mfma_f32_16x16x32_f16(al[i], bh[j], accM[i][j], 0, 0, 0);
      }
  }

#pragma unroll
  for (int i = 0; i < RI; ++i)
#pragma unroll
    for (int j = 0; j < 4; ++j)
#pragma unroll
      for (int rg = 0; rg < 4; ++rg) {
        int m = m0 + wm + i * 16 + lhi * 4 + rg;
        int n = n0 + wn + j * 16 + llo;
        size_t idx = (size_t)m * ldc + n;
        float v = accH[i][j][rg] + accM[i][j][rg] * (1.0f / 1024.0f);
        if (R) v += R[idx];
        C[idx] = v;
      }
}

// =====================================================================
// theta-shift q,k (f32 strided in fused C) -> f16 hi/lo [B][H][S][DK]
// =====================================================================
__global__ void prep_qk_kernel(const float* __restrict__ qk, int ld,
                               _Float16* __restrict__ qrH, _Float16* __restrict__ qrL,
                               _Float16* __restrict__ krH, _Float16* __restrict__ krL)
{
  int row = blockIdx.x;                 // b*S + s
  int s = row & (SEQ - 1), b = row >> 10;
  int pi = threadIdx.x;                 // 0..383
  int d0 = pi * 2;
  int h = d0 >> 6;
  int i = d0 & 63;
  int j = i >> 1;
  float ang = exp2f(-(float)j * (13.287712379549449f / 31.f)); // 10000^{-j/31}
  float arg = (float)s * ang;
  float cc = cosf(arg), sn = sinf(arg);
  size_t src = (size_t)row * ld + d0;
  size_t dst = ((size_t)(b * NH + h) * SEQ + s) * DKH + i;

  float q0 = qk[src], q1 = qk[src + 1];
  float rq0 = q0 * cc - q1 * sn;
  float rq1 = q1 * cc + q0 * sn;
  _Float16 h0 = (_Float16)rq0, h1 = (_Float16)rq1;
  qrH[dst]     = h0; qrL[dst]     = (_Float16)((rq0 - (float)h0) * 1024.f);
  qrH[dst + 1] = h1; qrL[dst + 1] = (_Float16)((rq1 - (float)h1) * 1024.f);

  float k0 = qk[src + 768], k1 = qk[src + 769];
  float rk0 = k0 * cc - k1 * sn;
  float rk1 = k1 * cc + k0 * sn;
  _Float16 g0 = (_Float16)rk0, g1 = (_Float16)rk1;
  krH[dst]     = g0; krL[dst]     = (_Float16)((rk0 - (float)g0) * 1024.f);
  krH[dst + 1] = g1; krL[dst + 1] = (_Float16)((rk1 - (float)g1) * 1024.f);
}

// =====================================================================
// v transpose: f32 strided (B,S,[H*128 in fused C]) -> f16 [B][H][128][S]
// =====================================================================
__global__ __launch_bounds__(256) void vtrans_kernel(const float* __restrict__ vsrc, int ld,
                                                     _Float16* __restrict__ vt)
{
  __shared__ _Float16 tl[128][65];
  int bh = blockIdx.x >> 4;
  int s0 = (blockIdx.x & 15) << 6;
  int b = bh / NH, h = bh % NH;
  int t = threadIdx.x;
#pragma unroll
  for (int it = 0; it < 32; ++it) {
    int idx = it * 256 + t;
    int sl = idx >> 7, d = idx & 127;
    tl[d][sl] = (_Float16)vsrc[(size_t)(b * SEQ + s0 + sl) * ld + h * DVH + d];
  }
  __syncthreads();
#pragma unroll
  for (int it = 0; it < 32; ++it) {
    int idx = it * 256 + t;
    int d = idx >> 6, sl = idx & 63;
    vt[((size_t)bh * DVH + d) * SEQ + s0 + sl] = tl[d][sl];
  }
}

// =====================================================================
// retention: per (row-block, b, h): o = (qr kr^T * D)/clip(sum|.|,1) @ v,
// then group-norm over DV=128. q/k hi/lo (3-term QK^T); p,v single f16.
// =====================================================================
__global__ __launch_bounds__(256) void attn_kernel(const _Float16* __restrict__ qrH_,
                                                   const _Float16* __restrict__ qrL_,
                                                   const _Float16* __restrict__ krH_,
                                                   const _Float16* __restrict__ krL_,
                                                   const _Float16* __restrict__ vt,
                                                   float* __restrict__ outp)
{
  __shared__ char pbuf[32768];          // 4 waves x [32][128] f16, XOR-swizzled
  const int tid = threadIdx.x, lane = tid & 63, w = tid >> 6;
  const int rb = blockIdx.x;            // row block 0..7
  const int bh = blockIdx.y;            // 0..47
  const int h = bh % NH, b = bh / NH;
  const int wrow0 = rb * 128 + w * 32;
  const int lhi = lane >> 4, llo = lane & 15;

  const _Float16* qbhH = qrH_ + (size_t)bh * SEQ * DKH;
  const _Float16* qbhL = qrL_ + (size_t)bh * SEQ * DKH;
  const _Float16* kbhH = krH_ + (size_t)bh * SEQ * DKH;
  const _Float16* kbhL = krL_ + (size_t)bh * SEQ * DKH;
  const _Float16* vbh  = vt   + (size_t)bh * DVH * SEQ;

  const float lg = log1pf(-exp2f(-(float)(5 + h)));   // ln(gamma_h)
  const float den_lg = expm1f(lg);                    // gamma - 1

  float invn[2][4];
#pragma unroll
  for (int rf = 0; rf < 2; ++rf)
#pragma unroll
    for (int rg = 0; rg < 4; ++rg) {
      int n = wrow0 + rf * 16 + lhi * 4 + rg;
      float sumD = expm1f((float)(n + 1) * lg) / den_lg;  // (1-g^{n+1})/(1-g)
      invn[rf][rg] = rsqrtf(sumD) * 0.125f;               // fold DK^-0.5
    }

  f16x8 qaH[2][2], qaL[2][2];
#pragma unroll
  for (int rf = 0; rf < 2; ++rf)
#pragma unroll
    for (int kt = 0; kt < 2; ++kt) {
      size_t qo = (size_t)(wrow0 + rf * 16 + llo) * DKH + kt * 32 + lhi * 8;
      qaH[rf][kt] = *(const f16x8*)(qbhH + qo);
      qaL[rf][kt] = *(const f16x8*)(qbhL + qo);
    }

  const f32x4 fz = {0.f, 0.f, 0.f, 0.f};
  f32x4 acc[2][8];
#pragma unroll
  for (int i = 0; i < 2; ++i)
#pragma unroll
    for (int j = 0; j < 8; ++j) acc[i][j] = fz;
  float dsum[2][4] = {{0, 0, 0, 0}, {0, 0, 0, 0}};

  for (int ct = 0; ct <= rb; ++ct) {
    __syncthreads();

    // ---- QK^T, per column-fragment: 3-term hi/lo split ----
#pragma unroll
    for (int fc = 0; fc < 8; ++fc) {
      f32x4 pH[2] = {fz, fz}, pM[2] = {fz, fz};
#pragma unroll
      for (int kt = 0; kt < 2; ++kt) {
        size_t kro = (size_t)(ct * 128 + fc * 16 + llo) * DKH + kt * 32 + lhi * 8;
        f16x8 kbH = *(const f16x8*)(kbhH + kro);
        f16x8 kbL = *(const f16x8*)(kbhL + kro);
        pH[0] = __builtin_amdgcn_mfma_f32_16x16x32_f16(qaH[0][kt], kbH, pH[0], 0, 0, 0);
        pH[1] = __builtin_amdgcn_mfma_f32_16x16x32_f16(qaH[1][kt], kbH, pH[1], 0, 0, 0);
        pM[0] = __builtin_amdgcn_mfma_f32_16x16x32_f16(qaL[0][kt], kbH, pM[0], 0, 0, 0);
        pM[1] = __builtin_amdgcn_mfma_f32_16x16x32_f16(qaL[1][kt], kbH, pM[1], 0, 0, 0);
        pM[0] = __builtin_amdgcn_mfma_f32_16x16x32_f16(qaH[0][kt], kbL, pM[0], 0, 0, 0);
        pM[1] = __builtin_amdgcn_mfma_f32_16x16x32_f16(qaH[1][kt], kbL, pM[1], 0, 0, 0);
      }
      // decay, |.|-sum, f16 -> LDS (swizzled)
#pragma unroll
      for (int rf = 0; rf < 2; ++rf)
#pragma unroll
        for (int rg = 0; rg < 4; ++rg) {
          int n = wrow0 + rf * 16 + lhi * 4 + rg;
          int m = ct * 128 + fc * 16 + llo;
          int e = n - m;
          float pv = 0.f;
          if (e >= 0)
            pv = (pH[rf][rg] + pM[rf][rg] * (1.f / 1024.f)) * expf((float)e * lg) * invn[rf][rg];
          dsum[rf][rg] += fabsf(pv);
          int prow = rf * 16 + lhi * 4 + rg;
          int byte = (w << 13) + prow * 256 + (fc * 16 + llo) * 2;
          byte ^= (prow & 7) << 4;
          *(_Float16*)(pbuf + byte) = (_Float16)pv;
        }
    }
    __syncthreads();

    // ---- PV ----
    f16x8 pa[2][4];
#pragma unroll
    for (int rf2 = 0; rf2 < 2; ++rf2)
#pragma unroll
      for (int kt = 0; kt < 4; ++kt) {
        int prow = rf2 * 16 + llo;
        int byte = (w << 13) + prow * 256 + kt * 64 + lhi * 16;
        byte ^= (prow & 7) << 4;
        pa[rf2][kt] = *(const f16x8*)(pbuf + byte);
      }
#pragma unroll
    for (int fd = 0; fd < 8; ++fd)
#pragma unroll
      for (int kt = 0; kt < 4; ++kt) {
        f16x8 vb = *(const f16x8*)(vbh + (size_t)(fd * 16 + llo) * SEQ + ct * 128 + kt * 32 + lhi * 8);
        acc[0][fd] = __builtin_amdgcn_mfma_f32_16x16x32_f16(pa[0][kt], vb, acc[0][fd], 0, 0, 0);
        acc[1][fd] = __builtin_amdgcn_mfma_f32_16x16x32_f16(pa[1][kt], vb, acc[1][fd], 0, 0, 0);
      }
  }

  // epilogue: row normalize + group-norm + store
#pragma unroll
  for (int rf = 0; rf < 2; ++rf) {
    float inv_[4];
#pragma unroll
    for (int rg = 0; rg < 4; ++rg) {
      float d = dsum[rf][rg];
      d += __shfl_xor(d, 1); d += __shfl_xor(d, 2);
      d += __shfl_xor(d, 4); d += __shfl_xor(d, 8);
      inv_[rg] = 1.f / fmaxf(d, 1.f);
    }
    float ssq[4] = {0, 0, 0, 0};
#pragma unroll
    for (int fd = 0; fd < 8; ++fd)
#pragma unroll
      for (int rg = 0; rg < 4; ++rg) {
        acc[rf][fd][rg] *= inv_[rg];
        ssq[rg] += acc[rf][fd][rg] * acc[rf][fd][rg];
      }
    float s2[4];
#pragma unroll
    for (int rg = 0; rg < 4; ++rg) {
      float t2 = ssq[rg];
      t2 += __shfl_xor(t2, 1); t2 += __shfl_xor(t2, 2);
      t2 += __shfl_xor(t2, 4); t2 += __shfl_xor(t2, 8);
      s2[rg] = rsqrtf(t2 * (1.f / 128.f) + 1e-5f);
    }
#pragma unroll
    for (int fd = 0; fd < 8; ++fd)
#pragma unroll
      for (int rg = 0; rg < 4; ++rg) {
        int n = wrow0 + rf * 16 + lhi * 4 + rg;
        int col = fd * 16 + llo;
        outp[(size_t)(b * SEQ + n) * DVAL + h * DVH + col] = acc[rf][fd][rg] * s2[rg];
      }
  }
}

// =====================================================================
// out = silu(a) * b -> f16 hi/lo dense pair; a,b strided (float4 units)
// =====================================================================
__global__ void silu_mul_kernel(const float* __restrict__ a, int lda4,
                                const float* __restrict__ b, int ldb4,
                                _Float16* __restrict__ oh, _Float16* __restrict__ ol,
                                int cols4, int total)
{
  int stride = gridDim.x * blockDim.x;
  for (int i = blockIdx.x * blockDim.x + threadIdx.x; i < total; i += stride) {
    int rr = i / cols4, cc = i - rr * cols4;
    float4 av = ((const float4*)a)[(size_t)rr * lda4 + cc];
    float4 bv = ((const float4*)b)[(size_t)rr * ldb4 + cc];
    float y0 = av.x / (1.f + expf(-av.x)) * bv.x;
    float y1 = av.y / (1.f + expf(-av.y)) * bv.y;
    float y2 = av.z / (1.f + expf(-av.z)) * bv.z;
    float y3 = av.w / (1.f + expf(-av.w)) * bv.w;
    f16x4 rh, rl;
    rh.x = (_Float16)y0; rl.x = (_Float16)((y0 - (float)rh.x) * 1024.f);
    rh.y = (_Float16)y1; rl.y = (_Float16)((y1 - (float)rh.y) * 1024.f);
    rh.z = (_Float16)y2; rl.z = (_Float16)((y2 - (float)rh.z) * 1024.f);
    rh.w = (_Float16)y3; rl.w = (_Float16)((y3 - (float)rh.w) * 1024.f);
    ((f16x4*)oh)[i] = rh;
    ((f16x4*)ol)[i] = rl;
  }
}

// =====================================================================
// mean pool over S
// =====================================================================
__global__ void pool_kernel(const float* __restrict__ xf, float* __restrict__ pooled)
{
  int d = blockIdx.x * 256 + threadIdx.x;   // grid.x = 3
  int b = blockIdx.y;
  float acc = 0.f;
  for (int s = 0; s < SEQ; ++s) acc += xf[((size_t)(b * SEQ + s)) * DMOD + d];
  pooled[b * DMOD + d] = acc * (1.f / SEQ);
}

// =====================================================================
// classifier: out[b][c] = pooled[b] . clf_w[:,c] + clf_b[c]
// =====================================================================
__global__ void clf_kernel(const float* __restrict__ pooled, const float* __restrict__ cw,
                           const float* __restrict__ cb, float* __restrict__ out)
{
  int b = blockIdx.x, c = threadIdx.x;
  if (c < 100) {
    float acc = cb[c];
    for (int d = 0; d < DMOD; ++d) acc += pooled[b * DMOD + d] * cw[d * 100 + c];
    out[b * 100 + c] = acc;
  }
}

// =====================================================================
// host
// =====================================================================
extern "C" void kernel_launch(void* const* d_in, const int* in_sizes, int n_in,
                              void* d_out, int out_size, void* d_ws, size_t ws_size,
                              hipStream_t stream)
{
  const int*   ids  = (const int*)d_in[0];
  const float* emb  = (const float*)d_in[1];
  const float* wq   = (const float*)d_in[2];
  const float* wk   = (const float*)d_in[3];
  const float* wv   = (const float*)d_in[4];
  const float* wg   = (const float*)d_in[5];
  const float* wo   = (const float*)d_in[6];
  const float* ln1g = (const float*)d_in[7];
  const float* ln1b = (const float*)d_in[8];
  const float* ln2g = (const float*)d_in[9];
  const float* ln2b = (const float*)d_in[10];
  const float* fc1  = (const float*)d_in[11];
  const float* gate = (const float*)d_in[12];
  const float* fc2  = (const float*)d_in[13];
  const float* lnfg = (const float*)d_in[14];
  const float* lnfb = (const float*)d_in[15];
  const float* clfw = (const float*)d_in[16];
  const float* clfb = (const float*)d_in[17];
  float* out = (float*)d_out;

  char* ws = (char*)d_ws;
  size_t off = 0;
  auto alloc = [&](size_t bytes) {
    size_t r = off;
    off = (off + bytes + 255) & ~(size_t)255;
    return r;
  };

  // fused weight plane sizes (per 12 layers, f16)
  const size_t W_QKVG = 12ull * 4608 * 768 * 2;   // 84.9 MB per plane
  const size_t W_O    = 12ull * 768 * 1536 * 2;
  const size_t W_F1GT = 12ull * 6144 * 768 * 2;
  const size_t W_F2   = 12ull * 768 * 3072 * 2;
  const bool big = ws_size >= 756ull * 1024 * 1024;
  const size_t d12 = big ? 1 : 12;   // divide per-layer buffers in small mode

  _Float16* wQKVGh = (_Float16*)(ws + alloc(W_QKVG / d12));
  _Float16* wQKVGl = (_Float16*)(ws + alloc(W_QKVG / d12));
  _Float16* wOh    = (_Float16*)(ws + alloc(W_O    / d12));
  _Float16* wOl    = (_Float16*)(ws + alloc(W_O    / d12));
  _Float16* wF1GTh = (_Float16*)(ws + alloc(W_F1GT / d12));
  _Float16* wF1GTl = (_Float16*)(ws + alloc(W_F1GT / d12));
  _Float16* wF2h   = (_Float16*)(ws + alloc(W_F2   / d12));
  _Float16* wF2l   = (_Float16*)(ws + alloc(W_F2   / d12));

  float*    x    = (float*)(ws + alloc((size_t)BS * DMOD * 4));
  _Float16* hbfH = (_Float16*)(ws + alloc((size_t)BS * DMOD * 2));
  _Float16* hbfL = (_Float16*)(ws + alloc((size_t)BS * DMOD * 2));
  float*    cbuf = (float*)(ws + alloc((size_t)BS * 6144 * 4));   // fused GEMM out
  char*     regB = ws + alloc(6ull * BS * DKH * NH * 2 * 3);      // 37.75 MB
  float*    ao   = (float*)(ws + alloc((size_t)BS * DVAL * 4));   // follows regB
  float*    pooled = (float*)(ws + alloc(4 * DMOD * 4));

  _Float16* qrbH = (_Float16*)regB;
  _Float16* qrbL = (_Float16*)(regB + 6291456);
  _Float16* krbH = (_Float16*)(regB + 12582912);
  _Float16* krbL = (_Float16*)(regB + 18874368);
  _Float16* vtb  = (_Float16*)(regB + 25165824);
  _Float16* ogbH = (_Float16*)regB;                 // alias (post-attn)
  _Float16* ogbL = (_Float16*)(regB + 12582912);
  _Float16* ffnbH = (_Float16*)regB;                // alias (post-wo, spills into ao)
  _Float16* ffnbL = (_Float16*)(regB + 25165824);

  dim3 tb(32, 8);
  const long lsDD = 768l * 768, lsDV = 768l * 1536, lsDF = 768l * 3072;
  const long oQKVG = 4608l * 768, oO = 768l * 1536, oF1 = 6144l * 768, oF2 = 768l * 3072;

  if (big) {
    wcvt_kernel<<<dim3(24, 24, 12), tb, 0, stream>>>(wq,   wQKVGh, wQKVGl, 768, 768,  lsDD, oQKVG, 0);
    wcvt_kernel<<<dim3(24, 24, 12), tb, 0, stream>>>(wk,   wQKVGh, wQKVGl, 768, 768,  lsDD, oQKVG, 768);
    wcvt_kernel<<<dim3(48, 24, 12), tb, 0, stream>>>(wv,   wQKVGh, wQKVGl, 768, 1536, lsDV, oQKVG, 1536);
    wcvt_kernel<<<dim3(48, 24, 12), tb, 0, stream>>>(wg,   wQKVGh, wQKVGl, 768, 1536, lsDV, oQKVG, 3072);
    wcvt_kernel<<<dim3(24, 48, 12), tb, 0, stream>>>(wo,   wOh,    wOl,    1536, 768, lsDV, oO,    0);
    wcvt_kernel<<<dim3(96, 24, 12), tb, 0, stream>>>(fc1,  wF1GTh, wF1GTl, 768, 3072, lsDF, oF1,   0);
    wcvt_kernel<<<dim3(96, 24, 12), tb, 0, stream>>>(gate, wF1GTh, wF1GTl, 768, 3072, lsDF, oF1,   3072);
    wcvt_kernel<<<dim3(24, 96, 12), tb, 0, stream>>>(fc2,  wF2h,   wF2l,   3072, 768, lsDF, oF2,   0);
  }

  embed_kernel<<<BS, 192, 0, stream>>>(ids, emb, x);

  for (int l = 0; l < 12; ++l) {
    const _Float16 *Wqkh, *Wqkl, *Woh_, *Wol_, *Wfh, *Wfl, *W2h, *W2l;
    if (big) {
      Wqkh = wQKVGh + (size_t)l * oQKVG;  Wqkl = wQKVGl + (size_t)l * oQKVG;
      Woh_ = wOh    + (size_t)l * oO;     Wol_ = wOl    + (size_t)l * oO;
      Wfh  = wF1GTh + (size_t)l * oF1;    Wfl  = wF1GTl + (size_t)l * oF1;
      W2h  = wF2h   + (size_t)l * oF2;    W2l  = wF2l   + (size_t)l * oF2;
    } else {
      wcvt_kernel<<<dim3(24, 24, 1), tb, 0, stream>>>(wq   + (size_t)l * lsDD, wQKVGh, wQKVGl, 768, 768,  0, 0, 0);
      wcvt_kernel<<<dim3(24, 24, 1), tb, 0, stream>>>(wk   + (size_t)l * lsDD, wQKVGh, wQKVGl, 768, 768,  0, 0, 768);
      wcvt_kernel<<<dim3(48, 24, 1), tb, 0, stream>>>(wv   + (size_t)l * lsDV, wQKVGh, wQKVGl, 768, 1536, 0, 0, 1536);
      wcvt_kernel<<<dim3(48, 24, 1), tb, 0, stream>>>(wg   + (size_t)l * lsDV, wQKVGh, wQKVGl, 768, 1536, 0, 0, 3072);
      wcvt_kernel<<<dim3(24, 48, 1), tb, 0, stream>>>(wo   + (size_t)l * lsDV, wOh,    wOl,    1536, 768, 0, 0, 0);
      wcvt_kernel<<<dim3(96, 24, 1), tb, 0, stream>>>(fc1  + (size_t)l * lsDF, wF1GTh, wF1GTl, 768, 3072, 0, 0, 0);
      wcvt_kernel<<<dim3(96, 24, 1), tb, 0, stream>>>(gate + (size_t)l * lsDF, wF1GTh, wF1GTl, 768, 3072, 0, 0, 3072);
      wcvt_kernel<<<dim3(24, 96, 1), tb, 0, stream>>>(fc2  + (size_t)l * lsDF, wF2h,   wF2l,   3072, 768, 0, 0, 0);
      Wqkh = wQKVGh; Wqkl = wQKVGl; Woh_ = wOh; Wol_ = wOl;
      Wfh = wF1GTh; Wfl = wF1GTl; W2h = wF2h; W2l = wF2l;
    }

    ln_hl_kernel<<<BS, 256, 0, stream>>>(x, ln1g + l * 768, ln1b + l * 768, hbfH, hbfL);
    gemm_bt<128><<<36 * 32, 256, 0, stream>>>(hbfH, hbfL, Wqkh, Wqkl, cbuf, nullptr, 36, 768, 4608);
    prep_qk_kernel<<<BS, 384, 0, stream>>>(cbuf, 4608, qrbH, qrbL, krbH, krbL);
    vtrans_kernel<<<768, 256, 0, stream>>>(cbuf + 1536, 4608, vtb);
    attn_kernel<<<dim3(8, 48), 256, 0, stream>>>(qrbH, qrbL, krbH, krbL, vtb, ao);
    silu_mul_kernel<<<1024, 256, 0, stream>>>(cbuf + 3072, 1152, ao, 384, ogbH, ogbL,
                                              384, BS * 384);
    gemm_bt<64><<<6 * 64, 256, 0, stream>>>(ogbH, ogbL, Woh_, Wol_, x, x, 6, 1536, 768);
    ln_hl_kernel<<<BS, 256, 0, stream>>>(x, ln2g + l * 768, ln2b + l * 768, hbfH, hbfL);
    gemm_bt<128><<<48 * 32, 256, 0, stream>>>(hbfH, hbfL, Wfh, Wfl, cbuf, nullptr, 48, 768, 6144);
    silu_mul_kernel<<<2048, 256, 0, stream>>>(cbuf, 1536, cbuf + 3072, 1536, ffnbH, ffnbL,
                                              768, BS * 768);
    gemm_bt<64><<<6 * 64, 256, 0, stream>>>(ffnbH, ffnbL, W2h, W2l, x, x, 6, 3072, 768);
  }

  float* xf = cbuf;
  ln_kernel<<<BS, 256, 0, stream>>>(x, lnfg, lnfb, xf);
  pool_kernel<<<dim3(3, 4), 256, 0, stream>>>(xf, pooled);
  clf_kernel<<<4, 128, 0, stream>>>(pooled, clfw, clfb, out);
}

// Round 7
// 10155.584 us; speedup vs baseline: 1.2927x; 1.1250x over previous
//
#include <hip/hip_runtime.h>
#include <cstdint>
#include <cstddef>

// ---------- types ----------
typedef float     f32x4 __attribute__((ext_vector_type(4)));
typedef _Float16  f16x8 __attribute__((ext_vector_type(8)));
typedef _Float16  f16x4 __attribute__((ext_vector_type(4)));

#define GLD16(g, l)                                                            \
  __builtin_amdgcn_global_load_lds(                                           \
      (const __attribute__((address_space(1))) void*)(g),                     \
      (__attribute__((address_space(3))) void*)(l), 16, 0, 0)

// ---------- constants ----------
#define BQ    4
#define SEQ   1024
#define DMOD  768
#define NH    12
#define DKH   64
#define DVH   128
#define DVAL  1536
#define DFFN  3072
#define BS    4096   /* BQ*SEQ */

// =====================================================================
// weight transpose + f32->f16 hi/lo split into fused layout:
//   in[z][K][N] -> out[z][row_off+N][K] slices of a larger [NTOT][K] matrix
// =====================================================================
__global__ void wcvt_kernel(const float* __restrict__ win, _Float16* __restrict__ whi,
                            _Float16* __restrict__ wlo, int K, int N,
                            long in_ls, long out_ls, int row_off)
{
  __shared__ float tle[32][33];
  size_t ib = (size_t)blockIdx.z * in_ls;
  size_t ob = (size_t)blockIdx.z * out_ls;
  int k0 = blockIdx.y * 32, n0 = blockIdx.x * 32;
  int tx = threadIdx.x, ty = threadIdx.y;
#pragma unroll
  for (int i = 0; i < 4; ++i)
    tle[ty + 8*i][tx] = win[ib + (size_t)(k0 + ty + 8*i) * N + n0 + tx];
  __syncthreads();
#pragma unroll
  for (int i = 0; i < 4; ++i) {
    float v = tle[tx][ty + 8*i];
    _Float16 h = (_Float16)v;
    size_t idx = ob + (size_t)(n0 + ty + 8*i + row_off) * K + k0 + tx;
    whi[idx] = h;
    wlo[idx] = (_Float16)((v - (float)h) * 1024.0f);
  }
}

// =====================================================================
// embedding gather
// =====================================================================
__global__ void embed_kernel(const int* __restrict__ ids, const float* __restrict__ emb,
                             float* __restrict__ x)
{
  int tok = blockIdx.x;
  int id  = ids[tok];
  const float4* s = (const float4*)(emb + (size_t)id * DMOD);
  float4*       d = (float4*)(x + (size_t)tok * DMOD);
  d[threadIdx.x] = s[threadIdx.x];   // block = 192 threads
}

// =====================================================================
// layernorm over 768 -> f32 out (final LN)
// =====================================================================
__global__ __launch_bounds__(256) void ln_kernel(const float* __restrict__ x,
                                                 const float* __restrict__ g,
                                                 const float* __restrict__ bta,
                                                 float* __restrict__ out)
{
  int row = blockIdx.x;
  const float* xr = x + (size_t)row * DMOD;
  int t = threadIdx.x;
  float v0 = xr[t], v1 = xr[t + 256], v2 = xr[t + 512];
  float s  = v0 + v1 + v2;
  float sq = v0*v0 + v1*v1 + v2*v2;
#pragma unroll
  for (int m = 1; m < 64; m <<= 1) { s += __shfl_xor(s, m); sq += __shfl_xor(sq, m); }
  __shared__ float red[8];
  int wv = t >> 6, ln_ = t & 63;
  if (ln_ == 0) { red[wv] = s; red[wv + 4] = sq; }
  __syncthreads();
  s  = red[0] + red[1] + red[2] + red[3];
  sq = red[4] + red[5] + red[6] + red[7];
  float mu = s * (1.f / DMOD);
  float rs = rsqrtf(sq * (1.f / DMOD) - mu * mu + 1e-5f);
  out[(size_t)row * DMOD + t      ] = (v0 - mu) * rs * g[t      ] + bta[t      ];
  out[(size_t)row * DMOD + t + 256] = (v1 - mu) * rs * g[t + 256] + bta[t + 256];
  out[(size_t)row * DMOD + t + 512] = (v2 - mu) * rs * g[t + 512] + bta[t + 512];
}

// =====================================================================
// layernorm over 768 -> f16 hi/lo pair (GEMM A-operand)
// =====================================================================
__global__ __launch_bounds__(256) void ln_hl_kernel(const float* __restrict__ x,
                                                    const float* __restrict__ g,
                                                    const float* __restrict__ bta,
                                                    _Float16* __restrict__ oh,
                                                    _Float16* __restrict__ ol)
{
  int row = blockIdx.x;
  const float* xr = x + (size_t)row * DMOD;
  int t = threadIdx.x;
  float v0 = xr[t], v1 = xr[t + 256], v2 = xr[t + 512];
  float s  = v0 + v1 + v2;
  float sq = v0*v0 + v1*v1 + v2*v2;
#pragma unroll
  for (int m = 1; m < 64; m <<= 1) { s += __shfl_xor(s, m); sq += __shfl_xor(sq, m); }
  __shared__ float red[8];
  int wv = t >> 6, ln_ = t & 63;
  if (ln_ == 0) { red[wv] = s; red[wv + 4] = sq; }
  __syncthreads();
  s  = red[0] + red[1] + red[2] + red[3];
  sq = red[4] + red[5] + red[6] + red[7];
  float mu = s * (1.f / DMOD);
  float rs = rsqrtf(sq * (1.f / DMOD) - mu * mu + 1e-5f);
#pragma unroll
  for (int q = 0; q < 3; ++q) {
    int c = t + q * 256;
    float y = (xr[c] - mu) * rs * g[c] + bta[c];
    _Float16 h = (_Float16)y;
    size_t idx = (size_t)row * DMOD + c;
    oh[idx] = h;
    ol[idx] = (_Float16)((y - (float)h) * 1024.0f);
  }
}

// =====================================================================
// GEMM: C[M][N] (f32 ldc-strided, opt += R) =
//   (Ah + Al/1024)[M][K](f16) @ (Bh + Bl/1024)[NTOT][K](f16)^T
// BMx128 tile, BK=32, 4 waves, global_load_lds + XOR swizzle, XCD swizzle.
// =====================================================================
template<int BM>
__global__ __launch_bounds__(256) void gemm_bt(const _Float16* __restrict__ Ah,
                                               const _Float16* __restrict__ Al,
                                               const _Float16* __restrict__ Bh,
                                               const _Float16* __restrict__ Bl,
                                               float* __restrict__ C,
                                               const float* __restrict__ R,
                                               int nbx, int K, int ldc)
{
  constexpr int RI = BM / 32;           // row fragments per wave
  __shared__ char sAh[BM * 64];
  __shared__ char sAl[BM * 64];
  __shared__ char sBh[8192];
  __shared__ char sBl[8192];
  const int tid = threadIdx.x, lane = tid & 63, w = tid >> 6;

  // bijective XCD swizzle over the 1D grid
  int nwg = gridDim.x, bid = blockIdx.x;
  int qq = nwg >> 3, rr = nwg & 7;
  int xc = bid & 7, ix = bid >> 3;
  int wg = (xc < rr ? xc * (qq + 1) : rr * (qq + 1) + (xc - rr) * qq) + ix;
  int bx = wg % nbx, by = wg / nbx;

  const int m0 = by * BM, n0 = bx * 128;
  const int wm = (w >> 1) * (BM / 2), wn = (w & 1) * 64;
  const int lhi = lane >> 4, llo = lane & 15;

  const f32x4 fz = {0.f, 0.f, 0.f, 0.f};
  f32x4 accH[RI][4], accM[RI][4];
#pragma unroll
  for (int i = 0; i < RI; ++i)
#pragma unroll
    for (int j = 0; j < 4; ++j) { accH[i][j] = fz; accM[i][j] = fz; }

  for (int k0 = 0; k0 < K; k0 += 32) {
    __syncthreads();
#pragma unroll
    for (int i = 0; i < BM / 64; ++i) {           // A planes
      int off = w * (BM * 16) + i * 1024 + lane * 16;
      int r = off >> 6, c = (off >> 4) & 3;
      size_t go = (size_t)r * K + ((c ^ (r & 3)) << 3);
      GLD16(Ah + (size_t)m0 * K + k0 + go, sAh + w * (BM * 16) + i * 1024);
      GLD16(Al + (size_t)m0 * K + k0 + go, sAl + w * (BM * 16) + i * 1024);
    }
#pragma unroll
    for (int i = 0; i < 2; ++i) {                 // B planes
      int off = w * 2048 + i * 1024 + lane * 16;
      int r = off >> 6, c = (off >> 4) & 3;
      size_t go = (size_t)r * K + ((c ^ (r & 3)) << 3);
      GLD16(Bh + (size_t)n0 * K + k0 + go, sBh + w * 2048 + i * 1024);
      GLD16(Bl + (size_t)n0 * K + k0 + go, sBl + w * 2048 + i * 1024);
    }
    __syncthreads();

    f16x8 ah[RI], al[RI], bh[4], bl[4];
#pragma unroll
    for (int r = 0; r < RI; ++r) {
      int ra = wm + r * 16 + llo;
      int sa = ra * 64 + ((lhi ^ (ra & 3)) << 4);
      ah[r] = *(const f16x8*)(sAh + sa);
      al[r] = *(const f16x8*)(sAl + sa);
    }
#pragma unroll
    for (int r = 0; r < 4; ++r) {
      int rb = wn + r * 16 + llo;
      int sb = rb * 64 + ((lhi ^ (rb & 3)) << 4);
      bh[r] = *(const f16x8*)(sBh + sb);
      bl[r] = *(const f16x8*)(sBl + sb);
    }
#pragma unroll
    for (int i = 0; i < RI; ++i)
#pragma unroll
      for (int j = 0; j < 4; ++j) {
        accH[i][j] = __builtin_amdgcn_mfma_f32_16x16x32_f16(ah[i], bh[j], accH[i][j], 0, 0, 0);
        accM[i][j] = __builtin_amdgcn_mfma_f32_16x16x32_f16(ah[i], bl[j], accM[i][j], 0, 0, 0);
        accM[i][j] = __builtin_amdgcn_mfma_f32_16x16x32_f16(al[i], bh[j], accM[i][j], 0, 0, 0);
      }
  }

#pragma unroll
  for (int i = 0; i < RI; ++i)
#pragma unroll
    for (int j = 0; j < 4; ++j)
#pragma unroll
      for (int rg = 0; rg < 4; ++rg) {
        int m = m0 + wm + i * 16 + lhi * 4 + rg;
        int n = n0 + wn + j * 16 + llo;
        size_t idx = (size_t)m * ldc + n;
        float v = accH[i][j][rg] + accM[i][j][rg] * (1.0f / 1024.0f);
        if (R) v += R[idx];
        C[idx] = v;
      }
}

// =====================================================================
// theta-shift q,k (f32 strided in fused C) -> f16 hi/lo [B][H][S][DK]
// =====================================================================
__global__ void prep_qk_kernel(const float* __restrict__ qk, int ld,
                               _Float16* __restrict__ qrH, _Float16* __restrict__ qrL,
                               _Float16* __restrict__ krH, _Float16* __restrict__ krL)
{
  int row = blockIdx.x;                 // b*S + s
  int s = row & (SEQ - 1), b = row >> 10;
  int pi = threadIdx.x;                 // 0..383
  int d0 = pi * 2;
  int h = d0 >> 6;
  int i = d0 & 63;
  int j = i >> 1;
  float ang = exp2f(-(float)j * (13.287712379549449f / 31.f)); // 10000^{-j/31}
  float arg = (float)s * ang;
  float cc = cosf(arg), sn = sinf(arg);
  size_t src = (size_t)row * ld + d0;
  size_t dst = ((size_t)(b * NH + h) * SEQ + s) * DKH + i;

  float q0 = qk[src], q1 = qk[src + 1];
  float rq0 = q0 * cc - q1 * sn;
  float rq1 = q1 * cc + q0 * sn;
  _Float16 h0 = (_Float16)rq0, h1 = (_Float16)rq1;
  qrH[dst]     = h0; qrL[dst]     = (_Float16)((rq0 - (float)h0) * 1024.f);
  qrH[dst + 1] = h1; qrL[dst + 1] = (_Float16)((rq1 - (float)h1) * 1024.f);

  float k0 = qk[src + 768], k1 = qk[src + 769];
  float rk0 = k0 * cc - k1 * sn;
  float rk1 = k1 * cc + k0 * sn;
  _Float16 g0 = (_Float16)rk0, g1 = (_Float16)rk1;
  krH[dst]     = g0; krL[dst]     = (_Float16)((rk0 - (float)g0) * 1024.f);
  krH[dst + 1] = g1; krL[dst + 1] = (_Float16)((rk1 - (float)g1) * 1024.f);
}

// =====================================================================
// v transpose: f32 strided -> f16 [B][H][128][S]
// =====================================================================
__global__ __launch_bounds__(256) void vtrans_kernel(const float* __restrict__ vsrc, int ld,
                                                     _Float16* __restrict__ vt)
{
  __shared__ _Float16 tl[128][65];
  int bh = blockIdx.x >> 4;
  int s0 = (blockIdx.x & 15) << 6;
  int b = bh / NH, h = bh % NH;
  int t = threadIdx.x;
#pragma unroll
  for (int it = 0; it < 32; ++it) {
    int idx = it * 256 + t;
    int sl = idx >> 7, d = idx & 127;
    tl[d][sl] = (_Float16)vsrc[(size_t)(b * SEQ + s0 + sl) * ld + h * DVH + d];
  }
  __syncthreads();
#pragma unroll
  for (int it = 0; it < 32; ++it) {
    int idx = it * 256 + t;
    int d = idx >> 6, sl = idx & 63;
    vt[((size_t)bh * DVH + d) * SEQ + s0 + sl] = tl[d][sl];
  }
}

// =====================================================================
// retention stage 1: per (bh, rb, ct-chunk<=2): QK^T(3-term) -> decay ->
// PV partial; atomicAdd into accbuf[bh][s][dv] and dsacc[bh][s].
// 960 uniform blocks. Decay via hoisted exp factorization.
// =====================================================================
__global__ __launch_bounds__(256) void attn_part(const _Float16* __restrict__ qrH_,
                                                 const _Float16* __restrict__ qrL_,
                                                 const _Float16* __restrict__ krH_,
                                                 const _Float16* __restrict__ krL_,
                                                 const _Float16* __restrict__ vt,
                                                 float* __restrict__ accb,
                                                 float* __restrict__ dsacc)
{
  static const int RBtab[20] = {0,1,2,2,3,3,4,4,4,5,5,5,6,6,6,6,7,7,7,7};
  static const int C0tab[20] = {0,0,0,2,0,2,0,2,4,0,2,4,0,2,4,6,0,2,4,6};
  __shared__ char pbuf[32768];          // 4 waves x [32][128] f16, XOR-swizzled
  const int tid = threadIdx.x, lane = tid & 63, w = tid >> 6;
  const int rb = RBtab[blockIdx.x], c0 = C0tab[blockIdx.x];
  const int bh = blockIdx.y;            // 0..47
  const int h = bh % NH;
  const int wrow0 = rb * 128 + w * 32;
  const int lhi = lane >> 4, llo = lane & 15;

  const _Float16* qbhH = qrH_ + (size_t)bh * SEQ * DKH;
  const _Float16* qbhL = qrL_ + (size_t)bh * SEQ * DKH;
  const _Float16* kbhH = krH_ + (size_t)bh * SEQ * DKH;
  const _Float16* kbhL = krL_ + (size_t)bh * SEQ * DKH;
  const _Float16* vbh  = vt   + (size_t)bh * DVH * SEQ;

  const float lg = log1pf(-exp2f(-(float)(5 + h)));   // ln(gamma_h)
  const float den_lg = expm1f(lg);                    // gamma - 1

  float invn[2][4];
#pragma unroll
  for (int rf = 0; rf < 2; ++rf)
#pragma unroll
    for (int rg = 0; rg < 4; ++rg) {
      int n = wrow0 + rf * 16 + lhi * 4 + rg;
      float sumD = expm1f((float)(n + 1) * lg) / den_lg;  // (1-g^{n+1})/(1-g)
      invn[rf][rg] = rsqrtf(sumD) * 0.125f;               // fold DK^-0.5
    }

  // gamma^{-(fc*16+llo)} — ct-independent column factor
  float gm[8];
#pragma unroll
  for (int fc = 0; fc < 8; ++fc)
    gm[fc] = expf(-(float)(fc * 16 + llo) * lg);

  f16x8 qaH[2][2], qaL[2][2];
#pragma unroll
  for (int rf = 0; rf < 2; ++rf)
#pragma unroll
    for (int kt = 0; kt < 2; ++kt) {
      size_t qo = (size_t)(wrow0 + rf * 16 + llo) * DKH + kt * 32 + lhi * 8;
      qaH[rf][kt] = *(const f16x8*)(qbhH + qo);
      qaL[rf][kt] = *(const f16x8*)(qbhL + qo);
    }

  const f32x4 fz = {0.f, 0.f, 0.f, 0.f};
  f32x4 acc[2][8];
#pragma unroll
  for (int i = 0; i < 2; ++i)
#pragma unroll
    for (int j = 0; j < 8; ++j) acc[i][j] = fz;
  float dsum[2][4] = {{0, 0, 0, 0}, {0, 0, 0, 0}};

  const int ctend = (c0 + 1 < rb) ? c0 + 1 : rb;
  for (int ct = c0; ct <= ctend; ++ct) {
    const bool diag = (ct == rb);
    // gamma^{n - ct*128} * invn  — row factor for this tile
    float fn[2][4];
#pragma unroll
    for (int rf = 0; rf < 2; ++rf)
#pragma unroll
      for (int rg = 0; rg < 4; ++rg) {
        int n = wrow0 + rf * 16 + lhi * 4 + rg;
        fn[rf][rg] = expf((float)(n - ct * 128) * lg) * invn[rf][rg];
      }

    // ---- QK^T per column-fragment, 3-term hi/lo ----
#pragma unroll
    for (int fc = 0; fc < 8; ++fc) {
      f32x4 pH[2] = {fz, fz}, pM[2] = {fz, fz};
#pragma unroll
      for (int kt = 0; kt < 2; ++kt) {
        size_t kro = (size_t)(ct * 128 + fc * 16 + llo) * DKH + kt * 32 + lhi * 8;
        f16x8 kbH = *(const f16x8*)(kbhH + kro);
        f16x8 kbL = *(const f16x8*)(kbhL + kro);
        pH[0] = __builtin_amdgcn_mfma_f32_16x16x32_f16(qaH[0][kt], kbH, pH[0], 0, 0, 0);
        pH[1] = __builtin_amdgcn_mfma_f32_16x16x32_f16(qaH[1][kt], kbH, pH[1], 0, 0, 0);
        pM[0] = __builtin_amdgcn_mfma_f32_16x16x32_f16(qaL[0][kt], kbH, pM[0], 0, 0, 0);
        pM[1] = __builtin_amdgcn_mfma_f32_16x16x32_f16(qaL[1][kt], kbH, pM[1], 0, 0, 0);
        pM[0] = __builtin_amdgcn_mfma_f32_16x16x32_f16(qaH[0][kt], kbL, pM[0], 0, 0, 0);
        pM[1] = __builtin_amdgcn_mfma_f32_16x16x32_f16(qaH[1][kt], kbL, pM[1], 0, 0, 0);
      }
#pragma unroll
      for (int rf = 0; rf < 2; ++rf)
#pragma unroll
        for (int rg = 0; rg < 4; ++rg) {
          float pv = (pH[rf][rg] + pM[rf][rg] * (1.f / 1024.f)) * fn[rf][rg] * gm[fc];
          if (diag) {
            int e = (wrow0 + rf * 16 + lhi * 4 + rg) - (ct * 128 + fc * 16 + llo);
            if (e < 0) pv = 0.f;
          }
          dsum[rf][rg] += fabsf(pv);
          int prow = rf * 16 + lhi * 4 + rg;
          int byte = (w << 13) + prow * 256 + (fc * 16 + llo) * 2;
          byte ^= (prow & 7) << 4;
          *(_Float16*)(pbuf + byte) = (_Float16)pv;
        }
    }
    // each wave reads only its own pbuf slice — no barrier needed

    // ---- PV ----
    f16x8 pa[2][4];
#pragma unroll
    for (int rf2 = 0; rf2 < 2; ++rf2)
#pragma unroll
      for (int kt = 0; kt < 4; ++kt) {
        int prow = rf2 * 16 + llo;
        int byte = (w << 13) + prow * 256 + kt * 64 + lhi * 16;
        byte ^= (prow & 7) << 4;
        pa[rf2][kt] = *(const f16x8*)(pbuf + byte);
      }
#pragma unroll
    for (int fd = 0; fd < 8; ++fd)
#pragma unroll
      for (int kt = 0; kt < 4; ++kt) {
        f16x8 vb = *(const f16x8*)(vbh + (size_t)(fd * 16 + llo) * SEQ + ct * 128 + kt * 32 + lhi * 8);
        acc[0][fd] = __builtin_amdgcn_mfma_f32_16x16x32_f16(pa[0][kt], vb, acc[0][fd], 0, 0, 0);
        acc[1][fd] = __builtin_amdgcn_mfma_f32_16x16x32_f16(pa[1][kt], vb, acc[1][fd], 0, 0, 0);
      }
  }

  // ---- flush partials ----
  float* ab = accb + (size_t)bh * SEQ * DVH;
#pragma unroll
  for (int rf = 0; rf < 2; ++rf)
#pragma unroll
    for (int rg = 0; rg < 4; ++rg) {
      float d = dsum[rf][rg];
      d += __shfl_xor(d, 1); d += __shfl_xor(d, 2);
      d += __shfl_xor(d, 4); d += __shfl_xor(d, 8);
      int row = wrow0 + rf * 16 + lhi * 4 + rg;
      if (llo == 0) atomicAdd(&dsacc[bh * SEQ + row], d);
#pragma unroll
      for (int fd = 0; fd < 8; ++fd)
        atomicAdd(&ab[(size_t)row * DVH + fd * 16 + llo], acc[rf][fd][rg]);
    }
}

// =====================================================================
// retention stage 2: row-normalize + group-norm + store to (B,S,H*DV)
// =====================================================================
__global__ __launch_bounds__(256) void attn_norm(const float* __restrict__ accb,
                                                 const float* __restrict__ dsacc,
                                                 float* __restrict__ outp)
{
  int bh = blockIdx.y, h = bh % NH, b = bh / NH;
  int s0 = blockIdx.x * 32;
  int lane = threadIdx.x & 63, w = threadIdx.x >> 6;
  const float* ab = accb + ((size_t)bh * SEQ + s0) * DVH;
#pragma unroll
  for (int i = 0; i < 8; ++i) {
    int r = w * 8 + i;
    float2 v = *(const float2*)(ab + (size_t)r * DVH + lane * 2);
    float inv = 1.f / fmaxf(dsacc[bh * SEQ + s0 + r], 1.f);
    v.x *= inv; v.y *= inv;
    float ss = v.x * v.x + v.y * v.y;
#pragma unroll
    for (int m = 1; m < 64; m <<= 1) ss += __shfl_xor(ss, m);
    float rs = rsqrtf(ss * (1.f / 128.f) + 1e-5f);
    float2 o = {v.x * rs, v.y * rs};
    *(float2*)(outp + ((size_t)(b * SEQ + s0 + r)) * DVAL + h * DVH + lane * 2) = o;
  }
}

// =====================================================================
// out = silu(a) * b -> f16 hi/lo dense pair; a,b strided (float4 units)
// =====================================================================
__global__ void silu_mul_kernel(const float* __restrict__ a, int lda4,
                                const float* __restrict__ b, int ldb4,
                                _Float16* __restrict__ oh, _Float16* __restrict__ ol,
                                int cols4, int total)
{
  int stride = gridDim.x * blockDim.x;
  for (int i = blockIdx.x * blockDim.x + threadIdx.x; i < total; i += stride) {
    int rr = i / cols4, cc = i - rr * cols4;
    float4 av = ((const float4*)a)[(size_t)rr * lda4 + cc];
    float4 bv = ((const float4*)b)[(size_t)rr * ldb4 + cc];
    float y0 = av.x / (1.f + expf(-av.x)) * bv.x;
    float y1 = av.y / (1.f + expf(-av.y)) * bv.y;
    float y2 = av.z / (1.f + expf(-av.z)) * bv.z;
    float y3 = av.w / (1.f + expf(-av.w)) * bv.w;
    f16x4 rh, rl;
    rh.x = (_Float16)y0; rl.x = (_Float16)((y0 - (float)rh.x) * 1024.f);
    rh.y = (_Float16)y1; rl.y = (_Float16)((y1 - (float)rh.y) * 1024.f);
    rh.z = (_Float16)y2; rl.z = (_Float16)((y2 - (float)rh.z) * 1024.f);
    rh.w = (_Float16)y3; rl.w = (_Float16)((y3 - (float)rh.w) * 1024.f);
    ((f16x4*)oh)[i] = rh;
    ((f16x4*)ol)[i] = rl;
  }
}

// =====================================================================
// mean pool over S
// =====================================================================
__global__ void pool_kernel(const float* __restrict__ xf, float* __restrict__ pooled)
{
  int d = blockIdx.x * 256 + threadIdx.x;   // grid.x = 3
  int b = blockIdx.y;
  float acc = 0.f;
  for (int s = 0; s < SEQ; ++s) acc += xf[((size_t)(b * SEQ + s)) * DMOD + d];
  pooled[b * DMOD + d] = acc * (1.f / SEQ);
}

// =====================================================================
// classifier
// =====================================================================
__global__ void clf_kernel(const float* __restrict__ pooled, const float* __restrict__ cw,
                           const float* __restrict__ cb, float* __restrict__ out)
{
  int b = blockIdx.x, c = threadIdx.x;
  if (c < 100) {
    float acc = cb[c];
    for (int d = 0; d < DMOD; ++d) acc += pooled[b * DMOD + d] * cw[d * 100 + c];
    out[b * 100 + c] = acc;
  }
}

// =====================================================================
// host
// =====================================================================
extern "C" void kernel_launch(void* const* d_in, const int* in_sizes, int n_in,
                              void* d_out, int out_size, void* d_ws, size_t ws_size,
                              hipStream_t stream)
{
  const int*   ids  = (const int*)d_in[0];
  const float* emb  = (const float*)d_in[1];
  const float* wq   = (const float*)d_in[2];
  const float* wk   = (const float*)d_in[3];
  const float* wv   = (const float*)d_in[4];
  const float* wg   = (const float*)d_in[5];
  const float* wo   = (const float*)d_in[6];
  const float* ln1g = (const float*)d_in[7];
  const float* ln1b = (const float*)d_in[8];
  const float* ln2g = (const float*)d_in[9];
  const float* ln2b = (const float*)d_in[10];
  const float* fc1  = (const float*)d_in[11];
  const float* gate = (const float*)d_in[12];
  const float* fc2  = (const float*)d_in[13];
  const float* lnfg = (const float*)d_in[14];
  const float* lnfb = (const float*)d_in[15];
  const float* clfw = (const float*)d_in[16];
  const float* clfb = (const float*)d_in[17];
  float* out = (float*)d_out;

  char* ws = (char*)d_ws;
  size_t off = 0;
  auto alloc = [&](size_t bytes) {
    size_t r = off;
    off = (off + bytes + 255) & ~(size_t)255;
    return r;
  };

  const size_t W_QKVG = 12ull * 4608 * 768 * 2;
  const size_t W_O    = 12ull * 768 * 1536 * 2;
  const size_t W_F1GT = 12ull * 6144 * 768 * 2;
  const size_t W_F2   = 12ull * 768 * 3072 * 2;
  const bool big = ws_size >= 900ull * 1024 * 1024;
  const size_t d12 = big ? 1 : 12;

  _Float16* wQKVGh = (_Float16*)(ws + alloc(W_QKVG / d12));
  _Float16* wQKVGl = (_Float16*)(ws + alloc(W_QKVG / d12));
  _Float16* wOh    = (_Float16*)(ws + alloc(W_O    / d12));
  _Float16* wOl    = (_Float16*)(ws + alloc(W_O    / d12));
  _Float16* wF1GTh = (_Float16*)(ws + alloc(W_F1GT / d12));
  _Float16* wF1GTl = (_Float16*)(ws + alloc(W_F1GT / d12));
  _Float16* wF2h   = (_Float16*)(ws + alloc(W_F2   / d12));
  _Float16* wF2l   = (_Float16*)(ws + alloc(W_F2   / d12));

  float*    x    = (float*)(ws + alloc((size_t)BS * DMOD * 4));
  _Float16* hbfH = (_Float16*)(ws + alloc((size_t)BS * DMOD * 2));
  _Float16* hbfL = (_Float16*)(ws + alloc((size_t)BS * DMOD * 2));
  float*    cbuf = (float*)(ws + alloc((size_t)BS * 6144 * 4));   // fused GEMM out
  char*     regB = ws + alloc(6ull * BS * DKH * NH * 2 * 3);
  float*    ao   = (float*)(ws + alloc((size_t)BS * DVAL * 4));
  float*    accb = (float*)(ws + alloc((size_t)BS * DVAL * 4 + 48ull * SEQ * 4)); // + dsacc
  float*    dsacc = accb + (size_t)BS * DVAL;
  float*    pooled = (float*)(ws + alloc(4 * DMOD * 4));

  _Float16* qrbH = (_Float16*)regB;
  _Float16* qrbL = (_Float16*)(regB + 6291456);
  _Float16* krbH = (_Float16*)(regB + 12582912);
  _Float16* krbL = (_Float16*)(regB + 18874368);
  _Float16* vtb  = (_Float16*)(regB + 25165824);
  _Float16* ogbH = (_Float16*)regB;                 // alias (post-attn)
  _Float16* ogbL = (_Float16*)(regB + 12582912);
  _Float16* ffnbH = (_Float16*)regB;                // alias (post-wo)
  _Float16* ffnbL = (_Float16*)(regB + 25165824);

  dim3 tb(32, 8);
  const long lsDD = 768l * 768, lsDV = 768l * 1536, lsDF = 768l * 3072;
  const long oQKVG = 4608l * 768, oO = 768l * 1536, oF1 = 6144l * 768, oF2 = 768l * 3072;

  if (big) {
    wcvt_kernel<<<dim3(24, 24, 12), tb, 0, stream>>>(wq,   wQKVGh, wQKVGl, 768, 768,  lsDD, oQKVG, 0);
    wcvt_kernel<<<dim3(24, 24, 12), tb, 0, stream>>>(wk,   wQKVGh, wQKVGl, 768, 768,  lsDD, oQKVG, 768);
    wcvt_kernel<<<dim3(48, 24, 12), tb, 0, stream>>>(wv,   wQKVGh, wQKVGl, 768, 1536, lsDV, oQKVG, 1536);
    wcvt_kernel<<<dim3(48, 24, 12), tb, 0, stream>>>(wg,   wQKVGh, wQKVGl, 768, 1536, lsDV, oQKVG, 3072);
    wcvt_kernel<<<dim3(24, 48, 12), tb, 0, stream>>>(wo,   wOh,    wOl,    1536, 768, lsDV, oO,    0);
    wcvt_kernel<<<dim3(96, 24, 12), tb, 0, stream>>>(fc1,  wF1GTh, wF1GTl, 768, 3072, lsDF, oF1,   0);
    wcvt_kernel<<<dim3(96, 24, 12), tb, 0, stream>>>(gate, wF1GTh, wF1GTl, 768, 3072, lsDF, oF1,   3072);
    wcvt_kernel<<<dim3(24, 96, 12), tb, 0, stream>>>(fc2,  wF2h,   wF2l,   3072, 768, lsDF, oF2,   0);
  }

  embed_kernel<<<BS, 192, 0, stream>>>(ids, emb, x);

  for (int l = 0; l < 12; ++l) {
    const _Float16 *Wqkh, *Wqkl, *Woh_, *Wol_, *Wfh, *Wfl, *W2h, *W2l;
    if (big) {
      Wqkh = wQKVGh + (size_t)l * oQKVG;  Wqkl = wQKVGl + (size_t)l * oQKVG;
      Woh_ = wOh    + (size_t)l * oO;     Wol_ = wOl    + (size_t)l * oO;
      Wfh  = wF1GTh + (size_t)l * oF1;    Wfl  = wF1GTl + (size_t)l * oF1;
      W2h  = wF2h   + (size_t)l * oF2;    W2l  = wF2l   + (size_t)l * oF2;
    } else {
      wcvt_kernel<<<dim3(24, 24, 1), tb, 0, stream>>>(wq   + (size_t)l * lsDD, wQKVGh, wQKVGl, 768, 768,  0, 0, 0);
      wcvt_kernel<<<dim3(24, 24, 1), tb, 0, stream>>>(wk   + (size_t)l * lsDD, wQKVGh, wQKVGl, 768, 768,  0, 0, 768);
      wcvt_kernel<<<dim3(48, 24, 1), tb, 0, stream>>>(wv   + (size_t)l * lsDV, wQKVGh, wQKVGl, 768, 1536, 0, 0, 1536);
      wcvt_kernel<<<dim3(48, 24, 1), tb, 0, stream>>>(wg   + (size_t)l * lsDV, wQKVGh, wQKVGl, 768, 1536, 0, 0, 3072);
      wcvt_kernel<<<dim3(24, 48, 1), tb, 0, stream>>>(wo   + (size_t)l * lsDV, wOh,    wOl,    1536, 768, 0, 0, 0);
      wcvt_kernel<<<dim3(96, 24, 1), tb, 0, stream>>>(fc1  + (size_t)l * lsDF, wF1GTh, wF1GTl, 768, 3072, 0, 0, 0);
      wcvt_kernel<<<dim3(96, 24, 1), tb, 0, stream>>>(gate + (size_t)l * lsDF, wF1GTh, wF1GTl, 768, 3072, 0, 0, 3072);
      wcvt_kernel<<<dim3(24, 96, 1), tb, 0, stream>>>(fc2  + (size_t)l * lsDF, wF2h,   wF2l,   3072, 768, 0, 0, 0);
      Wqkh = wQKVGh; Wqkl = wQKVGl; Woh_ = wOh; Wol_ = wOl;
      Wfh = wF1GTh; Wfl = wF1GTl; W2h = wF2h; W2l = wF2l;
    }

    ln_hl_kernel<<<BS, 256, 0, stream>>>(x, ln1g + l * 768, ln1b + l * 768, hbfH, hbfL);
    gemm_bt<128><<<36 * 32, 256, 0, stream>>>(hbfH, hbfL, Wqkh, Wqkl, cbuf, nullptr, 36, 768, 4608);
    prep_qk_kernel<<<BS, 384, 0, stream>>>(cbuf, 4608, qrbH, qrbL, krbH, krbL);
    vtrans_kernel<<<768, 256, 0, stream>>>(cbuf + 1536, 4608, vtb);
    hipMemsetAsync(accb, 0, (size_t)BS * DVAL * 4 + 48ull * SEQ * 4, stream);
    attn_part<<<dim3(20, 48), 256, 0, stream>>>(qrbH, qrbL, krbH, krbL, vtb, accb, dsacc);
    attn_norm<<<dim3(32, 48), 256, 0, stream>>>(accb, dsacc, ao);
    silu_mul_kernel<<<1024, 256, 0, stream>>>(cbuf + 3072, 1152, ao, 384, ogbH, ogbL,
                                              384, BS * 384);
    gemm_bt<64><<<6 * 64, 256, 0, stream>>>(ogbH, ogbL, Woh_, Wol_, x, x, 6, 1536, 768);
    ln_hl_kernel<<<BS, 256, 0, stream>>>(x, ln2g + l * 768, ln2b + l * 768, hbfH, hbfL);
    gemm_bt<128><<<48 * 32, 256, 0, stream>>>(hbfH, hbfL, Wfh, Wfl, cbuf, nullptr, 48, 768, 6144);
    silu_mul_kernel<<<2048, 256, 0, stream>>>(cbuf, 1536, cbuf + 3072, 1536, ffnbH, ffnbL,
                                              768, BS * 768);
    gemm_bt<64><<<6 * 64, 256, 0, stream>>>(ffnbH, ffnbL, W2h, W2l, x, x, 6, 3072, 768);
  }

  float* xf = cbuf;
  ln_kernel<<<BS, 256, 0, stream>>>(x, lnfg, lnfb, xf);
  pool_kernel<<<dim3(3, 4), 256, 0, stream>>>(xf, pooled);
  clf_kernel<<<4, 128, 0, stream>>>(pooled, clfw, clfb, out);
}

// Round 8
// 9816.092 us; speedup vs baseline: 1.3375x; 1.0346x over previous
//
#include <hip/hip_runtime.h>
#include <cstdint>
#include <cstddef>

// ---------- types ----------
typedef float     f32x4 __attribute__((ext_vector_type(4)));
typedef _Float16  f16x8 __attribute__((ext_vector_type(8)));
typedef _Float16  f16x4 __attribute__((ext_vector_type(4)));
typedef _Float16  f16x2 __attribute__((ext_vector_type(2)));

#define GLD16(g, l)                                                            \
  __builtin_amdgcn_global_load_lds(                                           \
      (const __attribute__((address_space(1))) void*)(g),                     \
      (__attribute__((address_space(3))) void*)(l), 16, 0, 0)

// ---------- constants ----------
#define BQ    4
#define SEQ   1024
#define DMOD  768
#define NH    12
#define DKH   64
#define DVH   128
#define DVAL  1536
#define DFFN  3072
#define BS    4096   /* BQ*SEQ */

// =====================================================================
// weight transpose + f32->f16 hi/lo split into fused layout.
// mode 0: outrow = row_off + n  (linear)
// mode 1: fc1 interleave : outrow = (n>>6)*128 + ((n>>5)&1)*64 + (n&31)
// mode 2: gate interleave: outrow = (n>>6)*128 + ((n>>5)&1)*64 + 32 + (n&31)
// (modes 1/2 put fc1 cols c and gate cols c in the same 128-row tile so the
//  GEMM epilogue computes silu(f1)*gate lane-locally)
// =====================================================================
__global__ void wcvt_kernel(const float* __restrict__ win, _Float16* __restrict__ whi,
                            _Float16* __restrict__ wlo, int K, int N,
                            long in_ls, long out_ls, int row_off, int mode)
{
  __shared__ float tle[32][33];
  size_t ib = (size_t)blockIdx.z * in_ls;
  size_t ob = (size_t)blockIdx.z * out_ls;
  int k0 = blockIdx.y * 32, n0 = blockIdx.x * 32;
  int tx = threadIdx.x, ty = threadIdx.y;
#pragma unroll
  for (int i = 0; i < 4; ++i)
    tle[ty + 8*i][tx] = win[ib + (size_t)(k0 + ty + 8*i) * N + n0 + tx];
  __syncthreads();
#pragma unroll
  for (int i = 0; i < 4; ++i) {
    float v = tle[tx][ty + 8*i];
    _Float16 h = (_Float16)v;
    int n = n0 + ty + 8*i;
    int orow;
    if (mode == 0)      orow = row_off + n;
    else if (mode == 1) orow = (n >> 6) * 128 + ((n >> 5) & 1) * 64 + (n & 31);
    else                orow = (n >> 6) * 128 + ((n >> 5) & 1) * 64 + 32 + (n & 31);
    size_t idx = ob + (size_t)orow * K + k0 + tx;
    whi[idx] = h;
    wlo[idx] = (_Float16)((v - (float)h) * 1024.0f);
  }
}

// =====================================================================
// embedding gather
// =====================================================================
__global__ void embed_kernel(const int* __restrict__ ids, const float* __restrict__ emb,
                             float* __restrict__ x)
{
  int tok = blockIdx.x;
  int id  = ids[tok];
  const float4* s = (const float4*)(emb + (size_t)id * DMOD);
  float4*       d = (float4*)(x + (size_t)tok * DMOD);
  d[threadIdx.x] = s[threadIdx.x];   // block = 192 threads
}

// =====================================================================
// layernorm over 768 -> f32 out (final LN)
// =====================================================================
__global__ __launch_bounds__(256) void ln_kernel(const float* __restrict__ x,
                                                 const float* __restrict__ g,
                                                 const float* __restrict__ bta,
                                                 float* __restrict__ out)
{
  int row = blockIdx.x;
  const float* xr = x + (size_t)row * DMOD;
  int t = threadIdx.x;
  float v0 = xr[t], v1 = xr[t + 256], v2 = xr[t + 512];
  float s  = v0 + v1 + v2;
  float sq = v0*v0 + v1*v1 + v2*v2;
#pragma unroll
  for (int m = 1; m < 64; m <<= 1) { s += __shfl_xor(s, m); sq += __shfl_xor(sq, m); }
  __shared__ float red[8];
  int wv = t >> 6, ln_ = t & 63;
  if (ln_ == 0) { red[wv] = s; red[wv + 4] = sq; }
  __syncthreads();
  s  = red[0] + red[1] + red[2] + red[3];
  sq = red[4] + red[5] + red[6] + red[7];
  float mu = s * (1.f / DMOD);
  float rs = rsqrtf(sq * (1.f / DMOD) - mu * mu + 1e-5f);
  out[(size_t)row * DMOD + t      ] = (v0 - mu) * rs * g[t      ] + bta[t      ];
  out[(size_t)row * DMOD + t + 256] = (v1 - mu) * rs * g[t + 256] + bta[t + 256];
  out[(size_t)row * DMOD + t + 512] = (v2 - mu) * rs * g[t + 512] + bta[t + 512];
}

// =====================================================================
// layernorm over 768 -> f16 hi/lo pair (GEMM A-operand)
// =====================================================================
__global__ __launch_bounds__(256) void ln_hl_kernel(const float* __restrict__ x,
                                                    const float* __restrict__ g,
                                                    const float* __restrict__ bta,
                                                    _Float16* __restrict__ oh,
                                                    _Float16* __restrict__ ol)
{
  int row = blockIdx.x;
  const float* xr = x + (size_t)row * DMOD;
  int t = threadIdx.x;
  float v0 = xr[t], v1 = xr[t + 256], v2 = xr[t + 512];
  float s  = v0 + v1 + v2;
  float sq = v0*v0 + v1*v1 + v2*v2;
#pragma unroll
  for (int m = 1; m < 64; m <<= 1) { s += __shfl_xor(s, m); sq += __shfl_xor(sq, m); }
  __shared__ float red[8];
  int wv = t >> 6, ln_ = t & 63;
  if (ln_ == 0) { red[wv] = s; red[wv + 4] = sq; }
  __syncthreads();
  s  = red[0] + red[1] + red[2] + red[3];
  sq = red[4] + red[5] + red[6] + red[7];
  float mu = s * (1.f / DMOD);
  float rs = rsqrtf(sq * (1.f / DMOD) - mu * mu + 1e-5f);
#pragma unroll
  for (int q = 0; q < 3; ++q) {
    int c = t + q * 256;
    float y = (xr[c] - mu) * rs * g[c] + bta[c];
    _Float16 h = (_Float16)y;
    size_t idx = (size_t)row * DMOD + c;
    oh[idx] = h;
    ol[idx] = (_Float16)((y - (float)h) * 1024.0f);
  }
}

// =====================================================================
// GEMM: (Ah + Al/1024)[M][K] @ (Bh + Bl/1024)[NTOT][K]^T, 3-term split.
// BMx128 tile, BK=32, 4 waves, global_load_lds + XOR swizzle, XCD swizzle.
// MODE 0: C[M][ldc] f32 (opt += R).
// MODE 1: silu-gate epilogue (fc1/gate interleaved weights): j0,1 = f1,
//         j2,3 = gate of same cols; writes f16 hi/lo pair at ldc_out=3072.
// =====================================================================
template<int BM, int MODE>
__global__ __launch_bounds__(256) void gemm_bt(const _Float16* __restrict__ Ah,
                                               const _Float16* __restrict__ Al,
                                               const _Float16* __restrict__ Bh,
                                               const _Float16* __restrict__ Bl,
                                               float* __restrict__ C,
                                               const float* __restrict__ R,
                                               _Float16* __restrict__ OH,
                                               _Float16* __restrict__ OL,
                                               int nbx, int K, int ldc)
{
  constexpr int RI = BM / 32;           // row fragments per wave
  __shared__ char sAh[BM * 64];
  __shared__ char sAl[BM * 64];
  __shared__ char sBh[8192];
  __shared__ char sBl[8192];
  const int tid = threadIdx.x, lane = tid & 63, w = tid >> 6;

  // bijective XCD swizzle over the 1D grid
  int nwg = gridDim.x, bid = blockIdx.x;
  int qq = nwg >> 3, rr = nwg & 7;
  int xc = bid & 7, ix = bid >> 3;
  int wg = (xc < rr ? xc * (qq + 1) : rr * (qq + 1) + (xc - rr) * qq) + ix;
  int bx = wg % nbx, by = wg / nbx;

  const int m0 = by * BM, n0 = bx * 128;
  const int wm = (w >> 1) * (BM / 2), wn = (w & 1) * 64;
  const int lhi = lane >> 4, llo = lane & 15;

  const f32x4 fz = {0.f, 0.f, 0.f, 0.f};
  f32x4 accH[RI][4], accM[RI][4];
#pragma unroll
  for (int i = 0; i < RI; ++i)
#pragma unroll
    for (int j = 0; j < 4; ++j) { accH[i][j] = fz; accM[i][j] = fz; }

  for (int k0 = 0; k0 < K; k0 += 32) {
    __syncthreads();
#pragma unroll
    for (int i = 0; i < BM / 64; ++i) {           // A planes
      int off = w * (BM * 16) + i * 1024 + lane * 16;
      int r = off >> 6, c = (off >> 4) & 3;
      size_t go = (size_t)r * K + ((c ^ (r & 3)) << 3);
      GLD16(Ah + (size_t)m0 * K + k0 + go, sAh + w * (BM * 16) + i * 1024);
      GLD16(Al + (size_t)m0 * K + k0 + go, sAl + w * (BM * 16) + i * 1024);
    }
#pragma unroll
    for (int i = 0; i < 2; ++i) {                 // B planes
      int off = w * 2048 + i * 1024 + lane * 16;
      int r = off >> 6, c = (off >> 4) & 3;
      size_t go = (size_t)r * K + ((c ^ (r & 3)) << 3);
      GLD16(Bh + (size_t)n0 * K + k0 + go, sBh + w * 2048 + i * 1024);
      GLD16(Bl + (size_t)n0 * K + k0 + go, sBl + w * 2048 + i * 1024);
    }
    __syncthreads();

    f16x8 ah[RI], al[RI], bh[4], bl[4];
#pragma unroll
    for (int r = 0; r < RI; ++r) {
      int ra = wm + r * 16 + llo;
      int sa = ra * 64 + ((lhi ^ (ra & 3)) << 4);
      ah[r] = *(const f16x8*)(sAh + sa);
      al[r] = *(const f16x8*)(sAl + sa);
    }
#pragma unroll
    for (int r = 0; r < 4; ++r) {
      int rb = wn + r * 16 + llo;
      int sb = rb * 64 + ((lhi ^ (rb & 3)) << 4);
      bh[r] = *(const f16x8*)(sBh + sb);
      bl[r] = *(const f16x8*)(sBl + sb);
    }
#pragma unroll
    for (int i = 0; i < RI; ++i)
#pragma unroll
      for (int j = 0; j < 4; ++j) {
        accH[i][j] = __builtin_amdgcn_mfma_f32_16x16x32_f16(ah[i], bh[j], accH[i][j], 0, 0, 0);
        accM[i][j] = __builtin_amdgcn_mfma_f32_16x16x32_f16(ah[i], bl[j], accM[i][j], 0, 0, 0);
        accM[i][j] = __builtin_amdgcn_mfma_f32_16x16x32_f16(al[i], bh[j], accM[i][j], 0, 0, 0);
      }
  }

  if (MODE == 0) {
#pragma unroll
    for (int i = 0; i < RI; ++i)
#pragma unroll
      for (int j = 0; j < 4; ++j)
#pragma unroll
        for (int rg = 0; rg < 4; ++rg) {
          int m = m0 + wm + i * 16 + lhi * 4 + rg;
          int n = n0 + wn + j * 16 + llo;
          size_t idx = (size_t)m * ldc + n;
          float v = accH[i][j][rg] + accM[i][j][rg] * (1.0f / 1024.0f);
          if (R) v += R[idx];
          C[idx] = v;
        }
  } else {
    // silu(f1)*gate, f16 hi/lo out at col = bx*64 + wn*32 + j*16 + llo
#pragma unroll
    for (int i = 0; i < RI; ++i)
#pragma unroll
      for (int j = 0; j < 2; ++j)
#pragma unroll
        for (int rg = 0; rg < 4; ++rg) {
          int m = m0 + wm + i * 16 + lhi * 4 + rg;
          int n = (n0 >> 1) + (wn >> 1) + j * 16 + llo;
          float f1 = accH[i][j][rg]     + accM[i][j][rg]     * (1.0f / 1024.0f);
          float gv = accH[i][j + 2][rg] + accM[i][j + 2][rg] * (1.0f / 1024.0f);
          float y = f1 / (1.f + expf(-f1)) * gv;
          _Float16 h = (_Float16)y;
          size_t idx = (size_t)m * 3072 + n;
          OH[idx] = h;
          OL[idx] = (_Float16)((y - (float)h) * 1024.f);
        }
  }
}

// =====================================================================
// theta-shift q,k (f32 strided in fused C) -> f16 hi/lo [B][H][S][DK]
// =====================================================================
__global__ void prep_qk_kernel(const float* __restrict__ qk, int ld,
                               _Float16* __restrict__ qrH, _Float16* __restrict__ qrL,
                               _Float16* __restrict__ krH, _Float16* __restrict__ krL)
{
  int row = blockIdx.x;                 // b*S + s
  int s = row & (SEQ - 1), b = row >> 10;
  int pi = threadIdx.x;                 // 0..383
  int d0 = pi * 2;
  int h = d0 >> 6;
  int i = d0 & 63;
  int j = i >> 1;
  float ang = exp2f(-(float)j * (13.287712379549449f / 31.f)); // 10000^{-j/31}
  float arg = (float)s * ang;
  float cc = cosf(arg), sn = sinf(arg);
  size_t src = (size_t)row * ld + d0;
  size_t dst = ((size_t)(b * NH + h) * SEQ + s) * DKH + i;

  float q0 = qk[src], q1 = qk[src + 1];
  float rq0 = q0 * cc - q1 * sn;
  float rq1 = q1 * cc + q0 * sn;
  _Float16 h0 = (_Float16)rq0, h1 = (_Float16)rq1;
  qrH[dst]     = h0; qrL[dst]     = (_Float16)((rq0 - (float)h0) * 1024.f);
  qrH[dst + 1] = h1; qrL[dst + 1] = (_Float16)((rq1 - (float)h1) * 1024.f);

  float k0 = qk[src + 768], k1 = qk[src + 769];
  float rk0 = k0 * cc - k1 * sn;
  float rk1 = k1 * cc + k0 * sn;
  _Float16 g0 = (_Float16)rk0, g1 = (_Float16)rk1;
  krH[dst]     = g0; krL[dst]     = (_Float16)((rk0 - (float)g0) * 1024.f);
  krH[dst + 1] = g1; krL[dst + 1] = (_Float16)((rk1 - (float)g1) * 1024.f);
}

// =====================================================================
// v transpose: f32 strided -> f16 [B][H][128][S]
// =====================================================================
__global__ __launch_bounds__(256) void vtrans_kernel(const float* __restrict__ vsrc, int ld,
                                                     _Float16* __restrict__ vt)
{
  __shared__ _Float16 tl[128][65];
  int bh = blockIdx.x >> 4;
  int s0 = (blockIdx.x & 15) << 6;
  int b = bh / NH, h = bh % NH;
  int t = threadIdx.x;
#pragma unroll
  for (int it = 0; it < 32; ++it) {
    int idx = it * 256 + t;
    int sl = idx >> 7, d = idx & 127;
    tl[d][sl] = (_Float16)vsrc[(size_t)(b * SEQ + s0 + sl) * ld + h * DVH + d];
  }
  __syncthreads();
#pragma unroll
  for (int it = 0; it < 32; ++it) {
    int idx = it * 256 + t;
    int d = idx >> 6, sl = idx & 63;
    vt[((size_t)bh * DVH + d) * SEQ + s0 + sl] = tl[d][sl];
  }
}

// =====================================================================
// retention stage 1: per (bh, rb, ct-chunk<=2): QK^T(3-term) -> decay ->
// PV partial; atomicAdd into accbuf[bh][s][dv] and dsacc[bh][s].
// =====================================================================
__global__ __launch_bounds__(256) void attn_part(const _Float16* __restrict__ qrH_,
                                                 const _Float16* __restrict__ qrL_,
                                                 const _Float16* __restrict__ krH_,
                                                 const _Float16* __restrict__ krL_,
                                                 const _Float16* __restrict__ vt,
                                                 float* __restrict__ accb,
                                                 float* __restrict__ dsacc)
{
  static const int RBtab[20] = {0,1,2,2,3,3,4,4,4,5,5,5,6,6,6,6,7,7,7,7};
  static const int C0tab[20] = {0,0,0,2,0,2,0,2,4,0,2,4,0,2,4,6,0,2,4,6};
  __shared__ char pbuf[32768];          // 4 waves x [32][128] f16, XOR-swizzled
  const int tid = threadIdx.x, lane = tid & 63, w = tid >> 6;
  const int rb = RBtab[blockIdx.x], c0 = C0tab[blockIdx.x];
  const int bh = blockIdx.y;            // 0..47
  const int h = bh % NH;
  const int wrow0 = rb * 128 + w * 32;
  const int lhi = lane >> 4, llo = lane & 15;

  const _Float16* qbhH = qrH_ + (size_t)bh * SEQ * DKH;
  const _Float16* qbhL = qrL_ + (size_t)bh * SEQ * DKH;
  const _Float16* kbhH = krH_ + (size_t)bh * SEQ * DKH;
  const _Float16* kbhL = krL_ + (size_t)bh * SEQ * DKH;
  const _Float16* vbh  = vt   + (size_t)bh * DVH * SEQ;

  const float lg = log1pf(-exp2f(-(float)(5 + h)));   // ln(gamma_h)
  const float den_lg = expm1f(lg);                    // gamma - 1

  float invn[2][4];
#pragma unroll
  for (int rf = 0; rf < 2; ++rf)
#pragma unroll
    for (int rg = 0; rg < 4; ++rg) {
      int n = wrow0 + rf * 16 + lhi * 4 + rg;
      float sumD = expm1f((float)(n + 1) * lg) / den_lg;  // (1-g^{n+1})/(1-g)
      invn[rf][rg] = rsqrtf(sumD) * 0.125f;               // fold DK^-0.5
    }

  float gm[8];
#pragma unroll
  for (int fc = 0; fc < 8; ++fc)
    gm[fc] = expf(-(float)(fc * 16 + llo) * lg);

  f16x8 qaH[2][2], qaL[2][2];
#pragma unroll
  for (int rf = 0; rf < 2; ++rf)
#pragma unroll
    for (int kt = 0; kt < 2; ++kt) {
      size_t qo = (size_t)(wrow0 + rf * 16 + llo) * DKH + kt * 32 + lhi * 8;
      qaH[rf][kt] = *(const f16x8*)(qbhH + qo);
      qaL[rf][kt] = *(const f16x8*)(qbhL + qo);
    }

  const f32x4 fz = {0.f, 0.f, 0.f, 0.f};
  f32x4 acc[2][8];
#pragma unroll
  for (int i = 0; i < 2; ++i)
#pragma unroll
    for (int j = 0; j < 8; ++j) acc[i][j] = fz;
  float dsum[2][4] = {{0, 0, 0, 0}, {0, 0, 0, 0}};

  const int ctend = (c0 + 1 < rb) ? c0 + 1 : rb;
  for (int ct = c0; ct <= ctend; ++ct) {
    const bool diag = (ct == rb);
    float fn[2][4];
#pragma unroll
    for (int rf = 0; rf < 2; ++rf)
#pragma unroll
      for (int rg = 0; rg < 4; ++rg) {
        int n = wrow0 + rf * 16 + lhi * 4 + rg;
        fn[rf][rg] = expf((float)(n - ct * 128) * lg) * invn[rf][rg];
      }

#pragma unroll
    for (int fc = 0; fc < 8; ++fc) {
      f32x4 pH[2] = {fz, fz}, pM[2] = {fz, fz};
#pragma unroll
      for (int kt = 0; kt < 2; ++kt) {
        size_t kro = (size_t)(ct * 128 + fc * 16 + llo) * DKH + kt * 32 + lhi * 8;
        f16x8 kbH = *(const f16x8*)(kbhH + kro);
        f16x8 kbL = *(const f16x8*)(kbhL + kro);
        pH[0] = __builtin_amdgcn_mfma_f32_16x16x32_f16(qaH[0][kt], kbH, pH[0], 0, 0, 0);
        pH[1] = __builtin_amdgcn_mfma_f32_16x16x32_f16(qaH[1][kt], kbH, pH[1], 0, 0, 0);
        pM[0] = __builtin_amdgcn_mfma_f32_16x16x32_f16(qaL[0][kt], kbH, pM[0], 0, 0, 0);
        pM[1] = __builtin_amdgcn_mfma_f32_16x16x32_f16(qaL[1][kt], kbH, pM[1], 0, 0, 0);
        pM[0] = __builtin_amdgcn_mfma_f32_16x16x32_f16(qaH[0][kt], kbL, pM[0], 0, 0, 0);
        pM[1] = __builtin_amdgcn_mfma_f32_16x16x32_f16(qaH[1][kt], kbL, pM[1], 0, 0, 0);
      }
#pragma unroll
      for (int rf = 0; rf < 2; ++rf)
#pragma unroll
        for (int rg = 0; rg < 4; ++rg) {
          float pv = (pH[rf][rg] + pM[rf][rg] * (1.f / 1024.f)) * fn[rf][rg] * gm[fc];
          if (diag) {
            int e = (wrow0 + rf * 16 + lhi * 4 + rg) - (ct * 128 + fc * 16 + llo);
            if (e < 0) pv = 0.f;
          }
          dsum[rf][rg] += fabsf(pv);
          int prow = rf * 16 + lhi * 4 + rg;
          int byte = (w << 13) + prow * 256 + (fc * 16 + llo) * 2;
          byte ^= (prow & 7) << 4;
          *(_Float16*)(pbuf + byte) = (_Float16)pv;
        }
    }
    // each wave reads only its own pbuf slice — no barrier needed

    f16x8 pa[2][4];
#pragma unroll
    for (int rf2 = 0; rf2 < 2; ++rf2)
#pragma unroll
      for (int kt = 0; kt < 4; ++kt) {
        int prow = rf2 * 16 + llo;
        int byte = (w << 13) + prow * 256 + kt * 64 + lhi * 16;
        byte ^= (prow & 7) << 4;
        pa[rf2][kt] = *(const f16x8*)(pbuf + byte);
      }
#pragma unroll
    for (int fd = 0; fd < 8; ++fd)
#pragma unroll
      for (int kt = 0; kt < 4; ++kt) {
        f16x8 vb = *(const f16x8*)(vbh + (size_t)(fd * 16 + llo) * SEQ + ct * 128 + kt * 32 + lhi * 8);
        acc[0][fd] = __builtin_amdgcn_mfma_f32_16x16x32_f16(pa[0][kt], vb, acc[0][fd], 0, 0, 0);
        acc[1][fd] = __builtin_amdgcn_mfma_f32_16x16x32_f16(pa[1][kt], vb, acc[1][fd], 0, 0, 0);
      }
  }

  float* ab = accb + (size_t)bh * SEQ * DVH;
#pragma unroll
  for (int rf = 0; rf < 2; ++rf)
#pragma unroll
    for (int rg = 0; rg < 4; ++rg) {
      float d = dsum[rf][rg];
      d += __shfl_xor(d, 1); d += __shfl_xor(d, 2);
      d += __shfl_xor(d, 4); d += __shfl_xor(d, 8);
      int row = wrow0 + rf * 16 + lhi * 4 + rg;
      if (llo == 0) atomicAdd(&dsacc[bh * SEQ + row], d);
#pragma unroll
      for (int fd = 0; fd < 8; ++fd)
        atomicAdd(&ab[(size_t)row * DVH + fd * 16 + llo], acc[rf][fd][rg]);
    }
}

// =====================================================================
// retention stage 2: row-normalize + group-norm + silu(g)*o fused,
// writes ogb f16 hi/lo [B*S][1536]
// =====================================================================
__global__ __launch_bounds__(256) void attn_norm(const float* __restrict__ accb,
                                                 const float* __restrict__ dsacc,
                                                 const float* __restrict__ gsrc, int ldg,
                                                 _Float16* __restrict__ oh,
                                                 _Float16* __restrict__ ol)
{
  int bh = blockIdx.y, h = bh % NH, b = bh / NH;
  int s0 = blockIdx.x * 32;
  int lane = threadIdx.x & 63, w = threadIdx.x >> 6;
  const float* ab = accb + ((size_t)bh * SEQ + s0) * DVH;
#pragma unroll
  for (int i = 0; i < 8; ++i) {
    int r = w * 8 + i;
    size_t row = (size_t)(b * SEQ + s0 + r);
    float2 v = *(const float2*)(ab + (size_t)r * DVH + lane * 2);
    float inv = 1.f / fmaxf(dsacc[bh * SEQ + s0 + r], 1.f);
    v.x *= inv; v.y *= inv;
    float ss = v.x * v.x + v.y * v.y;
#pragma unroll
    for (int m = 1; m < 64; m <<= 1) ss += __shfl_xor(ss, m);
    float rs = rsqrtf(ss * (1.f / 128.f) + 1e-5f);
    float o0 = v.x * rs, o1 = v.y * rs;
    float2 g = *(const float2*)(gsrc + row * ldg + h * DVH + lane * 2);
    float y0 = g.x / (1.f + expf(-g.x)) * o0;
    float y1 = g.y / (1.f + expf(-g.y)) * o1;
    _Float16 h0 = (_Float16)y0, h1 = (_Float16)y1;
    f16x2 vh = {h0, h1};
    f16x2 vl = {(_Float16)((y0 - (float)h0) * 1024.f),
                (_Float16)((y1 - (float)h1) * 1024.f)};
    size_t oidx = row * DVAL + h * DVH + lane * 2;
    *(f16x2*)(oh + oidx) = vh;
    *(f16x2*)(ol + oidx) = vl;
  }
}

// =====================================================================
// mean pool over S
// =====================================================================
__global__ void pool_kernel(const float* __restrict__ xf, float* __restrict__ pooled)
{
  int d = blockIdx.x * 256 + threadIdx.x;   // grid.x = 3
  int b = blockIdx.y;
  float acc = 0.f;
  for (int s = 0; s < SEQ; ++s) acc += xf[((size_t)(b * SEQ + s)) * DMOD + d];
  pooled[b * DMOD + d] = acc * (1.f / SEQ);
}

// =====================================================================
// classifier
// =====================================================================
__global__ void clf_kernel(const float* __restrict__ pooled, const float* __restrict__ cw,
                           const float* __restrict__ cb, float* __restrict__ out)
{
  int b = blockIdx.x, c = threadIdx.x;
  if (c < 100) {
    float acc = cb[c];
    for (int d = 0; d < DMOD; ++d) acc += pooled[b * DMOD + d] * cw[d * 100 + c];
    out[b * 100 + c] = acc;
  }
}

// =====================================================================
// host
// =====================================================================
extern "C" void kernel_launch(void* const* d_in, const int* in_sizes, int n_in,
                              void* d_out, int out_size, void* d_ws, size_t ws_size,
                              hipStream_t stream)
{
  const int*   ids  = (const int*)d_in[0];
  const float* emb  = (const float*)d_in[1];
  const float* wq   = (const float*)d_in[2];
  const float* wk   = (const float*)d_in[3];
  const float* wv   = (const float*)d_in[4];
  const float* wg   = (const float*)d_in[5];
  const float* wo   = (const float*)d_in[6];
  const float* ln1g = (const float*)d_in[7];
  const float* ln1b = (const float*)d_in[8];
  const float* ln2g = (const float*)d_in[9];
  const float* ln2b = (const float*)d_in[10];
  const float* fc1  = (const float*)d_in[11];
  const float* gate = (const float*)d_in[12];
  const float* fc2  = (const float*)d_in[13];
  const float* lnfg = (const float*)d_in[14];
  const float* lnfb = (const float*)d_in[15];
  const float* clfw = (const float*)d_in[16];
  const float* clfb = (const float*)d_in[17];
  float* out = (float*)d_out;

  char* ws = (char*)d_ws;
  size_t off = 0;
  auto alloc = [&](size_t bytes) {
    size_t r = off;
    off = (off + bytes + 255) & ~(size_t)255;
    return r;
  };

  const size_t W_QKVG = 12ull * 4608 * 768 * 2;
  const size_t W_O    = 12ull * 768 * 1536 * 2;
  const size_t W_F1GT = 12ull * 6144 * 768 * 2;
  const size_t W_F2   = 12ull * 768 * 3072 * 2;
  const bool big = ws_size >= 780ull * 1024 * 1024;
  const size_t d12 = big ? 1 : 12;

  _Float16* wQKVGh = (_Float16*)(ws + alloc(W_QKVG / d12));
  _Float16* wQKVGl = (_Float16*)(ws + alloc(W_QKVG / d12));
  _Float16* wOh    = (_Float16*)(ws + alloc(W_O    / d12));
  _Float16* wOl    = (_Float16*)(ws + alloc(W_O    / d12));
  _Float16* wF1GTh = (_Float16*)(ws + alloc(W_F1GT / d12));
  _Float16* wF1GTl = (_Float16*)(ws + alloc(W_F1GT / d12));
  _Float16* wF2h   = (_Float16*)(ws + alloc(W_F2   / d12));
  _Float16* wF2l   = (_Float16*)(ws + alloc(W_F2   / d12));

  float*    x    = (float*)(ws + alloc((size_t)BS * DMOD * 4));
  _Float16* hbfH = (_Float16*)(ws + alloc((size_t)BS * DMOD * 2));
  _Float16* hbfL = (_Float16*)(ws + alloc((size_t)BS * DMOD * 2));
  float*    cbuf = (float*)(ws + alloc((size_t)BS * 4608 * 4));   // qkvg GEMM out
  char*     regB = ws + alloc(8ull * 6291456);                    // 50.3 MB
  float*    accb = (float*)(ws + alloc((size_t)BS * DVAL * 4 + 48ull * SEQ * 4));
  float*    dsacc = accb + (size_t)BS * DVAL;
  float*    pooled = (float*)(ws + alloc(4 * DMOD * 4));

  _Float16* qrbH = (_Float16*)regB;
  _Float16* qrbL = (_Float16*)(regB + 6291456);
  _Float16* krbH = (_Float16*)(regB + 12582912);
  _Float16* krbL = (_Float16*)(regB + 18874368);
  _Float16* vtb  = (_Float16*)(regB + 25165824);
  _Float16* ogbH = (_Float16*)regB;                 // alias (post-attn_part)
  _Float16* ogbL = (_Float16*)(regB + 12582912);
  _Float16* ffnbH = (_Float16*)regB;                // alias (post-wo)
  _Float16* ffnbL = (_Float16*)(regB + 25165824);

  dim3 tb(32, 8);
  const long lsDD = 768l * 768, lsDV = 768l * 1536, lsDF = 768l * 3072;
  const long oQKVG = 4608l * 768, oO = 768l * 1536, oF1 = 6144l * 768, oF2 = 768l * 3072;

  if (big) {
    wcvt_kernel<<<dim3(24, 24, 12), tb, 0, stream>>>(wq,   wQKVGh, wQKVGl, 768, 768,  lsDD, oQKVG, 0,    0);
    wcvt_kernel<<<dim3(24, 24, 12), tb, 0, stream>>>(wk,   wQKVGh, wQKVGl, 768, 768,  lsDD, oQKVG, 768,  0);
    wcvt_kernel<<<dim3(48, 24, 12), tb, 0, stream>>>(wv,   wQKVGh, wQKVGl, 768, 1536, lsDV, oQKVG, 1536, 0);
    wcvt_kernel<<<dim3(48, 24, 12), tb, 0, stream>>>(wg,   wQKVGh, wQKVGl, 768, 1536, lsDV, oQKVG, 3072, 0);
    wcvt_kernel<<<dim3(24, 48, 12), tb, 0, stream>>>(wo,   wOh,    wOl,    1536, 768, lsDV, oO,    0,    0);
    wcvt_kernel<<<dim3(96, 24, 12), tb, 0, stream>>>(fc1,  wF1GTh, wF1GTl, 768, 3072, lsDF, oF1,   0,    1);
    wcvt_kernel<<<dim3(96, 24, 12), tb, 0, stream>>>(gate, wF1GTh, wF1GTl, 768, 3072, lsDF, oF1,   0,    2);
    wcvt_kernel<<<dim3(24, 96, 12), tb, 0, stream>>>(fc2,  wF2h,   wF2l,   3072, 768, lsDF, oF2,   0,    0);
  }

  embed_kernel<<<BS, 192, 0, stream>>>(ids, emb, x);

  for (int l = 0; l < 12; ++l) {
    const _Float16 *Wqkh, *Wqkl, *Woh_, *Wol_, *Wfh, *Wfl, *W2h, *W2l;
    if (big) {
      Wqkh = wQKVGh + (size_t)l * oQKVG;  Wqkl = wQKVGl + (size_t)l * oQKVG;
      Woh_ = wOh    + (size_t)l * oO;     Wol_ = wOl    + (size_t)l * oO;
      Wfh  = wF1GTh + (size_t)l * oF1;    Wfl  = wF1GTl + (size_t)l * oF1;
      W2h  = wF2h   + (size_t)l * oF2;    W2l  = wF2l   + (size_t)l * oF2;
    } else {
      wcvt_kernel<<<dim3(24, 24, 1), tb, 0, stream>>>(wq   + (size_t)l * lsDD, wQKVGh, wQKVGl, 768, 768,  0, 0, 0,    0);
      wcvt_kernel<<<dim3(24, 24, 1), tb, 0, stream>>>(wk   + (size_t)l * lsDD, wQKVGh, wQKVGl, 768, 768,  0, 0, 768,  0);
      wcvt_kernel<<<dim3(48, 24, 1), tb, 0, stream>>>(wv   + (size_t)l * lsDV, wQKVGh, wQKVGl, 768, 1536, 0, 0, 1536, 0);
      wcvt_kernel<<<dim3(48, 24, 1), tb, 0, stream>>>(wg   + (size_t)l * lsDV, wQKVGh, wQKVGl, 768, 1536, 0, 0, 3072, 0);
      wcvt_kernel<<<dim3(24, 48, 1), tb, 0, stream>>>(wo   + (size_t)l * lsDV, wOh,    wOl,    1536, 768, 0, 0, 0,    0);
      wcvt_kernel<<<dim3(96, 24, 1), tb, 0, stream>>>(fc1  + (size_t)l * lsDF, wF1GTh, wF1GTl, 768, 3072, 0, 0, 0,    1);
      wcvt_kernel<<<dim3(96, 24, 1), tb, 0, stream>>>(gate + (size_t)l * lsDF, wF1GTh, wF1GTl, 768, 3072, 0, 0, 0,    2);
      wcvt_kernel<<<dim3(24, 96, 1), tb, 0, stream>>>(fc2  + (size_t)l * lsDF, wF2h,   wF2l,   3072, 768, 0, 0, 0,    0);
      Wqkh = wQKVGh; Wqkl = wQKVGl; Woh_ = wOh; Wol_ = wOl;
      Wfh = wF1GTh; Wfl = wF1GTl; W2h = wF2h; W2l = wF2l;
    }

    ln_hl_kernel<<<BS, 256, 0, stream>>>(x, ln1g + l * 768, ln1b + l * 768, hbfH, hbfL);
    gemm_bt<128, 0><<<36 * 32, 256, 0, stream>>>(hbfH, hbfL, Wqkh, Wqkl, cbuf, nullptr,
                                                 nullptr, nullptr, 36, 768, 4608);
    prep_qk_kernel<<<BS, 384, 0, stream>>>(cbuf, 4608, qrbH, qrbL, krbH, krbL);
    vtrans_kernel<<<768, 256, 0, stream>>>(cbuf + 1536, 4608, vtb);
    hipMemsetAsync(accb, 0, (size_t)BS * DVAL * 4 + 48ull * SEQ * 4, stream);
    attn_part<<<dim3(20, 48), 256, 0, stream>>>(qrbH, qrbL, krbH, krbL, vtb, accb, dsacc);
    attn_norm<<<dim3(32, 48), 256, 0, stream>>>(accb, dsacc, cbuf + 3072, 4608, ogbH, ogbL);
    gemm_bt<64, 0><<<6 * 64, 256, 0, stream>>>(ogbH, ogbL, Woh_, Wol_, x, x,
                                               nullptr, nullptr, 6, 1536, 768);
    ln_hl_kernel<<<BS, 256, 0, stream>>>(x, ln2g + l * 768, ln2b + l * 768, hbfH, hbfL);
    gemm_bt<128, 1><<<48 * 32, 256, 0, stream>>>(hbfH, hbfL, Wfh, Wfl, nullptr, nullptr,
                                                 ffnbH, ffnbL, 48, 768, 0);
    gemm_bt<64, 0><<<6 * 64, 256, 0, stream>>>(ffnbH, ffnbL, W2h, W2l, x, x,
                                               nullptr, nullptr, 6, 3072, 768);
  }

  float* xf = cbuf;
  ln_kernel<<<BS, 256, 0, stream>>>(x, lnfg, lnfb, xf);
  pool_kernel<<<dim3(3, 4), 256, 0, stream>>>(xf, pooled);
  clf_kernel<<<4, 128, 0, stream>>>(pooled, clfw, clfb, out);
}

// Round 9
// 8303.695 us; speedup vs baseline: 1.5811x; 1.1821x over previous
//
#include <hip/hip_runtime.h>
#include <cstdint>
#include <cstddef>

// ---------- types ----------
typedef float     f32x4 __attribute__((ext_vector_type(4)));
typedef _Float16  f16x8 __attribute__((ext_vector_type(8)));
typedef _Float16  f16x4 __attribute__((ext_vector_type(4)));
typedef _Float16  f16x2 __attribute__((ext_vector_type(2)));

#define GLD16(g, l)                                                            \
  __builtin_amdgcn_global_load_lds(                                           \
      (const __attribute__((address_space(1))) void*)(g),                     \
      (__attribute__((address_space(3))) void*)(l), 16, 0, 0)

// ---------- constants ----------
#define BQ    4
#define SEQ   1024
#define DMOD  768
#define NH    12
#define DKH   64
#define DVH   128
#define DVAL  1536
#define DFFN  3072
#define BS    4096   /* BQ*SEQ */

// =====================================================================
// weight transpose + f32->f16 hi/lo split into fused layout.
// mode 0: outrow = row_off + n  (linear)
// mode 1: fc1 interleave : outrow = (n>>6)*128 + ((n>>5)&1)*64 + (n&31)
// mode 2: gate interleave: outrow = (n>>6)*128 + ((n>>5)&1)*64 + 32 + (n&31)
// =====================================================================
__global__ void wcvt_kernel(const float* __restrict__ win, _Float16* __restrict__ whi,
                            _Float16* __restrict__ wlo, int K, int N,
                            long in_ls, long out_ls, int row_off, int mode)
{
  __shared__ float tle[32][33];
  size_t ib = (size_t)blockIdx.z * in_ls;
  size_t ob = (size_t)blockIdx.z * out_ls;
  int k0 = blockIdx.y * 32, n0 = blockIdx.x * 32;
  int tx = threadIdx.x, ty = threadIdx.y;
#pragma unroll
  for (int i = 0; i < 4; ++i)
    tle[ty + 8*i][tx] = win[ib + (size_t)(k0 + ty + 8*i) * N + n0 + tx];
  __syncthreads();
#pragma unroll
  for (int i = 0; i < 4; ++i) {
    float v = tle[tx][ty + 8*i];
    _Float16 h = (_Float16)v;
    int n = n0 + ty + 8*i;
    int orow;
    if (mode == 0)      orow = row_off + n;
    else if (mode == 1) orow = (n >> 6) * 128 + ((n >> 5) & 1) * 64 + (n & 31);
    else                orow = (n >> 6) * 128 + ((n >> 5) & 1) * 64 + 32 + (n & 31);
    size_t idx = ob + (size_t)orow * K + k0 + tx;
    whi[idx] = h;
    wlo[idx] = (_Float16)((v - (float)h) * 1024.0f);
  }
}

// =====================================================================
// embedding gather
// =====================================================================
__global__ void embed_kernel(const int* __restrict__ ids, const float* __restrict__ emb,
                             float* __restrict__ x)
{
  int tok = blockIdx.x;
  int id  = ids[tok];
  const float4* s = (const float4*)(emb + (size_t)id * DMOD);
  float4*       d = (float4*)(x + (size_t)tok * DMOD);
  d[threadIdx.x] = s[threadIdx.x];   // block = 192 threads
}

// =====================================================================
// layernorm over 768 -> f32 out (final LN)
// =====================================================================
__global__ __launch_bounds__(256) void ln_kernel(const float* __restrict__ x,
                                                 const float* __restrict__ g,
                                                 const float* __restrict__ bta,
                                                 float* __restrict__ out)
{
  int row = blockIdx.x;
  const float* xr = x + (size_t)row * DMOD;
  int t = threadIdx.x;
  float v0 = xr[t], v1 = xr[t + 256], v2 = xr[t + 512];
  float s  = v0 + v1 + v2;
  float sq = v0*v0 + v1*v1 + v2*v2;
#pragma unroll
  for (int m = 1; m < 64; m <<= 1) { s += __shfl_xor(s, m); sq += __shfl_xor(sq, m); }
  __shared__ float red[8];
  int wv = t >> 6, ln_ = t & 63;
  if (ln_ == 0) { red[wv] = s; red[wv + 4] = sq; }
  __syncthreads();
  s  = red[0] + red[1] + red[2] + red[3];
  sq = red[4] + red[5] + red[6] + red[7];
  float mu = s * (1.f / DMOD);
  float rs = rsqrtf(sq * (1.f / DMOD) - mu * mu + 1e-5f);
  out[(size_t)row * DMOD + t      ] = (v0 - mu) * rs * g[t      ] + bta[t      ];
  out[(size_t)row * DMOD + t + 256] = (v1 - mu) * rs * g[t + 256] + bta[t + 256];
  out[(size_t)row * DMOD + t + 512] = (v2 - mu) * rs * g[t + 512] + bta[t + 512];
}

// =====================================================================
// layernorm over 768 -> f16 (GEMM A-operand, single plane)
// =====================================================================
__global__ __launch_bounds__(256) void ln_h_kernel(const float* __restrict__ x,
                                                   const float* __restrict__ g,
                                                   const float* __restrict__ bta,
                                                   _Float16* __restrict__ oh)
{
  int row = blockIdx.x;
  const float* xr = x + (size_t)row * DMOD;
  int t = threadIdx.x;
  float v0 = xr[t], v1 = xr[t + 256], v2 = xr[t + 512];
  float s  = v0 + v1 + v2;
  float sq = v0*v0 + v1*v1 + v2*v2;
#pragma unroll
  for (int m = 1; m < 64; m <<= 1) { s += __shfl_xor(s, m); sq += __shfl_xor(sq, m); }
  __shared__ float red[8];
  int wv = t >> 6, ln_ = t & 63;
  if (ln_ == 0) { red[wv] = s; red[wv + 4] = sq; }
  __syncthreads();
  s  = red[0] + red[1] + red[2] + red[3];
  sq = red[4] + red[5] + red[6] + red[7];
  float mu = s * (1.f / DMOD);
  float rs = rsqrtf(sq * (1.f / DMOD) - mu * mu + 1e-5f);
#pragma unroll
  for (int q = 0; q < 3; ++q) {
    int c = t + q * 256;
    float y = (xr[c] - mu) * rs * g[c] + bta[c];
    oh[(size_t)row * DMOD + c] = (_Float16)y;
  }
}

// =====================================================================
// GEMM: A[M][K](f16) @ (Bh + Bl/1024)[NTOT][K](f16)^T, 2-term split
// (weight-lo kept for fp32-class weights; act-lo dropped — pooled away).
// BMx128 tile, BK=32, 4 waves, global_load_lds + XOR swizzle, XCD swizzle.
// MODE 0: C[M][ldc] f32 (opt += R).
// MODE 1: silu-gate epilogue (fc1/gate interleaved weights): j0,1 = f1,
//         j2,3 = gate of same cols; writes f16 at ldc_out=3072.
// =====================================================================
template<int BM, int MODE>
__global__ __launch_bounds__(256) void gemm_bt(const _Float16* __restrict__ Ah,
                                               const _Float16* __restrict__ Bh,
                                               const _Float16* __restrict__ Bl,
                                               float* __restrict__ C,
                                               const float* __restrict__ R,
                                               _Float16* __restrict__ OH,
                                               int nbx, int K, int ldc)
{
  constexpr int RI = BM / 32;           // row fragments per wave
  __shared__ char sAh[BM * 64];
  __shared__ char sBh[8192];
  __shared__ char sBl[8192];
  const int tid = threadIdx.x, lane = tid & 63, w = tid >> 6;

  // bijective XCD swizzle over the 1D grid
  int nwg = gridDim.x, bid = blockIdx.x;
  int qq = nwg >> 3, rr = nwg & 7;
  int xc = bid & 7, ix = bid >> 3;
  int wg = (xc < rr ? xc * (qq + 1) : rr * (qq + 1) + (xc - rr) * qq) + ix;
  int bx = wg % nbx, by = wg / nbx;

  const int m0 = by * BM, n0 = bx * 128;
  const int wm = (w >> 1) * (BM / 2), wn = (w & 1) * 64;
  const int lhi = lane >> 4, llo = lane & 15;

  const f32x4 fz = {0.f, 0.f, 0.f, 0.f};
  f32x4 accH[RI][4], accM[RI][4];
#pragma unroll
  for (int i = 0; i < RI; ++i)
#pragma unroll
    for (int j = 0; j < 4; ++j) { accH[i][j] = fz; accM[i][j] = fz; }

  for (int k0 = 0; k0 < K; k0 += 32) {
    __syncthreads();
#pragma unroll
    for (int i = 0; i < BM / 64; ++i) {           // A plane (hi only)
      int off = w * (BM * 16) + i * 1024 + lane * 16;
      int r = off >> 6, c = (off >> 4) & 3;
      size_t go = (size_t)r * K + ((c ^ (r & 3)) << 3);
      GLD16(Ah + (size_t)m0 * K + k0 + go, sAh + w * (BM * 16) + i * 1024);
    }
#pragma unroll
    for (int i = 0; i < 2; ++i) {                 // B planes (hi+lo)
      int off = w * 2048 + i * 1024 + lane * 16;
      int r = off >> 6, c = (off >> 4) & 3;
      size_t go = (size_t)r * K + ((c ^ (r & 3)) << 3);
      GLD16(Bh + (size_t)n0 * K + k0 + go, sBh + w * 2048 + i * 1024);
      GLD16(Bl + (size_t)n0 * K + k0 + go, sBl + w * 2048 + i * 1024);
    }
    __syncthreads();

    f16x8 ah[RI], bh[4], bl[4];
#pragma unroll
    for (int r = 0; r < RI; ++r) {
      int ra = wm + r * 16 + llo;
      ah[r] = *(const f16x8*)(sAh + ra * 64 + ((lhi ^ (ra & 3)) << 4));
    }
#pragma unroll
    for (int r = 0; r < 4; ++r) {
      int rb = wn + r * 16 + llo;
      int sb = rb * 64 + ((lhi ^ (rb & 3)) << 4);
      bh[r] = *(const f16x8*)(sBh + sb);
      bl[r] = *(const f16x8*)(sBl + sb);
    }
#pragma unroll
    for (int i = 0; i < RI; ++i)
#pragma unroll
      for (int j = 0; j < 4; ++j) {
        accH[i][j] = __builtin_amdgcn_mfma_f32_16x16x32_f16(ah[i], bh[j], accH[i][j], 0, 0, 0);
        accM[i][j] = __builtin_amdgcn_mfma_f32_16x16x32_f16(ah[i], bl[j], accM[i][j], 0, 0, 0);
      }
  }

  if (MODE == 0) {
#pragma unroll
    for (int i = 0; i < RI; ++i)
#pragma unroll
      for (int j = 0; j < 4; ++j)
#pragma unroll
        for (int rg = 0; rg < 4; ++rg) {
          int m = m0 + wm + i * 16 + lhi * 4 + rg;
          int n = n0 + wn + j * 16 + llo;
          size_t idx = (size_t)m * ldc + n;
          float v = accH[i][j][rg] + accM[i][j][rg] * (1.0f / 1024.0f);
          if (R) v += R[idx];
          C[idx] = v;
        }
  } else {
    // silu(f1)*gate, f16 out at col = bx*64 + wn/2 + j*16 + llo
#pragma unroll
    for (int i = 0; i < RI; ++i)
#pragma unroll
      for (int j = 0; j < 2; ++j)
#pragma unroll
        for (int rg = 0; rg < 4; ++rg) {
          int m = m0 + wm + i * 16 + lhi * 4 + rg;
          int n = (n0 >> 1) + (wn >> 1) + j * 16 + llo;
          float f1 = accH[i][j][rg]     + accM[i][j][rg]     * (1.0f / 1024.0f);
          float gv = accH[i][j + 2][rg] + accM[i][j + 2][rg] * (1.0f / 1024.0f);
          float y = f1 / (1.f + expf(-f1)) * gv;
          OH[(size_t)m * 3072 + n] = (_Float16)y;
        }
  }
}

// =====================================================================
// theta-shift q,k (f32 strided in fused C) -> f16 hi/lo [B][H][S][DK]
// =====================================================================
__global__ void prep_qk_kernel(const float* __restrict__ qk, int ld,
                               _Float16* __restrict__ qrH, _Float16* __restrict__ qrL,
                               _Float16* __restrict__ krH, _Float16* __restrict__ krL)
{
  int row = blockIdx.x;                 // b*S + s
  int s = row & (SEQ - 1), b = row >> 10;
  int pi = threadIdx.x;                 // 0..383
  int d0 = pi * 2;
  int h = d0 >> 6;
  int i = d0 & 63;
  int j = i >> 1;
  float ang = exp2f(-(float)j * (13.287712379549449f / 31.f)); // 10000^{-j/31}
  float arg = (float)s * ang;
  float cc = cosf(arg), sn = sinf(arg);
  size_t src = (size_t)row * ld + d0;
  size_t dst = ((size_t)(b * NH + h) * SEQ + s) * DKH + i;

  float q0 = qk[src], q1 = qk[src + 1];
  float rq0 = q0 * cc - q1 * sn;
  float rq1 = q1 * cc + q0 * sn;
  _Float16 h0 = (_Float16)rq0, h1 = (_Float16)rq1;
  qrH[dst]     = h0; qrL[dst]     = (_Float16)((rq0 - (float)h0) * 1024.f);
  qrH[dst + 1] = h1; qrL[dst + 1] = (_Float16)((rq1 - (float)h1) * 1024.f);

  float k0 = qk[src + 768], k1 = qk[src + 769];
  float rk0 = k0 * cc - k1 * sn;
  float rk1 = k1 * cc + k0 * sn;
  _Float16 g0 = (_Float16)rk0, g1 = (_Float16)rk1;
  krH[dst]     = g0; krL[dst]     = (_Float16)((rk0 - (float)g0) * 1024.f);
  krH[dst + 1] = g1; krL[dst + 1] = (_Float16)((rk1 - (float)g1) * 1024.f);
}

// =====================================================================
// v transpose: f32 strided -> f16 [B][H][128][S]
// =====================================================================
__global__ __launch_bounds__(256) void vtrans_kernel(const float* __restrict__ vsrc, int ld,
                                                     _Float16* __restrict__ vt)
{
  __shared__ _Float16 tl[128][65];
  int bh = blockIdx.x >> 4;
  int s0 = (blockIdx.x & 15) << 6;
  int b = bh / NH, h = bh % NH;
  int t = threadIdx.x;
#pragma unroll
  for (int it = 0; it < 32; ++it) {
    int idx = it * 256 + t;
    int sl = idx >> 7, d = idx & 127;
    tl[d][sl] = (_Float16)vsrc[(size_t)(b * SEQ + s0 + sl) * ld + h * DVH + d];
  }
  __syncthreads();
#pragma unroll
  for (int it = 0; it < 32; ++it) {
    int idx = it * 256 + t;
    int d = idx >> 6, sl = idx & 63;
    vt[((size_t)bh * DVH + d) * SEQ + s0 + sl] = tl[d][sl];
  }
}

// =====================================================================
// retention stage 1: per (bh, rb, ct-chunk<=2): QK^T(3-term) -> decay ->
// PV partial; atomicAdd into accbuf[bh][s][dv] and dsacc[bh][s].
// =====================================================================
__global__ __launch_bounds__(256) void attn_part(const _Float16* __restrict__ qrH_,
                                                 const _Float16* __restrict__ qrL_,
                                                 const _Float16* __restrict__ krH_,
                                                 const _Float16* __restrict__ krL_,
                                                 const _Float16* __restrict__ vt,
                                                 float* __restrict__ accb,
                                                 float* __restrict__ dsacc)
{
  static const int RBtab[20] = {0,1,2,2,3,3,4,4,4,5,5,5,6,6,6,6,7,7,7,7};
  static const int C0tab[20] = {0,0,0,2,0,2,0,2,4,0,2,4,0,2,4,6,0,2,4,6};
  __shared__ char pbuf[32768];          // 4 waves x [32][128] f16, XOR-swizzled
  const int tid = threadIdx.x, lane = tid & 63, w = tid >> 6;
  const int rb = RBtab[blockIdx.x], c0 = C0tab[blockIdx.x];
  const int bh = blockIdx.y;            // 0..47
  const int h = bh % NH;
  const int wrow0 = rb * 128 + w * 32;
  const int lhi = lane >> 4, llo = lane & 15;

  const _Float16* qbhH = qrH_ + (size_t)bh * SEQ * DKH;
  const _Float16* qbhL = qrL_ + (size_t)bh * SEQ * DKH;
  const _Float16* kbhH = krH_ + (size_t)bh * SEQ * DKH;
  const _Float16* kbhL = krL_ + (size_t)bh * SEQ * DKH;
  const _Float16* vbh  = vt   + (size_t)bh * DVH * SEQ;

  const float lg = log1pf(-exp2f(-(float)(5 + h)));   // ln(gamma_h)
  const float den_lg = expm1f(lg);                    // gamma - 1

  float invn[2][4];
#pragma unroll
  for (int rf = 0; rf < 2; ++rf)
#pragma unroll
    for (int rg = 0; rg < 4; ++rg) {
      int n = wrow0 + rf * 16 + lhi * 4 + rg;
      float sumD = expm1f((float)(n + 1) * lg) / den_lg;  // (1-g^{n+1})/(1-g)
      invn[rf][rg] = rsqrtf(sumD) * 0.125f;               // fold DK^-0.5
    }

  float gm[8];
#pragma unroll
  for (int fc = 0; fc < 8; ++fc)
    gm[fc] = expf(-(float)(fc * 16 + llo) * lg);

  f16x8 qaH[2][2], qaL[2][2];
#pragma unroll
  for (int rf = 0; rf < 2; ++rf)
#pragma unroll
    for (int kt = 0; kt < 2; ++kt) {
      size_t qo = (size_t)(wrow0 + rf * 16 + llo) * DKH + kt * 32 + lhi * 8;
      qaH[rf][kt] = *(const f16x8*)(qbhH + qo);
      qaL[rf][kt] = *(const f16x8*)(qbhL + qo);
    }

  const f32x4 fz = {0.f, 0.f, 0.f, 0.f};
  f32x4 acc[2][8];
#pragma unroll
  for (int i = 0; i < 2; ++i)
#pragma unroll
    for (int j = 0; j < 8; ++j) acc[i][j] = fz;
  float dsum[2][4] = {{0, 0, 0, 0}, {0, 0, 0, 0}};

  const int ctend = (c0 + 1 < rb) ? c0 + 1 : rb;
  for (int ct = c0; ct <= ctend; ++ct) {
    const bool diag = (ct == rb);
    float fn[2][4];
#pragma unroll
    for (int rf = 0; rf < 2; ++rf)
#pragma unroll
      for (int rg = 0; rg < 4; ++rg) {
        int n = wrow0 + rf * 16 + lhi * 4 + rg;
        fn[rf][rg] = expf((float)(n - ct * 128) * lg) * invn[rf][rg];
      }

#pragma unroll
    for (int fc = 0; fc < 8; ++fc) {
      f32x4 pH[2] = {fz, fz}, pM[2] = {fz, fz};
#pragma unroll
      for (int kt = 0; kt < 2; ++kt) {
        size_t kro = (size_t)(ct * 128 + fc * 16 + llo) * DKH + kt * 32 + lhi * 8;
        f16x8 kbH = *(const f16x8*)(kbhH + kro);
        f16x8 kbL = *(const f16x8*)(kbhL + kro);
        pH[0] = __builtin_amdgcn_mfma_f32_16x16x32_f16(qaH[0][kt], kbH, pH[0], 0, 0, 0);
        pH[1] = __builtin_amdgcn_mfma_f32_16x16x32_f16(qaH[1][kt], kbH, pH[1], 0, 0, 0);
        pM[0] = __builtin_amdgcn_mfma_f32_16x16x32_f16(qaL[0][kt], kbH, pM[0], 0, 0, 0);
        pM[1] = __builtin_amdgcn_mfma_f32_16x16x32_f16(qaL[1][kt], kbH, pM[1], 0, 0, 0);
        pM[0] = __builtin_amdgcn_mfma_f32_16x16x32_f16(qaH[0][kt], kbL, pM[0], 0, 0, 0);
        pM[1] = __builtin_amdgcn_mfma_f32_16x16x32_f16(qaH[1][kt], kbL, pM[1], 0, 0, 0);
      }
#pragma unroll
      for (int rf = 0; rf < 2; ++rf)
#pragma unroll
        for (int rg = 0; rg < 4; ++rg) {
          float pv = (pH[rf][rg] + pM[rf][rg] * (1.f / 1024.f)) * fn[rf][rg] * gm[fc];
          if (diag) {
            int e = (wrow0 + rf * 16 + lhi * 4 + rg) - (ct * 128 + fc * 16 + llo);
            if (e < 0) pv = 0.f;
          }
          dsum[rf][rg] += fabsf(pv);
          int prow = rf * 16 + lhi * 4 + rg;
          int byte = (w << 13) + prow * 256 + (fc * 16 + llo) * 2;
          byte ^= (prow & 7) << 4;
          *(_Float16*)(pbuf + byte) = (_Float16)pv;
        }
    }
    // each wave reads only its own pbuf slice — no barrier needed

    f16x8 pa[2][4];
#pragma unroll
    for (int rf2 = 0; rf2 < 2; ++rf2)
#pragma unroll
      for (int kt = 0; kt < 4; ++kt) {
        int prow = rf2 * 16 + llo;
        int byte = (w << 13) + prow * 256 + kt * 64 + lhi * 16;
        byte ^= (prow & 7) << 4;
        pa[rf2][kt] = *(const f16x8*)(pbuf + byte);
      }
#pragma unroll
    for (int fd = 0; fd < 8; ++fd)
#pragma unroll
      for (int kt = 0; kt < 4; ++kt) {
        f16x8 vb = *(const f16x8*)(vbh + (size_t)(fd * 16 + llo) * SEQ + ct * 128 + kt * 32 + lhi * 8);
        acc[0][fd] = __builtin_amdgcn_mfma_f32_16x16x32_f16(pa[0][kt], vb, acc[0][fd], 0, 0, 0);
        acc[1][fd] = __builtin_amdgcn_mfma_f32_16x16x32_f16(pa[1][kt], vb, acc[1][fd], 0, 0, 0);
      }
  }

  float* ab = accb + (size_t)bh * SEQ * DVH;
#pragma unroll
  for (int rf = 0; rf < 2; ++rf)
#pragma unroll
    for (int rg = 0; rg < 4; ++rg) {
      float d = dsum[rf][rg];
      d += __shfl_xor(d, 1); d += __shfl_xor(d, 2);
      d += __shfl_xor(d, 4); d += __shfl_xor(d, 8);
      int row = wrow0 + rf * 16 + lhi * 4 + rg;
      if (llo == 0) atomicAdd(&dsacc[bh * SEQ + row], d);
#pragma unroll
      for (int fd = 0; fd < 8; ++fd)
        atomicAdd(&ab[(size_t)row * DVH + fd * 16 + llo], acc[rf][fd][rg]);
    }
}

// =====================================================================
// retention stage 2: row-normalize + group-norm + silu(g)*o fused,
// writes ogb f16 [B*S][1536]
// =====================================================================
__global__ __launch_bounds__(256) void attn_norm(const float* __restrict__ accb,
                                                 const float* __restrict__ dsacc,
                                                 const float* __restrict__ gsrc, int ldg,
                                                 _Float16* __restrict__ oh)
{
  int bh = blockIdx.y, h = bh % NH, b = bh / NH;
  int s0 = blockIdx.x * 32;
  int lane = threadIdx.x & 63, w = threadIdx.x >> 6;
  const float* ab = accb + ((size_t)bh * SEQ + s0) * DVH;
#pragma unroll
  for (int i = 0; i < 8; ++i) {
    int r = w * 8 + i;
    size_t row = (size_t)(b * SEQ + s0 + r);
    float2 v = *(const float2*)(ab + (size_t)r * DVH + lane * 2);
    float inv = 1.f / fmaxf(dsacc[bh * SEQ + s0 + r], 1.f);
    v.x *= inv; v.y *= inv;
    float ss = v.x * v.x + v.y * v.y;
#pragma unroll
    for (int m = 1; m < 64; m <<= 1) ss += __shfl_xor(ss, m);
    float rs = rsqrtf(ss * (1.f / 128.f) + 1e-5f);
    float o0 = v.x * rs, o1 = v.y * rs;
    float2 g = *(const float2*)(gsrc + row * ldg + h * DVH + lane * 2);
    float y0 = g.x / (1.f + expf(-g.x)) * o0;
    float y1 = g.y / (1.f + expf(-g.y)) * o1;
    f16x2 vh = {(_Float16)y0, (_Float16)y1};
    *(f16x2*)(oh + row * DVAL + h * DVH + lane * 2) = vh;
  }
}

// =====================================================================
// mean pool over S
// =====================================================================
__global__ void pool_kernel(const float* __restrict__ xf, float* __restrict__ pooled)
{
  int d = blockIdx.x * 256 + threadIdx.x;   // grid.x = 3
  int b = blockIdx.y;
  float acc = 0.f;
  for (int s = 0; s < SEQ; ++s) acc += xf[((size_t)(b * SEQ + s)) * DMOD + d];
  pooled[b * DMOD + d] = acc * (1.f / SEQ);
}

// =====================================================================
// classifier
// =====================================================================
__global__ void clf_kernel(const float* __restrict__ pooled, const float* __restrict__ cw,
                           const float* __restrict__ cb, float* __restrict__ out)
{
  int b = blockIdx.x, c = threadIdx.x;
  if (c < 100) {
    float acc = cb[c];
    for (int d = 0; d < DMOD; ++d) acc += pooled[b * DMOD + d] * cw[d * 100 + c];
    out[b * 100 + c] = acc;
  }
}

// =====================================================================
// host
// =====================================================================
extern "C" void kernel_launch(void* const* d_in, const int* in_sizes, int n_in,
                              void* d_out, int out_size, void* d_ws, size_t ws_size,
                              hipStream_t stream)
{
  const int*   ids  = (const int*)d_in[0];
  const float* emb  = (const float*)d_in[1];
  const float* wq   = (const float*)d_in[2];
  const float* wk   = (const float*)d_in[3];
  const float* wv   = (const float*)d_in[4];
  const float* wg   = (const float*)d_in[5];
  const float* wo   = (const float*)d_in[6];
  const float* ln1g = (const float*)d_in[7];
  const float* ln1b = (const float*)d_in[8];
  const float* ln2g = (const float*)d_in[9];
  const float* ln2b = (const float*)d_in[10];
  const float* fc1  = (const float*)d_in[11];
  const float* gate = (const float*)d_in[12];
  const float* fc2  = (const float*)d_in[13];
  const float* lnfg = (const float*)d_in[14];
  const float* lnfb = (const float*)d_in[15];
  const float* clfw = (const float*)d_in[16];
  const float* clfb = (const float*)d_in[17];
  float* out = (float*)d_out;

  char* ws = (char*)d_ws;
  size_t off = 0;
  auto alloc = [&](size_t bytes) {
    size_t r = off;
    off = (off + bytes + 255) & ~(size_t)255;
    return r;
  };

  const size_t W_QKVG = 12ull * 4608 * 768 * 2;
  const size_t W_O    = 12ull * 768 * 1536 * 2;
  const size_t W_F1GT = 12ull * 6144 * 768 * 2;
  const size_t W_F2   = 12ull * 768 * 3072 * 2;
  const bool big = ws_size >= 780ull * 1024 * 1024;
  const size_t d12 = big ? 1 : 12;

  _Float16* wQKVGh = (_Float16*)(ws + alloc(W_QKVG / d12));
  _Float16* wQKVGl = (_Float16*)(ws + alloc(W_QKVG / d12));
  _Float16* wOh    = (_Float16*)(ws + alloc(W_O    / d12));
  _Float16* wOl    = (_Float16*)(ws + alloc(W_O    / d12));
  _Float16* wF1GTh = (_Float16*)(ws + alloc(W_F1GT / d12));
  _Float16* wF1GTl = (_Float16*)(ws + alloc(W_F1GT / d12));
  _Float16* wF2h   = (_Float16*)(ws + alloc(W_F2   / d12));
  _Float16* wF2l   = (_Float16*)(ws + alloc(W_F2   / d12));

  float*    x    = (float*)(ws + alloc((size_t)BS * DMOD * 4));
  _Float16* hbfH = (_Float16*)(ws + alloc((size_t)BS * DMOD * 2));
  float*    cbuf = (float*)(ws + alloc((size_t)BS * 4608 * 4));   // qkvg GEMM out
  char*     regB = ws + alloc(8ull * 6291456);                    // 50.3 MB
  float*    accb = (float*)(ws + alloc((size_t)BS * DVAL * 4 + 48ull * SEQ * 4));
  float*    dsacc = accb + (size_t)BS * DVAL;
  float*    pooled = (float*)(ws + alloc(4 * DMOD * 4));

  _Float16* qrbH = (_Float16*)regB;
  _Float16* qrbL = (_Float16*)(regB + 6291456);
  _Float16* krbH = (_Float16*)(regB + 12582912);
  _Float16* krbL = (_Float16*)(regB + 18874368);
  _Float16* vtb  = (_Float16*)(regB + 25165824);
  _Float16* ogbH = (_Float16*)regB;                 // alias (post-attn_part)
  _Float16* ffnbH = (_Float16*)regB;                // alias (post-wo)

  dim3 tb(32, 8);
  const long lsDD = 768l * 768, lsDV = 768l * 1536, lsDF = 768l * 3072;
  const long oQKVG = 4608l * 768, oO = 768l * 1536, oF1 = 6144l * 768, oF2 = 768l * 3072;

  if (big) {
    wcvt_kernel<<<dim3(24, 24, 12), tb, 0, stream>>>(wq,   wQKVGh, wQKVGl, 768, 768,  lsDD, oQKVG, 0,    0);
    wcvt_kernel<<<dim3(24, 24, 12), tb, 0, stream>>>(wk,   wQKVGh, wQKVGl, 768, 768,  lsDD, oQKVG, 768,  0);
    wcvt_kernel<<<dim3(48, 24, 12), tb, 0, stream>>>(wv,   wQKVGh, wQKVGl, 768, 1536, lsDV, oQKVG, 1536, 0);
    wcvt_kernel<<<dim3(48, 24, 12), tb, 0, stream>>>(wg,   wQKVGh, wQKVGl, 768, 1536, lsDV, oQKVG, 3072, 0);
    wcvt_kernel<<<dim3(24, 48, 12), tb, 0, stream>>>(wo,   wOh,    wOl,    1536, 768, lsDV, oO,    0,    0);
    wcvt_kernel<<<dim3(96, 24, 12), tb, 0, stream>>>(fc1,  wF1GTh, wF1GTl, 768, 3072, lsDF, oF1,   0,    1);
    wcvt_kernel<<<dim3(96, 24, 12), tb, 0, stream>>>(gate, wF1GTh, wF1GTl, 768, 3072, lsDF, oF1,   0,    2);
    wcvt_kernel<<<dim3(24, 96, 12), tb, 0, stream>>>(fc2,  wF2h,   wF2l,   3072, 768, lsDF, oF2,   0,    0);
  }

  embed_kernel<<<BS, 192, 0, stream>>>(ids, emb, x);

  for (int l = 0; l < 12; ++l) {
    const _Float16 *Wqkh, *Wqkl, *Woh_, *Wol_, *Wfh, *Wfl, *W2h, *W2l;
    if (big) {
      Wqkh = wQKVGh + (size_t)l * oQKVG;  Wqkl = wQKVGl + (size_t)l * oQKVG;
      Woh_ = wOh    + (size_t)l * oO;     Wol_ = wOl    + (size_t)l * oO;
      Wfh  = wF1GTh + (size_t)l * oF1;    Wfl  = wF1GTl + (size_t)l * oF1;
      W2h  = wF2h   + (size_t)l * oF2;    W2l  = wF2l   + (size_t)l * oF2;
    } else {
      wcvt_kernel<<<dim3(24, 24, 1), tb, 0, stream>>>(wq   + (size_t)l * lsDD, wQKVGh, wQKVGl, 768, 768,  0, 0, 0,    0);
      wcvt_kernel<<<dim3(24, 24, 1), tb, 0, stream>>>(wk   + (size_t)l * lsDD, wQKVGh, wQKVGl, 768, 768,  0, 0, 768,  0);
      wcvt_kernel<<<dim3(48, 24, 1), tb, 0, stream>>>(wv   + (size_t)l * lsDV, wQKVGh, wQKVGl, 768, 1536, 0, 0, 1536, 0);
      wcvt_kernel<<<dim3(48, 24, 1), tb, 0, stream>>>(wg   + (size_t)l * lsDV, wQKVGh, wQKVGl, 768, 1536, 0, 0, 3072, 0);
      wcvt_kernel<<<dim3(24, 48, 1), tb, 0, stream>>>(wo   + (size_t)l * lsDV, wOh,    wOl,    1536, 768, 0, 0, 0,    0);
      wcvt_kernel<<<dim3(96, 24, 1), tb, 0, stream>>>(fc1  + (size_t)l * lsDF, wF1GTh, wF1GTl, 768, 3072, 0, 0, 0,    1);
      wcvt_kernel<<<dim3(96, 24, 1), tb, 0, stream>>>(gate + (size_t)l * lsDF, wF1GTh, wF1GTl, 768, 3072, 0, 0, 0,    2);
      wcvt_kernel<<<dim3(24, 96, 1), tb, 0, stream>>>(fc2  + (size_t)l * lsDF, wF2h,   wF2l,   3072, 768, 0, 0, 0,    0);
      Wqkh = wQKVGh; Wqkl = wQKVGl; Woh_ = wOh; Wol_ = wOl;
      Wfh = wF1GTh; Wfl = wF1GTl; W2h = wF2h; W2l = wF2l;
    }

    ln_h_kernel<<<BS, 256, 0, stream>>>(x, ln1g + l * 768, ln1b + l * 768, hbfH);
    gemm_bt<128, 0><<<36 * 32, 256, 0, stream>>>(hbfH, Wqkh, Wqkl, cbuf, nullptr,
                                                 nullptr, 36, 768, 4608);
    prep_qk_kernel<<<BS, 384, 0, stream>>>(cbuf, 4608, qrbH, qrbL, krbH, krbL);
    vtrans_kernel<<<768, 256, 0, stream>>>(cbuf + 1536, 4608, vtb);
    hipMemsetAsync(accb, 0, (size_t)BS * DVAL * 4 + 48ull * SEQ * 4, stream);
    attn_part<<<dim3(20, 48), 256, 0, stream>>>(qrbH, qrbL, krbH, krbL, vtb, accb, dsacc);
    attn_norm<<<dim3(32, 48), 256, 0, stream>>>(accb, dsacc, cbuf + 3072, 4608, ogbH);
    gemm_bt<64, 0><<<6 * 64, 256, 0, stream>>>(ogbH, Woh_, Wol_, x, x,
                                               nullptr, 6, 1536, 768);
    ln_h_kernel<<<BS, 256, 0, stream>>>(x, ln2g + l * 768, ln2b + l * 768, hbfH);
    gemm_bt<128, 1><<<48 * 32, 256, 0, stream>>>(hbfH, Wfh, Wfl, nullptr, nullptr,
                                                 ffnbH, 48, 768, 0);
    gemm_bt<64, 0><<<6 * 64, 256, 0, stream>>>(ffnbH, W2h, W2l, x, x,
                                               nullptr, 6, 3072, 768);
  }

  float* xf = cbuf;
  ln_kernel<<<BS, 256, 0, stream>>>(x, lnfg, lnfb, xf);
  pool_kernel<<<dim3(3, 4), 256, 0, stream>>>(xf, pooled);
  clf_kernel<<<4, 128, 0, stream>>>(pooled, clfw, clfb, out);
}

// Round 11
// 7739.136 us; speedup vs baseline: 1.6964x; 1.0729x over previous
//
#include <hip/hip_runtime.h>
#include <cstdint>
#include <cstddef>

// ---------- types ----------
typedef float     f32x4 __attribute__((ext_vector_type(4)));
typedef _Float16  f16x8 __attribute__((ext_vector_type(8)));
typedef _Float16  f16x2 __attribute__((ext_vector_type(2)));

#define GLD16(g, l)                                                            \
  __builtin_amdgcn_global_load_lds(                                           \
      (const __attribute__((address_space(1))) void*)(g),                     \
      (__attribute__((address_space(3))) void*)(l), 16, 0, 0)

// ---------- constants ----------
#define BQ    4
#define SEQ   1024
#define DMOD  768
#define NH    12
#define DKH   64
#define DVH   128
#define DVAL  1536
#define DFFN  3072
#define BS    4096   /* BQ*SEQ */

// =====================================================================
// weight transpose + f32->f16 hi/lo split into fused layout.
// mode 0: orow = row_off + n  (linear)
// mode 1: fc1 interleave : orow = (n>>6)*128 + ((n>>5)&1)*64 + (n&31)
// mode 2: gate interleave: orow = (n>>6)*128 + ((n>>5)&1)*64 + 32 + (n&31)
// =====================================================================
__global__ void wcvt_kernel(const float* __restrict__ win, _Float16* __restrict__ whi,
                            _Float16* __restrict__ wlo, int K, int N,
                            long in_ls, long out_ls, int row_off, int mode)
{
  __shared__ float tle[32][33];
  size_t ib = (size_t)blockIdx.z * in_ls;
  size_t ob = (size_t)blockIdx.z * out_ls;
  int k0 = blockIdx.y * 32, n0 = blockIdx.x * 32;
  int tx = threadIdx.x, ty = threadIdx.y;
#pragma unroll
  for (int i = 0; i < 4; ++i)
    tle[ty + 8*i][tx] = win[ib + (size_t)(k0 + ty + 8*i) * N + n0 + tx];
  __syncthreads();
#pragma unroll
  for (int i = 0; i < 4; ++i) {
    float v = tle[tx][ty + 8*i];
    _Float16 h = (_Float16)v;
    int n = n0 + ty + 8*i;
    int orow;
    if (mode == 0)      orow = row_off + n;
    else if (mode == 1) orow = (n >> 6) * 128 + ((n >> 5) & 1) * 64 + (n & 31);
    else                orow = (n >> 6) * 128 + ((n >> 5) & 1) * 64 + 32 + (n & 31);
    size_t idx = ob + (size_t)orow * K + k0 + tx;
    whi[idx] = h;
    wlo[idx] = (_Float16)((v - (float)h) * 1024.0f);
  }
}

// =====================================================================
// embedding gather
// =====================================================================
__global__ void embed_kernel(const int* __restrict__ ids, const float* __restrict__ emb,
                             float* __restrict__ x)
{
  int tok = blockIdx.x;
  int id  = ids[tok];
  const float4* s = (const float4*)(emb + (size_t)id * DMOD);
  float4*       d = (float4*)(x + (size_t)tok * DMOD);
  d[threadIdx.x] = s[threadIdx.x];   // block = 192 threads
}

// =====================================================================
// layernorm over 768 -> f32 out (final LN)
// =====================================================================
__global__ __launch_bounds__(256) void ln_kernel(const float* __restrict__ x,
                                                 const float* __restrict__ g,
                                                 const float* __restrict__ bta,
                                                 float* __restrict__ out)
{
  int row = blockIdx.x;
  const float* xr = x + (size_t)row * DMOD;
  int t = threadIdx.x;
  float v0 = xr[t], v1 = xr[t + 256], v2 = xr[t + 512];
  float s  = v0 + v1 + v2;
  float sq = v0*v0 + v1*v1 + v2*v2;
#pragma unroll
  for (int m = 1; m < 64; m <<= 1) { s += __shfl_xor(s, m); sq += __shfl_xor(sq, m); }
  __shared__ float red[8];
  int wv = t >> 6, ln_ = t & 63;
  if (ln_ == 0) { red[wv] = s; red[wv + 4] = sq; }
  __syncthreads();
  s  = red[0] + red[1] + red[2] + red[3];
  sq = red[4] + red[5] + red[6] + red[7];
  float mu = s * (1.f / DMOD);
  float rs = rsqrtf(sq * (1.f / DMOD) - mu * mu + 1e-5f);
  out[(size_t)row * DMOD + t      ] = (v0 - mu) * rs * g[t      ] + bta[t      ];
  out[(size_t)row * DMOD + t + 256] = (v1 - mu) * rs * g[t + 256] + bta[t + 256];
  out[(size_t)row * DMOD + t + 512] = (v2 - mu) * rs * g[t + 512] + bta[t + 512];
}

// =====================================================================
// layernorm over 768 -> f16 (GEMM A-operand)
// =====================================================================
__global__ __launch_bounds__(256) void ln_h_kernel(const float* __restrict__ x,
                                                   const float* __restrict__ g,
                                                   const float* __restrict__ bta,
                                                   _Float16* __restrict__ oh)
{
  int row = blockIdx.x;
  const float* xr = x + (size_t)row * DMOD;
  int t = threadIdx.x;
  float v0 = xr[t], v1 = xr[t + 256], v2 = xr[t + 512];
  float s  = v0 + v1 + v2;
  float sq = v0*v0 + v1*v1 + v2*v2;
#pragma unroll
  for (int m = 1; m < 64; m <<= 1) { s += __shfl_xor(s, m); sq += __shfl_xor(sq, m); }
  __shared__ float red[8];
  int wv = t >> 6, ln_ = t & 63;
  if (ln_ == 0) { red[wv] = s; red[wv + 4] = sq; }
  __syncthreads();
  s  = red[0] + red[1] + red[2] + red[3];
  sq = red[4] + red[5] + red[6] + red[7];
  float mu = s * (1.f / DMOD);
  float rs = rsqrtf(sq * (1.f / DMOD) - mu * mu + 1e-5f);
#pragma unroll
  for (int q = 0; q < 3; ++q) {
    int c = t + q * 256;
    float y = (xr[c] - mu) * rs * g[c] + bta[c];
    oh[(size_t)row * DMOD + c] = (_Float16)y;
  }
}

// =====================================================================
// GEMM: A[M][K](f16) @ (Bh + Bl/1024)[NTOT][K](f16)^T, 2-term split
// (weight hi/lo = fp32-class weights; activations single f16).
// BMx128 tile, BK=32, 4 waves, global_load_lds + XOR swizzle, XCD swizzle.
// 2-PHASE double-buffered pipeline: issue next tile's loads before computing
// the current one; one raw s_barrier + vmcnt(0) per K-step (T3 minimal).
// MODE 0: C[M][ldc] f32 (opt += R).
// MODE 1: silu-gate epilogue (fc1/gate interleaved): j0,1 = f1, j2,3 = gate
//         of same cols; writes f16 at ldc_out=3072.
// =====================================================================
template<int BM, int MODE>
__global__ __launch_bounds__(256) void gemm_bt(const _Float16* __restrict__ Ah,
                                               const _Float16* __restrict__ Bh,
                                               const _Float16* __restrict__ Bl,
                                               float* __restrict__ C,
                                               const float* __restrict__ R,
                                               _Float16* __restrict__ OH,
                                               int nbx, int K, int ldc)
{
  constexpr int RI = BM / 32;           // row fragments per wave
  __shared__ char sAh[2][BM * 64];
  __shared__ char sBh[2][8192];
  __shared__ char sBl[2][8192];
  const int tid = threadIdx.x, lane = tid & 63, w = tid >> 6;

  // bijective XCD swizzle over the 1D grid
  int nwg = gridDim.x, bid = blockIdx.x;
  int qq = nwg >> 3, rr = nwg & 7;
  int xc = bid & 7, ix = bid >> 3;
  int wg = (xc < rr ? xc * (qq + 1) : rr * (qq + 1) + (xc - rr) * qq) + ix;
  int bx = wg % nbx, by = wg / nbx;

  const int m0 = by * BM, n0 = bx * 128;
  const int wm = (w >> 1) * (BM / 2), wn = (w & 1) * 64;
  const int lhi = lane >> 4, llo = lane & 15;

  const f32x4 fz = {0.f, 0.f, 0.f, 0.f};
  f32x4 accH[RI][4], accM[RI][4];
#pragma unroll
  for (int i = 0; i < RI; ++i)
#pragma unroll
    for (int j = 0; j < 4; ++j) { accH[i][j] = fz; accM[i][j] = fz; }

  auto stage = [&](int buf, int k0) {
#pragma unroll
    for (int i = 0; i < BM / 64; ++i) {           // A plane
      int off = w * (BM * 16) + i * 1024 + lane * 16;
      int r = off >> 6, c = (off >> 4) & 3;
      size_t go = (size_t)r * K + ((c ^ (r & 3)) << 3);
      GLD16(Ah + (size_t)m0 * K + k0 + go, &sAh[buf][w * (BM * 16) + i * 1024]);
    }
#pragma unroll
    for (int i = 0; i < 2; ++i) {                 // B planes (hi+lo)
      int off = w * 2048 + i * 1024 + lane * 16;
      int r = off >> 6, c = (off >> 4) & 3;
      size_t go = (size_t)r * K + ((c ^ (r & 3)) << 3);
      GLD16(Bh + (size_t)n0 * K + k0 + go, &sBh[buf][w * 2048 + i * 1024]);
      GLD16(Bl + (size_t)n0 * K + k0 + go, &sBl[buf][w * 2048 + i * 1024]);
    }
  };

  // prologue: fill buffer 0
  stage(0, 0);
  asm volatile("s_waitcnt vmcnt(0)" ::: "memory");
  __builtin_amdgcn_s_barrier();

  int cur = 0;
  for (int k0 = 0; k0 < K; k0 += 32) {
    if (k0 + 32 < K) stage(cur ^ 1, k0 + 32);    // prefetch next tile

    f16x8 ah[RI], bh[4], bl[4];
#pragma unroll
    for (int r = 0; r < RI; ++r) {
      int ra = wm + r * 16 + llo;
      ah[r] = *(const f16x8*)(&sAh[cur][ra * 64 + ((lhi ^ (ra & 3)) << 4)]);
    }
#pragma unroll
    for (int r = 0; r < 4; ++r) {
      int rb = wn + r * 16 + llo;
      int sb = rb * 64 + ((lhi ^ (rb & 3)) << 4);
      bh[r] = *(const f16x8*)(&sBh[cur][sb]);
      bl[r] = *(const f16x8*)(&sBl[cur][sb]);
    }
#pragma unroll
    for (int i = 0; i < RI; ++i)
#pragma unroll
      for (int j = 0; j < 4; ++j) {
        accH[i][j] = __builtin_amdgcn_mfma_f32_16x16x32_f16(ah[i], bh[j], accH[i][j], 0, 0, 0);
        accM[i][j] = __builtin_amdgcn_mfma_f32_16x16x32_f16(ah[i], bl[j], accM[i][j], 0, 0, 0);
      }

    // next tile's loads have had the whole compute phase to land
    asm volatile("s_waitcnt vmcnt(0)" ::: "memory");
    __builtin_amdgcn_s_barrier();
    cur ^= 1;
  }

  if (MODE == 0) {
#pragma unroll
    for (int i = 0; i < RI; ++i)
#pragma unroll
      for (int j = 0; j < 4; ++j)
#pragma unroll
        for (int rg = 0; rg < 4; ++rg) {
          int m = m0 + wm + i * 16 + lhi * 4 + rg;
          int n = n0 + wn + j * 16 + llo;
          size_t idx = (size_t)m * ldc + n;
          float v = accH[i][j][rg] + accM[i][j][rg] * (1.0f / 1024.0f);
          if (R) v += R[idx];
          C[idx] = v;
        }
  } else {
    // silu(f1)*gate, f16 out at col = bx*64 + wn/2 + j*16 + llo
#pragma unroll
    for (int i = 0; i < RI; ++i)
#pragma unroll
      for (int j = 0; j < 2; ++j)
#pragma unroll
        for (int rg = 0; rg < 4; ++rg) {
          int m = m0 + wm + i * 16 + lhi * 4 + rg;
          int n = (n0 >> 1) + (wn >> 1) + j * 16 + llo;
          float f1 = accH[i][j][rg]     + accM[i][j][rg]     * (1.0f / 1024.0f);
          float gv = accH[i][j + 2][rg] + accM[i][j + 2][rg] * (1.0f / 1024.0f);
          float y = f1 / (1.f + expf(-f1)) * gv;
          OH[(size_t)m * 3072 + n] = (_Float16)y;
        }
  }
}

// =====================================================================
// theta-shift q,k (f32 strided in fused C) -> f16 hi/lo [B][H][S][DK]
// =====================================================================
__global__ void prep_qk_kernel(const float* __restrict__ qk, int ld,
                               _Float16* __restrict__ qrH, _Float16* __restrict__ qrL,
                               _Float16* __restrict__ krH, _Float16* __restrict__ krL)
{
  int row = blockIdx.x;                 // b*S + s
  int s = row & (SEQ - 1), b = row >> 10;
  int pi = threadIdx.x;                 // 0..383
  int d0 = pi * 2;
  int h = d0 >> 6;
  int i = d0 & 63;
  int j = i >> 1;
  float ang = exp2f(-(float)j * (13.287712379549449f / 31.f)); // 10000^{-j/31}
  float arg = (float)s * ang;
  float cc = cosf(arg), sn = sinf(arg);
  size_t src = (size_t)row * ld + d0;
  size_t dst = ((size_t)(b * NH + h) * SEQ + s) * DKH + i;

  float q0 = qk[src], q1 = qk[src + 1];
  float rq0 = q0 * cc - q1 * sn;
  float rq1 = q1 * cc + q0 * sn;
  _Float16 h0 = (_Float16)rq0, h1 = (_Float16)rq1;
  qrH[dst]     = h0; qrL[dst]     = (_Float16)((rq0 - (float)h0) * 1024.f);
  qrH[dst + 1] = h1; qrL[dst + 1] = (_Float16)((rq1 - (float)h1) * 1024.f);

  float k0 = qk[src + 768], k1 = qk[src + 769];
  float rk0 = k0 * cc - k1 * sn;
  float rk1 = k1 * cc + k0 * sn;
  _Float16 g0 = (_Float16)rk0, g1 = (_Float16)rk1;
  krH[dst]     = g0; krL[dst]     = (_Float16)((rk0 - (float)g0) * 1024.f);
  krH[dst + 1] = g1; krL[dst + 1] = (_Float16)((rk1 - (float)g1) * 1024.f);
}

// =====================================================================
// v transpose: f32 strided -> f16 [B][H][128][S]
// =====================================================================
__global__ __launch_bounds__(256) void vtrans_kernel(const float* __restrict__ vsrc, int ld,
                                                     _Float16* __restrict__ vt)
{
  __shared__ _Float16 tl[128][65];
  int bh = blockIdx.x >> 4;
  int s0 = (blockIdx.x & 15) << 6;
  int b = bh / NH, h = bh % NH;
  int t = threadIdx.x;
#pragma unroll
  for (int it = 0; it < 32; ++it) {
    int idx = it * 256 + t;
    int sl = idx >> 7, d = idx & 127;
    tl[d][sl] = (_Float16)vsrc[(size_t)(b * SEQ + s0 + sl) * ld + h * DVH + d];
  }
  __syncthreads();
#pragma unroll
  for (int it = 0; it < 32; ++it) {
    int idx = it * 256 + t;
    int d = idx >> 6, sl = idx & 63;
    vt[((size_t)bh * DVH + d) * SEQ + s0 + sl] = tl[d][sl];
  }
}

// =====================================================================
// retention stage 1: per (bh, rb, ct-chunk<=2): QK^T(3-term) -> decay ->
// PV partial; atomicAdd into accbuf[bh][s][dv] and dsacc[bh][s].
// =====================================================================
__global__ __launch_bounds__(256) void attn_part(const _Float16* __restrict__ qrH_,
                                                 const _Float16* __restrict__ qrL_,
                                                 const _Float16* __restrict__ krH_,
                                                 const _Float16* __restrict__ krL_,
                                                 const _Float16* __restrict__ vt,
                                                 float* __restrict__ accb,
                                                 float* __restrict__ dsacc)
{
  static const int RBtab[20] = {0,1,2,2,3,3,4,4,4,5,5,5,6,6,6,6,7,7,7,7};
  static const int C0tab[20] = {0,0,0,2,0,2,0,2,4,0,2,4,0,2,4,6,0,2,4,6};
  __shared__ char pbuf[32768];          // 4 waves x [32][128] f16, XOR-swizzled
  const int tid = threadIdx.x, lane = tid & 63, w = tid >> 6;
  const int rb = RBtab[blockIdx.x], c0 = C0tab[blockIdx.x];
  const int bh = blockIdx.y;            // 0..47
  const int h = bh % NH;
  const int wrow0 = rb * 128 + w * 32;
  const int lhi = lane >> 4, llo = lane & 15;

  const _Float16* qbhH = qrH_ + (size_t)bh * SEQ * DKH;
  const _Float16* qbhL = qrL_ + (size_t)bh * SEQ * DKH;
  const _Float16* kbhH = krH_ + (size_t)bh * SEQ * DKH;
  const _Float16* kbhL = krL_ + (size_t)bh * SEQ * DKH;
  const _Float16* vbh  = vt   + (size_t)bh * DVH * SEQ;

  const float lg = log1pf(-exp2f(-(float)(5 + h)));   // ln(gamma_h)
  const float den_lg = expm1f(lg);                    // gamma - 1

  float invn[2][4];
#pragma unroll
  for (int rf = 0; rf < 2; ++rf)
#pragma unroll
    for (int rg = 0; rg < 4; ++rg) {
      int n = wrow0 + rf * 16 + lhi * 4 + rg;
      float sumD = expm1f((float)(n + 1) * lg) / den_lg;  // (1-g^{n+1})/(1-g)
      invn[rf][rg] = rsqrtf(sumD) * 0.125f;               // fold DK^-0.5
    }

  float gm[8];
#pragma unroll
  for (int fc = 0; fc < 8; ++fc)
    gm[fc] = expf(-(float)(fc * 16 + llo) * lg);

  f16x8 qaH[2][2], qaL[2][2];
#pragma unroll
  for (int rf = 0; rf < 2; ++rf)
#pragma unroll
    for (int kt = 0; kt < 2; ++kt) {
      size_t qo = (size_t)(wrow0 + rf * 16 + llo) * DKH + kt * 32 + lhi * 8;
      qaH[rf][kt] = *(const f16x8*)(qbhH + qo);
      qaL[rf][kt] = *(const f16x8*)(qbhL + qo);
    }

  const f32x4 fz = {0.f, 0.f, 0.f, 0.f};
  f32x4 acc[2][8];
#pragma unroll
  for (int i = 0; i < 2; ++i)
#pragma unroll
    for (int j = 0; j < 8; ++j) acc[i][j] = fz;
  float dsum[2][4] = {{0, 0, 0, 0}, {0, 0, 0, 0}};

  const int ctend = (c0 + 1 < rb) ? c0 + 1 : rb;
  for (int ct = c0; ct <= ctend; ++ct) {
    const bool diag = (ct == rb);
    float fn[2][4];
#pragma unroll
    for (int rf = 0; rf < 2; ++rf)
#pragma unroll
      for (int rg = 0; rg < 4; ++rg) {
        int n = wrow0 + rf * 16 + lhi * 4 + rg;
        fn[rf][rg] = expf((float)(n - ct * 128) * lg) * invn[rf][rg];
      }

#pragma unroll
    for (int fc = 0; fc < 8; ++fc) {
      f32x4 pH[2] = {fz, fz}, pM[2] = {fz, fz};
#pragma unroll
      for (int kt = 0; kt < 2; ++kt) {
        size_t kro = (size_t)(ct * 128 + fc * 16 + llo) * DKH + kt * 32 + lhi * 8;
        f16x8 kbH = *(const f16x8*)(kbhH + kro);
        f16x8 kbL = *(const f16x8*)(kbhL + kro);
        pH[0] = __builtin_amdgcn_mfma_f32_16x16x32_f16(qaH[0][kt], kbH, pH[0], 0, 0, 0);
        pH[1] = __builtin_amdgcn_mfma_f32_16x16x32_f16(qaH[1][kt], kbH, pH[1], 0, 0, 0);
        pM[0] = __builtin_amdgcn_mfma_f32_16x16x32_f16(qaL[0][kt], kbH, pM[0], 0, 0, 0);
        pM[1] = __builtin_amdgcn_mfma_f32_16x16x32_f16(qaL[1][kt], kbH, pM[1], 0, 0, 0);
        pM[0] = __builtin_amdgcn_mfma_f32_16x16x32_f16(qaH[0][kt], kbL, pM[0], 0, 0, 0);
        pM[1] = __builtin_amdgcn_mfma_f32_16x16x32_f16(qaH[1][kt], kbL, pM[1], 0, 0, 0);
      }
#pragma unroll
      for (int rf = 0; rf < 2; ++rf)
#pragma unroll
        for (int rg = 0; rg < 4; ++rg) {
          float pv = (pH[rf][rg] + pM[rf][rg] * (1.f / 1024.f)) * fn[rf][rg] * gm[fc];
          if (diag) {
            int e = (wrow0 + rf * 16 + lhi * 4 + rg) - (ct * 128 + fc * 16 + llo);
            if (e < 0) pv = 0.f;
          }
          dsum[rf][rg] += fabsf(pv);
          int prow = rf * 16 + lhi * 4 + rg;
          int byte = (w << 13) + prow * 256 + (fc * 16 + llo) * 2;
          byte ^= (prow & 7) << 4;
          *(_Float16*)(pbuf + byte) = (_Float16)pv;
        }
    }
    // each wave reads only its own pbuf slice — no barrier needed

    f16x8 pa[2][4];
#pragma unroll
    for (int rf2 = 0; rf2 < 2; ++rf2)
#pragma unroll
      for (int kt = 0; kt < 4; ++kt) {
        int prow = rf2 * 16 + llo;
        int byte = (w << 13) + prow * 256 + kt * 64 + lhi * 16;
        byte ^= (prow & 7) << 4;
        pa[rf2][kt] = *(const f16x8*)(pbuf + byte);
      }
#pragma unroll
    for (int fd = 0; fd < 8; ++fd)
#pragma unroll
      for (int kt = 0; kt < 4; ++kt) {
        f16x8 vb = *(const f16x8*)(vbh + (size_t)(fd * 16 + llo) * SEQ + ct * 128 + kt * 32 + lhi * 8);
        acc[0][fd] = __builtin_amdgcn_mfma_f32_16x16x32_f16(pa[0][kt], vb, acc[0][fd], 0, 0, 0);
        acc[1][fd] = __builtin_amdgcn_mfma_f32_16x16x32_f16(pa[1][kt], vb, acc[1][fd], 0, 0, 0);
      }
  }

  float* ab = accb + (size_t)bh * SEQ * DVH;
#pragma unroll
  for (int rf = 0; rf < 2; ++rf)
#pragma unroll
    for (int rg = 0; rg < 4; ++rg) {
      float d = dsum[rf][rg];
      d += __shfl_xor(d, 1); d += __shfl_xor(d, 2);
      d += __shfl_xor(d, 4); d += __shfl_xor(d, 8);
      int row = wrow0 + rf * 16 + lhi * 4 + rg;
      if (llo == 0) atomicAdd(&dsacc[bh * SEQ + row], d);
#pragma unroll
      for (int fd = 0; fd < 8; ++fd)
        atomicAdd(&ab[(size_t)row * DVH + fd * 16 + llo], acc[rf][fd][rg]);
    }
}

// =====================================================================
// retention stage 2: row-normalize + group-norm + silu(g)*o fused,
// writes ogb f16 [B*S][1536]
// =====================================================================
__global__ __launch_bounds__(256) void attn_norm(const float* __restrict__ accb,
                                                 const float* __restrict__ dsacc,
                                                 const float* __restrict__ gsrc, int ldg,
                                                 _Float16* __restrict__ oh)
{
  int bh = blockIdx.y, h = bh % NH, b = bh / NH;
  int s0 = blockIdx.x * 32;
  int lane = threadIdx.x & 63, w = threadIdx.x >> 6;
  const float* ab = accb + ((size_t)bh * SEQ + s0) * DVH;
#pragma unroll
  for (int i = 0; i < 8; ++i) {
    int r = w * 8 + i;
    size_t row = (size_t)(b * SEQ + s0 + r);
    float2 v = *(const float2*)(ab + (size_t)r * DVH + lane * 2);
    float inv = 1.f / fmaxf(dsacc[bh * SEQ + s0 + r], 1.f);
    v.x *= inv; v.y *= inv;
    float ss = v.x * v.x + v.y * v.y;
#pragma unroll
    for (int m = 1; m < 64; m <<= 1) ss += __shfl_xor(ss, m);
    float rs = rsqrtf(ss * (1.f / 128.f) + 1e-5f);
    float o0 = v.x * rs, o1 = v.y * rs;
    float2 g = *(const float2*)(gsrc + row * ldg + h * DVH + lane * 2);
    float y0 = g.x / (1.f + expf(-g.x)) * o0;
    float y1 = g.y / (1.f + expf(-g.y)) * o1;
    f16x2 vh = {(_Float16)y0, (_Float16)y1};
    *(f16x2*)(oh + row * DVAL + h * DVH + lane * 2) = vh;
  }
}

// =====================================================================
// mean pool over S
// =====================================================================
__global__ void pool_kernel(const float* __restrict__ xf, float* __restrict__ pooled)
{
  int d = blockIdx.x * 256 + threadIdx.x;   // grid.x = 3
  int b = blockIdx.y;
  float acc = 0.f;
  for (int s = 0; s < SEQ; ++s) acc += xf[((size_t)(b * SEQ + s)) * DMOD + d];
  pooled[b * DMOD + d] = acc * (1.f / SEQ);
}

// =====================================================================
// classifier
// =====================================================================
__global__ void clf_kernel(const float* __restrict__ pooled, const float* __restrict__ cw,
                           const float* __restrict__ cb, float* __restrict__ out)
{
  int b = blockIdx.x, c = threadIdx.x;
  if (c < 100) {
    float acc = cb[c];
    for (int d = 0; d < DMOD; ++d) acc += pooled[b * DMOD + d] * cw[d * 100 + c];
    out[b * 100 + c] = acc;
  }
}

// =====================================================================
// host
// =====================================================================
extern "C" void kernel_launch(void* const* d_in, const int* in_sizes, int n_in,
                              void* d_out, int out_size, void* d_ws, size_t ws_size,
                              hipStream_t stream)
{
  const int*   ids  = (const int*)d_in[0];
  const float* emb  = (const float*)d_in[1];
  const float* wq   = (const float*)d_in[2];
  const float* wk   = (const float*)d_in[3];
  const float* wv   = (const float*)d_in[4];
  const float* wg   = (const float*)d_in[5];
  const float* wo   = (const float*)d_in[6];
  const float* ln1g = (const float*)d_in[7];
  const float* ln1b = (const float*)d_in[8];
  const float* ln2g = (const float*)d_in[9];
  const float* ln2b = (const float*)d_in[10];
  const float* fc1  = (const float*)d_in[11];
  const float* gate = (const float*)d_in[12];
  const float* fc2  = (const float*)d_in[13];
  const float* lnfg = (const float*)d_in[14];
  const float* lnfb = (const float*)d_in[15];
  const float* clfw = (const float*)d_in[16];
  const float* clfb = (const float*)d_in[17];
  float* out = (float*)d_out;

  char* ws = (char*)d_ws;
  size_t off = 0;
  auto alloc = [&](size_t bytes) {
    size_t r = off;
    off = (off + bytes + 255) & ~(size_t)255;
    return r;
  };

  const size_t W_QKVG = 12ull * 4608 * 768 * 2;
  const size_t W_O    = 12ull * 768 * 1536 * 2;
  const size_t W_F1GT = 12ull * 6144 * 768 * 2;
  const size_t W_F2   = 12ull * 768 * 3072 * 2;
  const bool big = ws_size >= 780ull * 1024 * 1024;
  const size_t d12 = big ? 1 : 12;

  _Float16* wQKVGh = (_Float16*)(ws + alloc(W_QKVG / d12));
  _Float16* wQKVGl = (_Float16*)(ws + alloc(W_QKVG / d12));
  _Float16* wOh    = (_Float16*)(ws + alloc(W_O    / d12));
  _Float16* wOl    = (_Float16*)(ws + alloc(W_O    / d12));
  _Float16* wF1GTh = (_Float16*)(ws + alloc(W_F1GT / d12));
  _Float16* wF1GTl = (_Float16*)(ws + alloc(W_F1GT / d12));
  _Float16* wF2h   = (_Float16*)(ws + alloc(W_F2   / d12));
  _Float16* wF2l   = (_Float16*)(ws + alloc(W_F2   / d12));

  float*    x    = (float*)(ws + alloc((size_t)BS * DMOD * 4));
  _Float16* hbfH = (_Float16*)(ws + alloc((size_t)BS * DMOD * 2));
  float*    cbuf = (float*)(ws + alloc((size_t)BS * 4608 * 4));   // qkvg GEMM out
  char*     regB = ws + alloc(8ull * 6291456);                    // 50.3 MB
  float*    accb = (float*)(ws + alloc((size_t)BS * DVAL * 4 + 48ull * SEQ * 4));
  float*    dsacc = accb + (size_t)BS * DVAL;
  float*    pooled = (float*)(ws + alloc(4 * DMOD * 4));

  _Float16* qrbH = (_Float16*)regB;
  _Float16* qrbL = (_Float16*)(regB + 6291456);
  _Float16* krbH = (_Float16*)(regB + 12582912);
  _Float16* krbL = (_Float16*)(regB + 18874368);
  _Float16* vtb  = (_Float16*)(regB + 25165824);
  _Float16* ogbH = (_Float16*)regB;                 // alias (post-attn_part)
  _Float16* ffnbH = (_Float16*)regB;                // alias (post-wo)

  dim3 tb(32, 8);
  const long lsDD = 768l * 768, lsDV = 768l * 1536, lsDF = 768l * 3072;
  const long oQKVG = 4608l * 768, oO = 768l * 1536, oF1 = 6144l * 768, oF2 = 768l * 3072;

  if (big) {
    wcvt_kernel<<<dim3(24, 24, 12), tb, 0, stream>>>(wq,   wQKVGh, wQKVGl, 768, 768,  lsDD, oQKVG, 0,    0);
    wcvt_kernel<<<dim3(24, 24, 12), tb, 0, stream>>>(wk,   wQKVGh, wQKVGl, 768, 768,  lsDD, oQKVG, 768,  0);
    wcvt_kernel<<<dim3(48, 24, 12), tb, 0, stream>>>(wv,   wQKVGh, wQKVGl, 768, 1536, lsDV, oQKVG, 1536, 0);
    wcvt_kernel<<<dim3(48, 24, 12), tb, 0, stream>>>(wg,   wQKVGh, wQKVGl, 768, 1536, lsDV, oQKVG, 3072, 0);
    wcvt_kernel<<<dim3(24, 48, 12), tb, 0, stream>>>(wo,   wOh,    wOl,    1536, 768, lsDV, oO,    0,    0);
    wcvt_kernel<<<dim3(96, 24, 12), tb, 0, stream>>>(fc1,  wF1GTh, wF1GTl, 768, 3072, lsDF, oF1,   0,    1);
    wcvt_kernel<<<dim3(96, 24, 12), tb, 0, stream>>>(gate, wF1GTh, wF1GTl, 768, 3072, lsDF, oF1,   0,    2);
    wcvt_kernel<<<dim3(24, 96, 12), tb, 0, stream>>>(fc2,  wF2h,   wF2l,   3072, 768, lsDF, oF2,   0,    0);
  }

  embed_kernel<<<BS, 192, 0, stream>>>(ids, emb, x);

  for (int l = 0; l < 12; ++l) {
    const _Float16 *Wqkh, *Wqkl, *Woh_, *Wol_, *Wfh, *Wfl, *W2h, *W2l;
    if (big) {
      Wqkh = wQKVGh + (size_t)l * oQKVG;  Wqkl = wQKVGl + (size_t)l * oQKVG;
      Woh_ = wOh    + (size_t)l * oO;     Wol_ = wOl    + (size_t)l * oO;
      Wfh  = wF1GTh + (size_t)l * oF1;    Wfl  = wF1GTl + (size_t)l * oF1;
      W2h  = wF2h   + (size_t)l * oF2;    W2l  = wF2l   + (size_t)l * oF2;
    } else {
      wcvt_kernel<<<dim3(24, 24, 1), tb, 0, stream>>>(wq   + (size_t)l * lsDD, wQKVGh, wQKVGl, 768, 768,  0, 0, 0,    0);
      wcvt_kernel<<<dim3(24, 24, 1), tb, 0, stream>>>(wk   + (size_t)l * lsDD, wQKVGh, wQKVGl, 768, 768,  0, 0, 768,  0);
      wcvt_kernel<<<dim3(48, 24, 1), tb, 0, stream>>>(wv   + (size_t)l * lsDV, wQKVGh, wQKVGl, 768, 1536, 0, 0, 1536, 0);
      wcvt_kernel<<<dim3(48, 24, 1), tb, 0, stream>>>(wg   + (size_t)l * lsDV, wQKVGh, wQKVGl, 768, 1536, 0, 0, 3072, 0);
      wcvt_kernel<<<dim3(24, 48, 1), tb, 0, stream>>>(wo   + (size_t)l * lsDV, wOh,    wOl,    1536, 768, 0, 0, 0,    0);
      wcvt_kernel<<<dim3(96, 24, 1), tb, 0, stream>>>(fc1  + (size_t)l * lsDF, wF1GTh, wF1GTl, 768, 3072, 0, 0, 0,    1);
      wcvt_kernel<<<dim3(96, 24, 1), tb, 0, stream>>>(gate + (size_t)l * lsDF, wF1GTh, wF1GTl, 768, 3072, 0, 0, 0,    2);
      wcvt_kernel<<<dim3(24, 96, 1), tb, 0, stream>>>(fc2  + (size_t)l * lsDF, wF2h,   wF2l,   3072, 768, 0, 0, 0,    0);
      Wqkh = wQKVGh; Wqkl = wQKVGl; Woh_ = wOh; Wol_ = wOl;
      Wfh = wF1GTh; Wfl = wF1GTl; W2h = wF2h; W2l = wF2l;
    }

    ln_h_kernel<<<BS, 256, 0, stream>>>(x, ln1g + l * 768, ln1b + l * 768, hbfH);
    gemm_bt<128, 0><<<36 * 32, 256, 0, stream>>>(hbfH, Wqkh, Wqkl, cbuf, nullptr,
                                                 nullptr, 36, 768, 4608);
    prep_qk_kernel<<<BS, 384, 0, stream>>>(cbuf, 4608, qrbH, qrbL, krbH, krbL);
    vtrans_kernel<<<768, 256, 0, stream>>>(cbuf + 1536, 4608, vtb);
    hipMemsetAsync(accb, 0, (size_t)BS * DVAL * 4 + 48ull * SEQ * 4, stream);
    attn_part<<<dim3(20, 48), 256, 0, stream>>>(qrbH, qrbL, krbH, krbL, vtb, accb, dsacc);
    attn_norm<<<dim3(32, 48), 256, 0, stream>>>(accb, dsacc, cbuf + 3072, 4608, ogbH);
    gemm_bt<64, 0><<<6 * 64, 256, 0, stream>>>(ogbH, Woh_, Wol_, x, x,
                                               nullptr, 6, 1536, 768);
    ln_h_kernel<<<BS, 256, 0, stream>>>(x, ln2g + l * 768, ln2b + l * 768, hbfH);
    gemm_bt<128, 1><<<48 * 32, 256, 0, stream>>>(hbfH, Wfh, Wfl, nullptr, nullptr,
                                                 ffnbH, 48, 768, 0);
    gemm_bt<64, 0><<<6 * 64, 256, 0, stream>>>(ffnbH, W2h, W2l, x, x,
                                               nullptr, 6, 3072, 768);
  }

  float* xf = cbuf;
  ln_kernel<<<BS, 256, 0, stream>>>(x, lnfg, lnfb, xf);
  pool_kernel<<<dim3(3, 4), 256, 0, stream>>>(xf, pooled);
  clf_kernel<<<4, 128, 0, stream>>>(pooled, clfw, clfb, out);
}

// Round 12
// 7736.880 us; speedup vs baseline: 1.6969x; 1.0003x over previous
//
#include <hip/hip_runtime.h>
#include <cstdint>
#include <cstddef>

// ---------- types ----------
typedef float     f32x4 __attribute__((ext_vector_type(4)));
typedef _Float16  f16x8 __attribute__((ext_vector_type(8)));
typedef _Float16  f16x2 __attribute__((ext_vector_type(2)));

#define GLD16(g, l)                                                            \
  __builtin_amdgcn_global_load_lds(                                           \
      (const __attribute__((address_space(1))) void*)(g),                     \
      (__attribute__((address_space(3))) void*)(l), 16, 0, 0)

// ---------- constants ----------
#define BQ    4
#define SEQ   1024
#define DMOD  768
#define NH    12
#define DKH   64
#define DVH   128
#define DVAL  1536
#define DFFN  3072
#define BS    4096   /* BQ*SEQ */

// =====================================================================
// weight transpose + f32->f16 hi/lo split into fused layout.
// mode 0: orow = row_off + n  (linear)
// mode 1: fc1 interleave : orow = (n>>6)*128 + ((n>>5)&1)*64 + (n&31)
// mode 2: gate interleave: orow = (n>>6)*128 + ((n>>5)&1)*64 + 32 + (n&31)
// =====================================================================
__global__ void wcvt_kernel(const float* __restrict__ win, _Float16* __restrict__ whi,
                            _Float16* __restrict__ wlo, int K, int N,
                            long in_ls, long out_ls, int row_off, int mode)
{
  __shared__ float tle[32][33];
  size_t ib = (size_t)blockIdx.z * in_ls;
  size_t ob = (size_t)blockIdx.z * out_ls;
  int k0 = blockIdx.y * 32, n0 = blockIdx.x * 32;
  int tx = threadIdx.x, ty = threadIdx.y;
#pragma unroll
  for (int i = 0; i < 4; ++i)
    tle[ty + 8*i][tx] = win[ib + (size_t)(k0 + ty + 8*i) * N + n0 + tx];
  __syncthreads();
#pragma unroll
  for (int i = 0; i < 4; ++i) {
    float v = tle[tx][ty + 8*i];
    _Float16 h = (_Float16)v;
    int n = n0 + ty + 8*i;
    int orow;
    if (mode == 0)      orow = row_off + n;
    else if (mode == 1) orow = (n >> 6) * 128 + ((n >> 5) & 1) * 64 + (n & 31);
    else                orow = (n >> 6) * 128 + ((n >> 5) & 1) * 64 + 32 + (n & 31);
    size_t idx = ob + (size_t)orow * K + k0 + tx;
    whi[idx] = h;
    wlo[idx] = (_Float16)((v - (float)h) * 1024.0f);
  }
}

// =====================================================================
// embedding gather
// =====================================================================
__global__ void embed_kernel(const int* __restrict__ ids, const float* __restrict__ emb,
                             float* __restrict__ x)
{
  int tok = blockIdx.x;
  int id  = ids[tok];
  const float4* s = (const float4*)(emb + (size_t)id * DMOD);
  float4*       d = (float4*)(x + (size_t)tok * DMOD);
  d[threadIdx.x] = s[threadIdx.x];   // block = 192 threads
}

// =====================================================================
// layernorm over 768 -> f32 out (final LN)
// =====================================================================
__global__ __launch_bounds__(256) void ln_kernel(const float* __restrict__ x,
                                                 const float* __restrict__ g,
                                                 const float* __restrict__ bta,
                                                 float* __restrict__ out)
{
  int row = blockIdx.x;
  const float* xr = x + (size_t)row * DMOD;
  int t = threadIdx.x;
  float v0 = xr[t], v1 = xr[t + 256], v2 = xr[t + 512];
  float s  = v0 + v1 + v2;
  float sq = v0*v0 + v1*v1 + v2*v2;
#pragma unroll
  for (int m = 1; m < 64; m <<= 1) { s += __shfl_xor(s, m); sq += __shfl_xor(sq, m); }
  __shared__ float red[8];
  int wv = t >> 6, ln_ = t & 63;
  if (ln_ == 0) { red[wv] = s; red[wv + 4] = sq; }
  __syncthreads();
  s  = red[0] + red[1] + red[2] + red[3];
  sq = red[4] + red[5] + red[6] + red[7];
  float mu = s * (1.f / DMOD);
  float rs = rsqrtf(sq * (1.f / DMOD) - mu * mu + 1e-5f);
  out[(size_t)row * DMOD + t      ] = (v0 - mu) * rs * g[t      ] + bta[t      ];
  out[(size_t)row * DMOD + t + 256] = (v1 - mu) * rs * g[t + 256] + bta[t + 256];
  out[(size_t)row * DMOD + t + 512] = (v2 - mu) * rs * g[t + 512] + bta[t + 512];
}

// =====================================================================
// layernorm over 768 -> f16 (GEMM A-operand)
// =====================================================================
__global__ __launch_bounds__(256) void ln_h_kernel(const float* __restrict__ x,
                                                   const float* __restrict__ g,
                                                   const float* __restrict__ bta,
                                                   _Float16* __restrict__ oh)
{
  int row = blockIdx.x;
  const float* xr = x + (size_t)row * DMOD;
  int t = threadIdx.x;
  float v0 = xr[t], v1 = xr[t + 256], v2 = xr[t + 512];
  float s  = v0 + v1 + v2;
  float sq = v0*v0 + v1*v1 + v2*v2;
#pragma unroll
  for (int m = 1; m < 64; m <<= 1) { s += __shfl_xor(s, m); sq += __shfl_xor(sq, m); }
  __shared__ float red[8];
  int wv = t >> 6, ln_ = t & 63;
  if (ln_ == 0) { red[wv] = s; red[wv + 4] = sq; }
  __syncthreads();
  s  = red[0] + red[1] + red[2] + red[3];
  sq = red[4] + red[5] + red[6] + red[7];
  float mu = s * (1.f / DMOD);
  float rs = rsqrtf(sq * (1.f / DMOD) - mu * mu + 1e-5f);
#pragma unroll
  for (int q = 0; q < 3; ++q) {
    int c = t + q * 256;
    float y = (xr[c] - mu) * rs * g[c] + bta[c];
    oh[(size_t)row * DMOD + c] = (_Float16)y;
  }
}

// =====================================================================
// GEMM: A[M][K](f16) @ (Bh + Bl/1024)[NTOT][K](f16)^T, 2-term split
// (weight hi/lo = fp32-class weights; activations single f16).
// BMx128 tile, BK=32, 4 waves, global_load_lds + XOR swizzle, XCD swizzle,
// 2-phase double-buffered pipeline (stage next before compute, one
// s_barrier + vmcnt(0) per K-step).
// MODE 0: C[M][ldc] f32 (opt += R).          (klen == K)
// MODE 1: silu-gate epilogue, f16 out.       (klen == K)
// MODE 2: split-K partial: atomicAdd into C (C pre-holds residual).
// =====================================================================
template<int BM, int MODE>
__global__ __launch_bounds__(256) void gemm_bt(const _Float16* __restrict__ Ah,
                                               const _Float16* __restrict__ Bh,
                                               const _Float16* __restrict__ Bl,
                                               float* __restrict__ C,
                                               const float* __restrict__ R,
                                               _Float16* __restrict__ OH,
                                               int nbx, int nby, int K, int klen,
                                               int ldc)
{
  constexpr int RI = BM / 32;           // row fragments per wave
  __shared__ char sAh[2][BM * 64];
  __shared__ char sBh[2][8192];
  __shared__ char sBl[2][8192];
  const int tid = threadIdx.x, lane = tid & 63, w = tid >> 6;

  // bijective XCD swizzle over the 1D grid
  int nwg = gridDim.x, bid = blockIdx.x;
  int qq = nwg >> 3, rr = nwg & 7;
  int xc = bid & 7, ix = bid >> 3;
  int wg = (xc < rr ? xc * (qq + 1) : rr * (qq + 1) + (xc - rr) * qq) + ix;
  int bx = wg % nbx;
  int rem = wg / nbx;
  int by = rem % nby;
  int kbase = (rem / nby) * klen;

  const int m0 = by * BM, n0 = bx * 128;
  const int wm = (w >> 1) * (BM / 2), wn = (w & 1) * 64;
  const int lhi = lane >> 4, llo = lane & 15;

  const f32x4 fz = {0.f, 0.f, 0.f, 0.f};
  f32x4 accH[RI][4], accM[RI][4];
#pragma unroll
  for (int i = 0; i < RI; ++i)
#pragma unroll
    for (int j = 0; j < 4; ++j) { accH[i][j] = fz; accM[i][j] = fz; }

  auto stage = [&](int buf, int k0) {
#pragma unroll
    for (int i = 0; i < BM / 64; ++i) {           // A plane
      int off = w * (BM * 16) + i * 1024 + lane * 16;
      int r = off >> 6, c = (off >> 4) & 3;
      size_t go = (size_t)r * K + ((c ^ (r & 3)) << 3);
      GLD16(Ah + (size_t)m0 * K + k0 + go, &sAh[buf][w * (BM * 16) + i * 1024]);
    }
#pragma unroll
    for (int i = 0; i < 2; ++i) {                 // B planes (hi+lo)
      int off = w * 2048 + i * 1024 + lane * 16;
      int r = off >> 6, c = (off >> 4) & 3;
      size_t go = (size_t)r * K + ((c ^ (r & 3)) << 3);
      GLD16(Bh + (size_t)n0 * K + k0 + go, &sBh[buf][w * 2048 + i * 1024]);
      GLD16(Bl + (size_t)n0 * K + k0 + go, &sBl[buf][w * 2048 + i * 1024]);
    }
  };

  // prologue: fill buffer 0
  stage(0, kbase);
  asm volatile("s_waitcnt vmcnt(0)" ::: "memory");
  __builtin_amdgcn_s_barrier();

  int cur = 0;
  const int kend = kbase + klen;
  for (int k0 = kbase; k0 < kend; k0 += 32) {
    if (k0 + 32 < kend) stage(cur ^ 1, k0 + 32);    // prefetch next tile

    f16x8 ah[RI], bh[4], bl[4];
#pragma unroll
    for (int r = 0; r < RI; ++r) {
      int ra = wm + r * 16 + llo;
      ah[r] = *(const f16x8*)(&sAh[cur][ra * 64 + ((lhi ^ (ra & 3)) << 4)]);
    }
#pragma unroll
    for (int r = 0; r < 4; ++r) {
      int rb = wn + r * 16 + llo;
      int sb = rb * 64 + ((lhi ^ (rb & 3)) << 4);
      bh[r] = *(const f16x8*)(&sBh[cur][sb]);
      bl[r] = *(const f16x8*)(&sBl[cur][sb]);
    }
#pragma unroll
    for (int i = 0; i < RI; ++i)
#pragma unroll
      for (int j = 0; j < 4; ++j) {
        accH[i][j] = __builtin_amdgcn_mfma_f32_16x16x32_f16(ah[i], bh[j], accH[i][j], 0, 0, 0);
        accM[i][j] = __builtin_amdgcn_mfma_f32_16x16x32_f16(ah[i], bl[j], accM[i][j], 0, 0, 0);
      }

    // next tile's loads have had the whole compute phase to land
    asm volatile("s_waitcnt vmcnt(0)" ::: "memory");
    __builtin_amdgcn_s_barrier();
    cur ^= 1;
  }

  if (MODE == 0) {
#pragma unroll
    for (int i = 0; i < RI; ++i)
#pragma unroll
      for (int j = 0; j < 4; ++j)
#pragma unroll
        for (int rg = 0; rg < 4; ++rg) {
          int m = m0 + wm + i * 16 + lhi * 4 + rg;
          int n = n0 + wn + j * 16 + llo;
          size_t idx = (size_t)m * ldc + n;
          float v = accH[i][j][rg] + accM[i][j][rg] * (1.0f / 1024.0f);
          if (R) v += R[idx];
          C[idx] = v;
        }
  } else if (MODE == 2) {
    // split-K partial accumulate (C already holds residual)
#pragma unroll
    for (int i = 0; i < RI; ++i)
#pragma unroll
      for (int j = 0; j < 4; ++j)
#pragma unroll
        for (int rg = 0; rg < 4; ++rg) {
          int m = m0 + wm + i * 16 + lhi * 4 + rg;
          int n = n0 + wn + j * 16 + llo;
          float v = accH[i][j][rg] + accM[i][j][rg] * (1.0f / 1024.0f);
          atomicAdd(&C[(size_t)m * ldc + n], v);
        }
  } else {
    // silu(f1)*gate, f16 out at col = bx*64 + wn/2 + j*16 + llo
#pragma unroll
    for (int i = 0; i < RI; ++i)
#pragma unroll
      for (int j = 0; j < 2; ++j)
#pragma unroll
        for (int rg = 0; rg < 4; ++rg) {
          int m = m0 + wm + i * 16 + lhi * 4 + rg;
          int n = (n0 >> 1) + (wn >> 1) + j * 16 + llo;
          float f1 = accH[i][j][rg]     + accM[i][j][rg]     * (1.0f / 1024.0f);
          float gv = accH[i][j + 2][rg] + accM[i][j + 2][rg] * (1.0f / 1024.0f);
          float y = f1 / (1.f + expf(-f1)) * gv;
          OH[(size_t)m * 3072 + n] = (_Float16)y;
        }
  }
}

// =====================================================================
// theta-shift q,k (f32 strided in fused C) -> f16 hi/lo [B][H][S][DK]
// =====================================================================
__global__ void prep_qk_kernel(const float* __restrict__ qk, int ld,
                               _Float16* __restrict__ qrH, _Float16* __restrict__ qrL,
                               _Float16* __restrict__ krH, _Float16* __restrict__ krL)
{
  int row = blockIdx.x;                 // b*S + s
  int s = row & (SEQ - 1), b = row >> 10;
  int pi = threadIdx.x;                 // 0..383
  int d0 = pi * 2;
  int h = d0 >> 6;
  int i = d0 & 63;
  int j = i >> 1;
  float ang = exp2f(-(float)j * (13.287712379549449f / 31.f)); // 10000^{-j/31}
  float arg = (float)s * ang;
  float cc = cosf(arg), sn = sinf(arg);
  size_t src = (size_t)row * ld + d0;
  size_t dst = ((size_t)(b * NH + h) * SEQ + s) * DKH + i;

  float q0 = qk[src], q1 = qk[src + 1];
  float rq0 = q0 * cc - q1 * sn;
  float rq1 = q1 * cc + q0 * sn;
  _Float16 h0 = (_Float16)rq0, h1 = (_Float16)rq1;
  qrH[dst]     = h0; qrL[dst]     = (_Float16)((rq0 - (float)h0) * 1024.f);
  qrH[dst + 1] = h1; qrL[dst + 1] = (_Float16)((rq1 - (float)h1) * 1024.f);

  float k0 = qk[src + 768], k1 = qk[src + 769];
  float rk0 = k0 * cc - k1 * sn;
  float rk1 = k1 * cc + k0 * sn;
  _Float16 g0 = (_Float16)rk0, g1 = (_Float16)rk1;
  krH[dst]     = g0; krL[dst]     = (_Float16)((rk0 - (float)g0) * 1024.f);
  krH[dst + 1] = g1; krL[dst + 1] = (_Float16)((rk1 - (float)g1) * 1024.f);
}

// =====================================================================
// v transpose: f32 strided -> f16 [B][H][128][S]
// =====================================================================
__global__ __launch_bounds__(256) void vtrans_kernel(const float* __restrict__ vsrc, int ld,
                                                     _Float16* __restrict__ vt)
{
  __shared__ _Float16 tl[128][65];
  int bh = blockIdx.x >> 4;
  int s0 = (blockIdx.x & 15) << 6;
  int b = bh / NH, h = bh % NH;
  int t = threadIdx.x;
#pragma unroll
  for (int it = 0; it < 32; ++it) {
    int idx = it * 256 + t;
    int sl = idx >> 7, d = idx & 127;
    tl[d][sl] = (_Float16)vsrc[(size_t)(b * SEQ + s0 + sl) * ld + h * DVH + d];
  }
  __syncthreads();
#pragma unroll
  for (int it = 0; it < 32; ++it) {
    int idx = it * 256 + t;
    int d = idx >> 6, sl = idx & 63;
    vt[((size_t)bh * DVH + d) * SEQ + s0 + sl] = tl[d][sl];
  }
}

// =====================================================================
// retention stage 1: per (bh, rb, ct-chunk<=2): QK^T(3-term) -> decay ->
// PV partial; atomicAdd into accbuf[bh][s][dv] and dsacc[bh][s].
// =====================================================================
__global__ __launch_bounds__(256) void attn_part(const _Float16* __restrict__ qrH_,
                                                 const _Float16* __restrict__ qrL_,
                                                 const _Float16* __restrict__ krH_,
                                                 const _Float16* __restrict__ krL_,
                                                 const _Float16* __restrict__ vt,
                                                 float* __restrict__ accb,
                                                 float* __restrict__ dsacc)
{
  static const int RBtab[20] = {0,1,2,2,3,3,4,4,4,5,5,5,6,6,6,6,7,7,7,7};
  static const int C0tab[20] = {0,0,0,2,0,2,0,2,4,0,2,4,0,2,4,6,0,2,4,6};
  __shared__ char pbuf[32768];          // 4 waves x [32][128] f16, XOR-swizzled
  const int tid = threadIdx.x, lane = tid & 63, w = tid >> 6;
  const int rb = RBtab[blockIdx.x], c0 = C0tab[blockIdx.x];
  const int bh = blockIdx.y;            // 0..47
  const int h = bh % NH;
  const int wrow0 = rb * 128 + w * 32;
  const int lhi = lane >> 4, llo = lane & 15;

  const _Float16* qbhH = qrH_ + (size_t)bh * SEQ * DKH;
  const _Float16* qbhL = qrL_ + (size_t)bh * SEQ * DKH;
  const _Float16* kbhH = krH_ + (size_t)bh * SEQ * DKH;
  const _Float16* kbhL = krL_ + (size_t)bh * SEQ * DKH;
  const _Float16* vbh  = vt   + (size_t)bh * DVH * SEQ;

  const float lg = log1pf(-exp2f(-(float)(5 + h)));   // ln(gamma_h)
  const float den_lg = expm1f(lg);                    // gamma - 1

  float invn[2][4];
#pragma unroll
  for (int rf = 0; rf < 2; ++rf)
#pragma unroll
    for (int rg = 0; rg < 4; ++rg) {
      int n = wrow0 + rf * 16 + lhi * 4 + rg;
      float sumD = expm1f((float)(n + 1) * lg) / den_lg;  // (1-g^{n+1})/(1-g)
      invn[rf][rg] = rsqrtf(sumD) * 0.125f;               // fold DK^-0.5
    }

  float gm[8];
#pragma unroll
  for (int fc = 0; fc < 8; ++fc)
    gm[fc] = expf(-(float)(fc * 16 + llo) * lg);

  f16x8 qaH[2][2], qaL[2][2];
#pragma unroll
  for (int rf = 0; rf < 2; ++rf)
#pragma unroll
    for (int kt = 0; kt < 2; ++kt) {
      size_t qo = (size_t)(wrow0 + rf * 16 + llo) * DKH + kt * 32 + lhi * 8;
      qaH[rf][kt] = *(const f16x8*)(qbhH + qo);
      qaL[rf][kt] = *(const f16x8*)(qbhL + qo);
    }

  const f32x4 fz = {0.f, 0.f, 0.f, 0.f};
  f32x4 acc[2][8];
#pragma unroll
  for (int i = 0; i < 2; ++i)
#pragma unroll
    for (int j = 0; j < 8; ++j) acc[i][j] = fz;
  float dsum[2][4] = {{0, 0, 0, 0}, {0, 0, 0, 0}};

  const int ctend = (c0 + 1 < rb) ? c0 + 1 : rb;
  for (int ct = c0; ct <= ctend; ++ct) {
    const bool diag = (ct == rb);
    float fn[2][4];
#pragma unroll
    for (int rf = 0; rf < 2; ++rf)
#pragma unroll
      for (int rg = 0; rg < 4; ++rg) {
        int n = wrow0 + rf * 16 + lhi * 4 + rg;
        fn[rf][rg] = expf((float)(n - ct * 128) * lg) * invn[rf][rg];
      }

#pragma unroll
    for (int fc = 0; fc < 8; ++fc) {
      f32x4 pH[2] = {fz, fz}, pM[2] = {fz, fz};
#pragma unroll
      for (int kt = 0; kt < 2; ++kt) {
        size_t kro = (size_t)(ct * 128 + fc * 16 + llo) * DKH + kt * 32 + lhi * 8;
        f16x8 kbH = *(const f16x8*)(kbhH + kro);
        f16x8 kbL = *(const f16x8*)(kbhL + kro);
        pH[0] = __builtin_amdgcn_mfma_f32_16x16x32_f16(qaH[0][kt], kbH, pH[0], 0, 0, 0);
        pH[1] = __builtin_amdgcn_mfma_f32_16x16x32_f16(qaH[1][kt], kbH, pH[1], 0, 0, 0);
        pM[0] = __builtin_amdgcn_mfma_f32_16x16x32_f16(qaL[0][kt], kbH, pM[0], 0, 0, 0);
        pM[1] = __builtin_amdgcn_mfma_f32_16x16x32_f16(qaL[1][kt], kbH, pM[1], 0, 0, 0);
        pM[0] = __builtin_amdgcn_mfma_f32_16x16x32_f16(qaH[0][kt], kbL, pM[0], 0, 0, 0);
        pM[1] = __builtin_amdgcn_mfma_f32_16x16x32_f16(qaH[1][kt], kbL, pM[1], 0, 0, 0);
      }
#pragma unroll
      for (int rf = 0; rf < 2; ++rf)
#pragma unroll
        for (int rg = 0; rg < 4; ++rg) {
          float pv = (pH[rf][rg] + pM[rf][rg] * (1.f / 1024.f)) * fn[rf][rg] * gm[fc];
          if (diag) {
            int e = (wrow0 + rf * 16 + lhi * 4 + rg) - (ct * 128 + fc * 16 + llo);
            if (e < 0) pv = 0.f;
          }
          dsum[rf][rg] += fabsf(pv);
          int prow = rf * 16 + lhi * 4 + rg;
          int byte = (w << 13) + prow * 256 + (fc * 16 + llo) * 2;
          byte ^= (prow & 7) << 4;
          *(_Float16*)(pbuf + byte) = (_Float16)pv;
        }
    }
    // each wave reads only its own pbuf slice — no barrier needed

    f16x8 pa[2][4];
#pragma unroll
    for (int rf2 = 0; rf2 < 2; ++rf2)
#pragma unroll
      for (int kt = 0; kt < 4; ++kt) {
        int prow = rf2 * 16 + llo;
        int byte = (w << 13) + prow * 256 + kt * 64 + lhi * 16;
        byte ^= (prow & 7) << 4;
        pa[rf2][kt] = *(const f16x8*)(pbuf + byte);
      }
#pragma unroll
    for (int fd = 0; fd < 8; ++fd)
#pragma unroll
      for (int kt = 0; kt < 4; ++kt) {
        f16x8 vb = *(const f16x8*)(vbh + (size_t)(fd * 16 + llo) * SEQ + ct * 128 + kt * 32 + lhi * 8);
        acc[0][fd] = __builtin_amdgcn_mfma_f32_16x16x32_f16(pa[0][kt], vb, acc[0][fd], 0, 0, 0);
        acc[1][fd] = __builtin_amdgcn_mfma_f32_16x16x32_f16(pa[1][kt], vb, acc[1][fd], 0, 0, 0);
      }
  }

  float* ab = accb + (size_t)bh * SEQ * DVH;
#pragma unroll
  for (int rf = 0; rf < 2; ++rf)
#pragma unroll
    for (int rg = 0; rg < 4; ++rg) {
      float d = dsum[rf][rg];
      d += __shfl_xor(d, 1); d += __shfl_xor(d, 2);
      d += __shfl_xor(d, 4); d += __shfl_xor(d, 8);
      int row = wrow0 + rf * 16 + lhi * 4 + rg;
      if (llo == 0) atomicAdd(&dsacc[bh * SEQ + row], d);
#pragma unroll
      for (int fd = 0; fd < 8; ++fd)
        atomicAdd(&ab[(size_t)row * DVH + fd * 16 + llo], acc[rf][fd][rg]);
    }
}

// =====================================================================
// retention stage 2: row-normalize + group-norm + silu(g)*o fused,
// writes ogb f16 [B*S][1536]
// =====================================================================
__global__ __launch_bounds__(256) void attn_norm(const float* __restrict__ accb,
                                                 const float* __restrict__ dsacc,
                                                 const float* __restrict__ gsrc, int ldg,
                                                 _Float16* __restrict__ oh)
{
  int bh = blockIdx.y, h = bh % NH, b = bh / NH;
  int s0 = blockIdx.x * 32;
  int lane = threadIdx.x & 63, w = threadIdx.x >> 6;
  const float* ab = accb + ((size_t)bh * SEQ + s0) * DVH;
#pragma unroll
  for (int i = 0; i < 8; ++i) {
    int r = w * 8 + i;
    size_t row = (size_t)(b * SEQ + s0 + r);
    float2 v = *(const float2*)(ab + (size_t)r * DVH + lane * 2);
    float inv = 1.f / fmaxf(dsacc[bh * SEQ + s0 + r], 1.f);
    v.x *= inv; v.y *= inv;
    float ss = v.x * v.x + v.y * v.y;
#pragma unroll
    for (int m = 1; m < 64; m <<= 1) ss += __shfl_xor(ss, m);
    float rs = rsqrtf(ss * (1.f / 128.f) + 1e-5f);
    float o0 = v.x * rs, o1 = v.y * rs;
    float2 g = *(const float2*)(gsrc + row * ldg + h * DVH + lane * 2);
    float y0 = g.x / (1.f + expf(-g.x)) * o0;
    float y1 = g.y / (1.f + expf(-g.y)) * o1;
    f16x2 vh = {(_Float16)y0, (_Float16)y1};
    *(f16x2*)(oh + row * DVAL + h * DVH + lane * 2) = vh;
  }
}

// =====================================================================
// mean pool over S
// =====================================================================
__global__ void pool_kernel(const float* __restrict__ xf, float* __restrict__ pooled)
{
  int d = blockIdx.x * 256 + threadIdx.x;   // grid.x = 3
  int b = blockIdx.y;
  float acc = 0.f;
  for (int s = 0; s < SEQ; ++s) acc += xf[((size_t)(b * SEQ + s)) * DMOD + d];
  pooled[b * DMOD + d] = acc * (1.f / SEQ);
}

// =====================================================================
// classifier
// =====================================================================
__global__ void clf_kernel(const float* __restrict__ pooled, const float* __restrict__ cw,
                           const float* __restrict__ cb, float* __restrict__ out)
{
  int b = blockIdx.x, c = threadIdx.x;
  if (c < 100) {
    float acc = cb[c];
    for (int d = 0; d < DMOD; ++d) acc += pooled[b * DMOD + d] * cw[d * 100 + c];
    out[b * 100 + c] = acc;
  }
}

// =====================================================================
// host
// =====================================================================
extern "C" void kernel_launch(void* const* d_in, const int* in_sizes, int n_in,
                              void* d_out, int out_size, void* d_ws, size_t ws_size,
                              hipStream_t stream)
{
  const int*   ids  = (const int*)d_in[0];
  const float* emb  = (const float*)d_in[1];
  const float* wq   = (const float*)d_in[2];
  const float* wk   = (const float*)d_in[3];
  const float* wv   = (const float*)d_in[4];
  const float* wg   = (const float*)d_in[5];
  const float* wo   = (const float*)d_in[6];
  const float* ln1g = (const float*)d_in[7];
  const float* ln1b = (const float*)d_in[8];
  const float* ln2g = (const float*)d_in[9];
  const float* ln2b = (const float*)d_in[10];
  const float* fc1  = (const float*)d_in[11];
  const float* gate = (const float*)d_in[12];
  const float* fc2  = (const float*)d_in[13];
  const float* lnfg = (const float*)d_in[14];
  const float* lnfb = (const float*)d_in[15];
  const float* clfw = (const float*)d_in[16];
  const float* clfb = (const float*)d_in[17];
  float* out = (float*)d_out;

  char* ws = (char*)d_ws;
  size_t off = 0;
  auto alloc = [&](size_t bytes) {
    size_t r = off;
    off = (off + bytes + 255) & ~(size_t)255;
    return r;
  };

  const size_t W_QKVG = 12ull * 4608 * 768 * 2;
  const size_t W_O    = 12ull * 768 * 1536 * 2;
  const size_t W_F1GT = 12ull * 6144 * 768 * 2;
  const size_t W_F2   = 12ull * 768 * 3072 * 2;
  const bool big = ws_size >= 780ull * 1024 * 1024;
  const size_t d12 = big ? 1 : 12;

  _Float16* wQKVGh = (_Float16*)(ws + alloc(W_QKVG / d12));
  _Float16* wQKVGl = (_Float16*)(ws + alloc(W_QKVG / d12));
  _Float16* wOh    = (_Float16*)(ws + alloc(W_O    / d12));
  _Float16* wOl    = (_Float16*)(ws + alloc(W_O    / d12));
  _Float16* wF1GTh = (_Float16*)(ws + alloc(W_F1GT / d12));
  _Float16* wF1GTl = (_Float16*)(ws + alloc(W_F1GT / d12));
  _Float16* wF2h   = (_Float16*)(ws + alloc(W_F2   / d12));
  _Float16* wF2l   = (_Float16*)(ws + alloc(W_F2   / d12));

  float*    x    = (float*)(ws + alloc((size_t)BS * DMOD * 4));
  _Float16* hbfH = (_Float16*)(ws + alloc((size_t)BS * DMOD * 2));
  float*    cbuf = (float*)(ws + alloc((size_t)BS * 4608 * 4));   // qkvg GEMM out
  char*     regB = ws + alloc(8ull * 6291456);                    // 50.3 MB
  float*    accb = (float*)(ws + alloc((size_t)BS * DVAL * 4 + 48ull * SEQ * 4));
  float*    dsacc = accb + (size_t)BS * DVAL;
  float*    pooled = (float*)(ws + alloc(4 * DMOD * 4));

  _Float16* qrbH = (_Float16*)regB;
  _Float16* qrbL = (_Float16*)(regB + 6291456);
  _Float16* krbH = (_Float16*)(regB + 12582912);
  _Float16* krbL = (_Float16*)(regB + 18874368);
  _Float16* vtb  = (_Float16*)(regB + 25165824);
  _Float16* ogbH = (_Float16*)regB;                 // alias (post-attn_part)
  _Float16* ffnbH = (_Float16*)regB;                // alias (post-wo)

  dim3 tb(32, 8);
  const long lsDD = 768l * 768, lsDV = 768l * 1536, lsDF = 768l * 3072;
  const long oQKVG = 4608l * 768, oO = 768l * 1536, oF1 = 6144l * 768, oF2 = 768l * 3072;

  if (big) {
    wcvt_kernel<<<dim3(24, 24, 12), tb, 0, stream>>>(wq,   wQKVGh, wQKVGl, 768, 768,  lsDD, oQKVG, 0,    0);
    wcvt_kernel<<<dim3(24, 24, 12), tb, 0, stream>>>(wk,   wQKVGh, wQKVGl, 768, 768,  lsDD, oQKVG, 768,  0);
    wcvt_kernel<<<dim3(48, 24, 12), tb, 0, stream>>>(wv,   wQKVGh, wQKVGl, 768, 1536, lsDV, oQKVG, 1536, 0);
    wcvt_kernel<<<dim3(48, 24, 12), tb, 0, stream>>>(wg,   wQKVGh, wQKVGl, 768, 1536, lsDV, oQKVG, 3072, 0);
    wcvt_kernel<<<dim3(24, 48, 12), tb, 0, stream>>>(wo,   wOh,    wOl,    1536, 768, lsDV, oO,    0,    0);
    wcvt_kernel<<<dim3(96, 24, 12), tb, 0, stream>>>(fc1,  wF1GTh, wF1GTl, 768, 3072, lsDF, oF1,   0,    1);
    wcvt_kernel<<<dim3(96, 24, 12), tb, 0, stream>>>(gate, wF1GTh, wF1GTl, 768, 3072, lsDF, oF1,   0,    2);
    wcvt_kernel<<<dim3(24, 96, 12), tb, 0, stream>>>(fc2,  wF2h,   wF2l,   3072, 768, lsDF, oF2,   0,    0);
  }

  embed_kernel<<<BS, 192, 0, stream>>>(ids, emb, x);

  for (int l = 0; l < 12; ++l) {
    const _Float16 *Wqkh, *Wqkl, *Woh_, *Wol_, *Wfh, *Wfl, *W2h, *W2l;
    if (big) {
      Wqkh = wQKVGh + (size_t)l * oQKVG;  Wqkl = wQKVGl + (size_t)l * oQKVG;
      Woh_ = wOh    + (size_t)l * oO;     Wol_ = wOl    + (size_t)l * oO;
      Wfh  = wF1GTh + (size_t)l * oF1;    Wfl  = wF1GTl + (size_t)l * oF1;
      W2h  = wF2h   + (size_t)l * oF2;    W2l  = wF2l   + (size_t)l * oF2;
    } else {
      wcvt_kernel<<<dim3(24, 24, 1), tb, 0, stream>>>(wq   + (size_t)l * lsDD, wQKVGh, wQKVGl, 768, 768,  0, 0, 0,    0);
      wcvt_kernel<<<dim3(24, 24, 1), tb, 0, stream>>>(wk   + (size_t)l * lsDD, wQKVGh, wQKVGl, 768, 768,  0, 0, 768,  0);
      wcvt_kernel<<<dim3(48, 24, 1), tb, 0, stream>>>(wv   + (size_t)l * lsDV, wQKVGh, wQKVGl, 768, 1536, 0, 0, 1536, 0);
      wcvt_kernel<<<dim3(48, 24, 1), tb, 0, stream>>>(wg   + (size_t)l * lsDV, wQKVGh, wQKVGl, 768, 1536, 0, 0, 3072, 0);
      wcvt_kernel<<<dim3(24, 48, 1), tb, 0, stream>>>(wo   + (size_t)l * lsDV, wOh,    wOl,    1536, 768, 0, 0, 0,    0);
      wcvt_kernel<<<dim3(96, 24, 1), tb, 0, stream>>>(fc1  + (size_t)l * lsDF, wF1GTh, wF1GTl, 768, 3072, 0, 0, 0,    1);
      wcvt_kernel<<<dim3(96, 24, 1), tb, 0, stream>>>(gate + (size_t)l * lsDF, wF1GTh, wF1GTl, 768, 3072, 0, 0, 0,    2);
      wcvt_kernel<<<dim3(24, 96, 1), tb, 0, stream>>>(fc2  + (size_t)l * lsDF, wF2h,   wF2l,   3072, 768, 0, 0, 0,    0);
      Wqkh = wQKVGh; Wqkl = wQKVGl; Woh_ = wOh; Wol_ = wOl;
      Wfh = wF1GTh; Wfl = wF1GTl; W2h = wF2h; W2l = wF2l;
    }

    ln_h_kernel<<<BS, 256, 0, stream>>>(x, ln1g + l * 768, ln1b + l * 768, hbfH);
    gemm_bt<128, 0><<<36 * 32, 256, 0, stream>>>(hbfH, Wqkh, Wqkl, cbuf, nullptr,
                                                 nullptr, 36, 32, 768, 768, 4608);
    prep_qk_kernel<<<BS, 384, 0, stream>>>(cbuf, 4608, qrbH, qrbL, krbH, krbL);
    vtrans_kernel<<<768, 256, 0, stream>>>(cbuf + 1536, 4608, vtb);
    hipMemsetAsync(accb, 0, (size_t)BS * DVAL * 4 + 48ull * SEQ * 4, stream);
    attn_part<<<dim3(20, 48), 256, 0, stream>>>(qrbH, qrbL, krbH, krbL, vtb, accb, dsacc);
    attn_norm<<<dim3(32, 48), 256, 0, stream>>>(accb, dsacc, cbuf + 3072, 4608, ogbH);
    // wo: split-K x2, partials atomically accumulate into x (holds residual)
    gemm_bt<64, 2><<<6 * 64 * 2, 256, 0, stream>>>(ogbH, Woh_, Wol_, x, nullptr,
                                                   nullptr, 6, 64, 1536, 768, 768);
    ln_h_kernel<<<BS, 256, 0, stream>>>(x, ln2g + l * 768, ln2b + l * 768, hbfH);
    gemm_bt<128, 1><<<48 * 32, 256, 0, stream>>>(hbfH, Wfh, Wfl, nullptr, nullptr,
                                                 ffnbH, 48, 32, 768, 768, 0);
    // f2: split-K x4
    gemm_bt<64, 2><<<6 * 64 * 4, 256, 0, stream>>>(ffnbH, W2h, W2l, x, nullptr,
                                                   nullptr, 6, 64, 3072, 768, 768);
  }

  float* xf = cbuf;
  ln_kernel<<<BS, 256, 0, stream>>>(x, lnfg, lnfb, xf);
  pool_kernel<<<dim3(3, 4), 256, 0, stream>>>(xf, pooled);
  clf_kernel<<<4, 128, 0, stream>>>(pooled, clfw, clfb, out);
}